// Round 16
// baseline (221.827 us; speedup 1.0000x reference)
//
#include <hip/hip_runtime.h>
#include <math.h>

#define N_NODES 50000
#define E_EDGES 800000
#define ET      (E_EDGES + N_NODES)   // edges + self loops
#define IN_DIM  128
#define HID     128
#define HEADS   8
#define C1      16
#define OUT_DIM 64
#define NEG_SLOPE 0.2f
#define LOG2E   1.4426950408889634f

#define TILE    8192
#define NT      ((ET + TILE - 1) / TILE)      // 104 tiles
#define NB      ((N_NODES + 255) / 256)       // 196 buckets of 256 nodes

#define CONV_BLOCKS (N_NODES * IN_DIM / 4 / 256)   // 6250
#define PREP_BLOCKS 112
#define MEGA_A (NT + CONV_BLOCKS + PREP_BLOCKS)    // 6466
#define L1T_BLOCKS ((N_NODES + 63) / 64)           // 782
#define MEGA_B (NB + L1T_BLOCKS)                   // 978

typedef unsigned int uint32;
typedef __attribute__((ext_vector_type(8))) short bf16x8;
typedef __attribute__((ext_vector_type(4))) float f32x4;

static __device__ __forceinline__ unsigned short f2bf(float f) {
    uint32 u = __float_as_uint(f);
    u += 0x7FFFu + ((u >> 16) & 1u);   // round to nearest even
    return (unsigned short)(u >> 16);
}

// ---------------- Mega-kernel A: bucket_hist + convert_x + prep_weights ----------------

__global__ __launch_bounds__(256) void prep_all(
        const int* __restrict__ dst, int* __restrict__ cnt,
        const float* __restrict__ x, unsigned short* __restrict__ xb,
        const float* __restrict__ W1, const float* __restrict__ as1,
        const float* __restrict__ ad1, const float* __restrict__ W2,
        const float* __restrict__ as2, const float* __restrict__ ad2,
        unsigned short* __restrict__ w1t, unsigned short* __restrict__ p1t,
        unsigned short* __restrict__ w2t, unsigned short* __restrict__ p2t) {
    __shared__ int hist[NB];
    int blk = blockIdx.x, t = threadIdx.x;
    if (blk < NT) {
        for (int b = t; b < NB; b += 256) hist[b] = 0;
        __syncthreads();
        int base = blk * TILE;
        #pragma unroll
        for (int it = 0; it < TILE / 256; ++it) {
            int i = base + it * 256 + t;
            if (i < ET) {
                int d = (i < E_EDGES) ? dst[i] : (i - E_EDGES);
                atomicAdd(&hist[d >> 8], 1);
            }
        }
        __syncthreads();
        for (int b = t; b < NB; b += 256) cnt[blk * NB + b] = hist[b];
    } else if (blk < NT + CONV_BLOCKS) {
        int i = (blk - NT) * 256 + t;
        float4 v = ((const float4*)x)[i];
        ushort4 o;
        o.x = f2bf(v.x); o.y = f2bf(v.y); o.z = f2bf(v.z); o.w = f2bf(v.w);
        ((ushort4*)xb)[i] = o;
    } else {
        int b = blk - NT - CONV_BLOCKS;    // 0..111
        if (b < 64) {
            int i = b * 256 + t;                // n*128+k
            int n = i >> 7, k = i & 127;
            w1t[n * IN_DIM + k] = f2bf(W1[k * HID + n]);
        } else if (b < 96) {
            int i = (b - 64) * 256 + t;         // n*128+k, n<64
            int n = i >> 7, k = i & 127;
            w2t[n * HID + k] = f2bf(W2[k * OUT_DIM + n]);
        } else if (b < 104) {
            int i = (b - 96) * 256 + t;         // j*128+k, j<16
            int j = i >> 7, k = i & 127;
            int hh = j & 7;
            const float* a = (j < 8) ? as1 : ad1;
            float acc = 0.f;
            #pragma unroll
            for (int c = 0; c < C1; ++c)
                acc = fmaf(W1[k * HID + hh * C1 + c], a[hh * C1 + c], acc);
            p1t[j * IN_DIM + k] = f2bf(acc * LOG2E);
        } else {
            int i = (b - 104) * 256 + t;        // j*128+k, j<16
            int j = i >> 7, k = i & 127;
            if (j < 2) {
                const float* a = (j == 0) ? as2 : ad2;
                float acc = 0.f;
                #pragma unroll
                for (int c = 0; c < OUT_DIM; ++c)
                    acc = fmaf(W2[k * OUT_DIM + c], a[c], acc);
                p2t[j * HID + k] = f2bf(acc * LOG2E);
            } else {
                p2t[j * HID + k] = 0;
            }
        }
    }
}

// ---------------- bucket_scatter (scan fused in) ----------------

__global__ __launch_bounds__(256) void bucket_scatter(
        const int* __restrict__ src, const int* __restrict__ dst,
        const int* __restrict__ cnt, int* __restrict__ bucketStart,
        uint32* __restrict__ pairs) {
    __shared__ int lcur[NB];
    __shared__ int sscan[256];
    int t = threadIdx.x;
    int tile = blockIdx.x;

    int run = 0, total = 0;
    if (t < NB) {
        for (int k = 0; k < NT; ++k) {
            int c = cnt[k * NB + t];     // coalesced across t
            if (k < tile) run += c;
            total += c;
        }
    }
    sscan[t] = (t < NB) ? total : 0;
    __syncthreads();
    #pragma unroll
    for (int off = 1; off < 256; off <<= 1) {
        int add = (t >= off) ? sscan[t - off] : 0;
        __syncthreads();
        sscan[t] += add;
        __syncthreads();
    }
    int bstart = sscan[t] - total;       // exclusive prefix
    if (t < NB) {
        lcur[t] = bstart + run;
        if (tile == 0) bucketStart[t] = bstart;
    }
    if (tile == 0 && t == 0) bucketStart[NB] = ET;
    __syncthreads();

    int base = tile * TILE;
    #pragma unroll
    for (int it = 0; it < TILE / 256; ++it) {
        int i = base + it * 256 + t;
        if (i < ET) {
            int s, d;
            if (i < E_EDGES) { s = src[i]; d = dst[i]; }
            else             { s = d = i - E_EDGES; }
            int pos = atomicAdd(&lcur[d >> 8], 1);
            pairs[pos] = ((uint32)s << 8) | (uint32)(d & 255);
        }
    }
}

// ---------------- Mega-kernel B: bucket_build + l1_transform_mfma ----------------

__global__ __launch_bounds__(256) void build_l1t(
        const uint32* __restrict__ pairs, const int* __restrict__ bucketStart,
        int* __restrict__ row_start, int* __restrict__ csr_src,
        const unsigned short* __restrict__ xb, const unsigned short* __restrict__ w1t,
        const unsigned short* __restrict__ p1t, unsigned short* __restrict__ h1b,
        float* __restrict__ a_src, float* __restrict__ a_dst) {
    __shared__ int sdeg[256];
    __shared__ int sscan[256];
    int t = threadIdx.x;
    if (blockIdx.x < NB) {
        int b = blockIdx.x;
        int beg = bucketStart[b], end = bucketStart[b + 1];
        sdeg[t] = 0;
        __syncthreads();
        for (int j = beg + t; j < end; j += 256)
            atomicAdd(&sdeg[pairs[j] & 255u], 1);
        __syncthreads();
        int v = sdeg[t];
        sscan[t] = v;
        __syncthreads();
        #pragma unroll
        for (int off = 1; off < 256; off <<= 1) {
            int add = (t >= off) ? sscan[t - off] : 0;
            __syncthreads();
            sscan[t] += add;
            __syncthreads();
        }
        int pos0 = beg + sscan[t] - v;   // exclusive prefix within bucket
        int n = b * 256 + t;
        if (n < N_NODES) row_start[n] = pos0;
        if (b == 0 && t == 0) row_start[N_NODES] = ET;
        __syncthreads();
        sscan[t] = pos0;                 // reuse as cursor
        __syncthreads();
        for (int j = beg + t; j < end; j += 256) {
            uint32 p = pairs[j];
            int pos = atomicAdd(&sscan[p & 255u], 1);
            csr_src[pos] = (int)(p >> 8);
        }
        return;
    }
    // ---- layer-1 transform via MFMA, LDS-free ----
    int bb = blockIdx.x - NB;
    int w = t >> 6, lane = t & 63;
    int l15 = lane & 15, quad = lane >> 4;
    int n0 = bb * 64 + w * 16;
    int mrow = n0 + l15;
    int mload = (mrow < N_NODES) ? mrow : (N_NODES - 1);

    bf16x8 af[4];
    #pragma unroll
    for (int s = 0; s < 4; ++s)
        af[s] = *(const bf16x8*)&xb[(size_t)mload * IN_DIM + s * 32 + quad * 8];

    #pragma unroll
    for (int tt = 0; tt < 9; ++tt) {
        const unsigned short* Brow = (tt < 8) ? &w1t[(tt * 16 + l15) * IN_DIM]
                                              : &p1t[l15 * IN_DIM];
        f32x4 acc = {0.f, 0.f, 0.f, 0.f};
        #pragma unroll
        for (int s = 0; s < 4; ++s) {
            bf16x8 bf = *(const bf16x8*)&Brow[s * 32 + quad * 8];
            acc = __builtin_amdgcn_mfma_f32_16x16x32_bf16(af[s], bf, acc, 0, 0, 0);
        }
        int nodeb = n0 + quad * 4;
        if (tt < 8) {
            int ch = tt * 16 + l15;
            #pragma unroll
            for (int r = 0; r < 4; ++r)
                if (nodeb + r < N_NODES)
                    h1b[(size_t)(nodeb + r) * HID + ch] = f2bf(acc[r]);
        } else {
            #pragma unroll
            for (int r = 0; r < 4; ++r) {
                if (nodeb + r < N_NODES) {
                    if (l15 < 8) a_src[(nodeb + r) * HEADS + l15] = acc[r];
                    else         a_dst[(nodeb + r) * HEADS + (l15 - 8)] = acc[r];
                }
            }
        }
    }
}

// ---------------- Fused: layer-1 aggregate + layer-2 transform ----------------
// 1024-thread block (16 waves) covers 64 nodes. Phase A: each wave aggregates
// 4 nodes in ONE pass (16 lanes/node, 8 bf16 ch/lane, uint4 gathers) -> full
// wave parallelism (12.5k waves). h_act lives in LDS (XOR-swizzled granules).
// Phase B: wave (rg = w>>2, u = w&3) MFMAs output tile tt=u for row group rg;
// u==0 also does the tt=4 attention tile.

__global__ __launch_bounds__(1024) void l1agg_l2t(
        const unsigned short* __restrict__ h1b, const float* __restrict__ a_src,
        const float* __restrict__ a_dst, const int* __restrict__ row_start,
        const int* __restrict__ csr_src, const float* __restrict__ b1,
        const unsigned short* __restrict__ w2t, const unsigned short* __restrict__ p2t,
        unsigned short* __restrict__ h2b, float* __restrict__ a_src2,
        float* __restrict__ a_dst2) {
    __shared__ unsigned short ha[64][128];   // 16 KB, swizzled granules
    int t = threadIdx.x;
    int w = t >> 6;              // 0..15
    uint32 lane = t & 63;
    uint32 quarter = lane >> 4;
    uint32 lane16 = lane & 15;
    int n0blk = blockIdx.x * 64;

    // ---------- phase A: 16 waves x 4 nodes ----------
    {
        uint32 c0 = lane16 * 8u;     // 8 channels per lane
        uint32 h = lane16 >> 1;      // head = c0 >> 4
        int n_local = (w >> 2) * 16 + (w & 3) * 4 + (int)quarter;
        int n = n0blk + n_local;
        int nc = (n < N_NODES) ? n : (N_NODES - 1);
        int beg = row_start[nc], end = row_start[nc + 1];
        int cnt = end - beg;
        int kmax = cnt;
        kmax = max(kmax, __shfl_xor(kmax, 16, 64));
        kmax = max(kmax, __shfl_xor(kmax, 32, 64));
        float adst = a_dst[nc * HEADS + h];
        float l = 0.f;
        float a0 = 0.f, a1 = 0.f, a2 = 0.f, a3 = 0.f;
        float a4 = 0.f, a5 = 0.f, a6 = 0.f, a7 = 0.f;

        for (int k = 0; k < kmax; k += 4) {
            uint32 ss[4]; float ee[4]; uint4 uu[4];
            #pragma unroll
            for (int q = 0; q < 4; ++q) {
                int j = beg + k + q;
                int jc = (j < end) ? j : (end - 1);    // cnt >= 1 (self loop)
                ss[q] = (uint32)csr_src[jc];
            }
            #pragma unroll
            for (int q = 0; q < 4; ++q) ee[q] = a_src[ss[q] * 8u + h];
            #pragma unroll
            for (int q = 0; q < 4; ++q) uu[q] = *(const uint4*)&h1b[(ss[q] << 7) + c0];
            #pragma unroll
            for (int q = 0; q < 4; ++q) {
                float e = ee[q] + adst;
                e = fmaxf(e, NEG_SLOPE * e);          // leaky relu (log2 domain)
                e = (k + q < cnt) ? e : -10000.f;     // masked lane -> p = 0
                float p = exp2f(e);
                l += p;
                a0 = fmaf(p, __uint_as_float(uu[q].x << 16), a0);
                a1 = fmaf(p, __uint_as_float(uu[q].x & 0xFFFF0000u), a1);
                a2 = fmaf(p, __uint_as_float(uu[q].y << 16), a2);
                a3 = fmaf(p, __uint_as_float(uu[q].y & 0xFFFF0000u), a3);
                a4 = fmaf(p, __uint_as_float(uu[q].z << 16), a4);
                a5 = fmaf(p, __uint_as_float(uu[q].z & 0xFFFF0000u), a5);
                a6 = fmaf(p, __uint_as_float(uu[q].w << 16), a6);
                a7 = fmaf(p, __uint_as_float(uu[q].w & 0xFFFF0000u), a7);
            }
        }

        float inv = 1.f / (l + 1e-16f);
        float v0 = a0 * inv + b1[c0 + 0];
        float v1 = a1 * inv + b1[c0 + 1];
        float v2 = a2 * inv + b1[c0 + 2];
        float v3 = a3 * inv + b1[c0 + 3];
        float v4 = a4 * inv + b1[c0 + 4];
        float v5 = a5 * inv + b1[c0 + 5];
        float v6 = a6 * inv + b1[c0 + 6];
        float v7 = a7 * inv + b1[c0 + 7];
        v0 = v0 > 0.f ? v0 : (__expf(v0) - 1.f);   // ELU
        v1 = v1 > 0.f ? v1 : (__expf(v1) - 1.f);
        v2 = v2 > 0.f ? v2 : (__expf(v2) - 1.f);
        v3 = v3 > 0.f ? v3 : (__expf(v3) - 1.f);
        v4 = v4 > 0.f ? v4 : (__expf(v4) - 1.f);
        v5 = v5 > 0.f ? v5 : (__expf(v5) - 1.f);
        v6 = v6 > 0.f ? v6 : (__expf(v6) - 1.f);
        v7 = v7 > 0.f ? v7 : (__expf(v7) - 1.f);
        uint4 packed;
        packed.x = (uint32)f2bf(v0) | ((uint32)f2bf(v1) << 16);
        packed.y = (uint32)f2bf(v2) | ((uint32)f2bf(v3) << 16);
        packed.z = (uint32)f2bf(v4) | ((uint32)f2bf(v5) << 16);
        packed.w = (uint32)f2bf(v6) | ((uint32)f2bf(v7) << 16);
        uint32 g = lane16 ^ ((uint32)n_local & 15u);   // swizzled granule
        *(uint4*)&ha[n_local][g * 8] = packed;
    }
    __syncthreads();

    // ---------- phase B: layer-2 transform from LDS, tt split across waves ----------
    {
        int rg = w >> 2, u = w & 3;
        int l15 = (int)lane16, quad = (int)quarter;
        int n0 = n0blk + rg * 16;
        int nloc = rg * 16 + l15;

        bf16x8 af[4];
        #pragma unroll
        for (int s = 0; s < 4; ++s) {
            uint32 g = (uint32)(s * 4 + quad) ^ (uint32)l15;
            af[s] = *(const bf16x8*)&ha[nloc][g * 8];
        }

        #pragma unroll
        for (int pass = 0; pass < 2; ++pass) {
            if (pass == 1 && u != 0) break;
            int tt = (pass == 0) ? u : 4;
            const unsigned short* Brow = (tt < 4) ? &w2t[(tt * 16 + l15) * HID]
                                                  : &p2t[l15 * HID];
            f32x4 acc = {0.f, 0.f, 0.f, 0.f};
            #pragma unroll
            for (int s = 0; s < 4; ++s) {
                bf16x8 bf = *(const bf16x8*)&Brow[s * 32 + quad * 8];
                acc = __builtin_amdgcn_mfma_f32_16x16x32_bf16(af[s], bf, acc, 0, 0, 0);
            }
            int nodeb = n0 + quad * 4;
            if (tt < 4) {
                int ch = tt * 16 + l15;
                #pragma unroll
                for (int r = 0; r < 4; ++r)
                    if (nodeb + r < N_NODES)
                        h2b[(size_t)(nodeb + r) * OUT_DIM + ch] = f2bf(acc[r]);
            } else {
                #pragma unroll
                for (int r = 0; r < 4; ++r) {
                    if (nodeb + r < N_NODES) {
                        if (l15 == 0) a_src2[nodeb + r] = acc[r];
                        else if (l15 == 1) a_dst2[nodeb + r] = acc[r];
                    }
                }
            }
        }
    }
}

// ---------------- Layer 2: aggregate + log_softmax ----------------
// 4 nodes per wave: 16 lanes per node, 4 channels/lane (uint2 gathers).

__global__ __launch_bounds__(128) void l2_aggregate(
        const unsigned short* __restrict__ h2b, const float* __restrict__ a_src2,
        const float* __restrict__ a_dst2, const int* __restrict__ row_start,
        const int* __restrict__ csr_src, const float* __restrict__ b2,
        float* __restrict__ out) {
    int t = threadIdx.x;
    int w = t >> 6;
    uint32 lane = t & 63;
    uint32 quarter = lane >> 4;
    uint32 lane16 = lane & 15;
    int n = blockIdx.x * 8 + w * 4 + (int)quarter;
    uint32 c0 = lane16 * 4u;
    int beg = row_start[n], end = row_start[n + 1];
    int cnt = end - beg;
    int kmax = cnt;
    kmax = max(kmax, __shfl_xor(kmax, 16, 64));
    kmax = max(kmax, __shfl_xor(kmax, 32, 64));
    float adst = a_dst2[n];
    float l = 0.f, a0 = 0.f, a1 = 0.f, a2 = 0.f, a3 = 0.f;

    for (int k = 0; k < kmax; k += 4) {
        uint32 ss[4]; float ee[4]; uint2 uu[4];
        #pragma unroll
        for (int q = 0; q < 4; ++q) {
            int j = beg + k + q;
            int jc = (j < end) ? j : (end - 1);
            ss[q] = (uint32)csr_src[jc];
        }
        #pragma unroll
        for (int q = 0; q < 4; ++q) ee[q] = a_src2[ss[q]];
        #pragma unroll
        for (int q = 0; q < 4; ++q) uu[q] = *(const uint2*)&h2b[(ss[q] << 6) + c0];
        #pragma unroll
        for (int q = 0; q < 4; ++q) {
            float e = ee[q] + adst;
            e = fmaxf(e, NEG_SLOPE * e);
            e = (k + q < cnt) ? e : -10000.f;   // masked lane -> p = 0
            float p = exp2f(e);
            l += p;
            a0 = fmaf(p, __uint_as_float(uu[q].x << 16), a0);
            a1 = fmaf(p, __uint_as_float(uu[q].x & 0xFFFF0000u), a1);
            a2 = fmaf(p, __uint_as_float(uu[q].y << 16), a2);
            a3 = fmaf(p, __uint_as_float(uu[q].y & 0xFFFF0000u), a3);
        }
    }

    float inv = 1.f / (l + 1e-16f);
    float o0 = a0 * inv + b2[c0 + 0];
    float o1 = a1 * inv + b2[c0 + 1];
    float o2 = a2 * inv + b2[c0 + 2];
    float o3 = a3 * inv + b2[c0 + 3];
    // log_softmax over 64 channels = 16 lanes x 4 (quarter-wave reduction)
    float mx = fmaxf(fmaxf(o0, o1), fmaxf(o2, o3));
    #pragma unroll
    for (int m = 8; m > 0; m >>= 1) mx = fmaxf(mx, __shfl_xor(mx, m, 16));
    float ex = __expf(o0 - mx) + __expf(o1 - mx) + __expf(o2 - mx) + __expf(o3 - mx);
    #pragma unroll
    for (int m = 8; m > 0; m >>= 1) ex += __shfl_xor(ex, m, 16);
    float lse = mx + __logf(ex);
    float4 o = make_float4(o0 - lse, o1 - lse, o2 - lse, o3 - lse);
    *(float4*)&out[(size_t)n * OUT_DIM + c0] = o;
}

// ---------------- launch ----------------

extern "C" void kernel_launch(void* const* d_in, const int* in_sizes, int n_in,
                              void* d_out, int out_size, void* d_ws, size_t ws_size,
                              hipStream_t stream) {
    const float* x   = (const float*)d_in[0];
    const int*   ei  = (const int*)d_in[1];
    const float* W1  = (const float*)d_in[2];
    const float* as1 = (const float*)d_in[3];
    const float* ad1 = (const float*)d_in[4];
    const float* b1  = (const float*)d_in[5];
    const float* W2  = (const float*)d_in[6];
    const float* as2 = (const float*)d_in[7];
    const float* ad2 = (const float*)d_in[8];
    const float* b2  = (const float*)d_in[9];
    float* out = (float*)d_out;

    const int* src = ei;             // row 0
    const int* dst = ei + E_EDGES;   // row 1

    char* ws = (char*)d_ws;
    size_t off = 0;
    auto alloc = [&](size_t bytes) -> void* {
        void* p = ws + off;
        off += (bytes + 255) & ~size_t(255);
        return p;
    };
    unsigned short* xb     = (unsigned short*)alloc((size_t)N_NODES * IN_DIM * 2);
    unsigned short* h1b    = (unsigned short*)alloc((size_t)N_NODES * HID * 2);
    unsigned short* h2b    = (unsigned short*)alloc((size_t)N_NODES * OUT_DIM * 2);
    unsigned short* w1t    = (unsigned short*)alloc((size_t)HID * IN_DIM * 2);
    unsigned short* p1t    = (unsigned short*)alloc((size_t)16 * IN_DIM * 2);
    unsigned short* w2t    = (unsigned short*)alloc((size_t)OUT_DIM * HID * 2);
    unsigned short* p2t    = (unsigned short*)alloc((size_t)16 * HID * 2);
    float* a_src1    = (float*)alloc((size_t)N_NODES * HEADS * 4);
    float* a_dst1    = (float*)alloc((size_t)N_NODES * HEADS * 4);
    float* a_src2    = (float*)alloc((size_t)N_NODES * 4);
    float* a_dst2    = (float*)alloc((size_t)N_NODES * 4);
    int*   row_start = (int*)alloc((size_t)(N_NODES + 1) * 4);
    int*   csr_src   = (int*)alloc((size_t)ET * 4);
    uint32* pairs    = (uint32*)alloc((size_t)ET * 4);
    int*   cnt       = (int*)alloc((size_t)NB * NT * 4);
    int*   bucketStart = (int*)alloc((size_t)(NB + 1) * 4);

    prep_all<<<MEGA_A, 256, 0, stream>>>(dst, cnt, x, xb, W1, as1, ad1,
                                         W2, as2, ad2, w1t, p1t, w2t, p2t);
    bucket_scatter<<<NT, 256, 0, stream>>>(src, dst, cnt, bucketStart, pairs);
    build_l1t<<<MEGA_B, 256, 0, stream>>>(pairs, bucketStart, row_start, csr_src,
                                          xb, w1t, p1t, h1b, a_src1, a_dst1);
    l1agg_l2t<<<L1T_BLOCKS, 1024, 0, stream>>>(h1b, a_src1, a_dst1, row_start, csr_src,
                                               b1, w2t, p2t, h2b, a_src2, a_dst2);
    l2_aggregate<<<N_NODES / 8, 128, 0, stream>>>(h2b, a_src2, a_dst2, row_start, csr_src, b2, out);
}

// Round 17
// 212.961 us; speedup vs baseline: 1.0416x; 1.0416x over previous
//
#include <hip/hip_runtime.h>
#include <math.h>

#define N_NODES 50000
#define E_EDGES 800000
#define ET      (E_EDGES + N_NODES)   // edges + self loops
#define IN_DIM  128
#define HID     128
#define HEADS   8
#define C1      16
#define OUT_DIM 64
#define NEG_SLOPE 0.2f
#define LOG2E   1.4426950408889634f

#define TILE    8192
#define NT      ((ET + TILE - 1) / TILE)      // 104 tiles
#define NB      ((N_NODES + 255) / 256)       // 196 buckets of 256 nodes

#define CONV_BLOCKS (N_NODES * IN_DIM / 4 / 256)   // 6250
#define PREP_BLOCKS 112
#define MEGA_A (NT + CONV_BLOCKS + PREP_BLOCKS)    // 6466
#define L1T_BLOCKS ((N_NODES + 63) / 64)           // 782
#define MEGA_B (NB + L1T_BLOCKS)                   // 978
#define FUSE_BLOCKS ((N_NODES + 31) / 32)          // 1563

typedef unsigned int uint32;
typedef __attribute__((ext_vector_type(8))) short bf16x8;
typedef __attribute__((ext_vector_type(4))) float f32x4;

static __device__ __forceinline__ unsigned short f2bf(float f) {
    uint32 u = __float_as_uint(f);
    u += 0x7FFFu + ((u >> 16) & 1u);   // round to nearest even
    return (unsigned short)(u >> 16);
}

// ---------------- Mega-kernel A: bucket_hist + convert_x + prep_weights ----------------

__global__ __launch_bounds__(256) void prep_all(
        const int* __restrict__ dst, int* __restrict__ cnt,
        const float* __restrict__ x, unsigned short* __restrict__ xb,
        const float* __restrict__ W1, const float* __restrict__ as1,
        const float* __restrict__ ad1, const float* __restrict__ W2,
        const float* __restrict__ as2, const float* __restrict__ ad2,
        unsigned short* __restrict__ w1t, unsigned short* __restrict__ p1t,
        unsigned short* __restrict__ w2t, unsigned short* __restrict__ p2t) {
    __shared__ int hist[NB];
    int blk = blockIdx.x, t = threadIdx.x;
    if (blk < NT) {
        for (int b = t; b < NB; b += 256) hist[b] = 0;
        __syncthreads();
        int base = blk * TILE;
        #pragma unroll
        for (int it = 0; it < TILE / 256; ++it) {
            int i = base + it * 256 + t;
            if (i < ET) {
                int d = (i < E_EDGES) ? dst[i] : (i - E_EDGES);
                atomicAdd(&hist[d >> 8], 1);
            }
        }
        __syncthreads();
        for (int b = t; b < NB; b += 256) cnt[blk * NB + b] = hist[b];
    } else if (blk < NT + CONV_BLOCKS) {
        int i = (blk - NT) * 256 + t;
        float4 v = ((const float4*)x)[i];
        ushort4 o;
        o.x = f2bf(v.x); o.y = f2bf(v.y); o.z = f2bf(v.z); o.w = f2bf(v.w);
        ((ushort4*)xb)[i] = o;
    } else {
        int b = blk - NT - CONV_BLOCKS;    // 0..111
        if (b < 64) {
            int i = b * 256 + t;                // n*128+k
            int n = i >> 7, k = i & 127;
            w1t[n * IN_DIM + k] = f2bf(W1[k * HID + n]);
        } else if (b < 96) {
            int i = (b - 64) * 256 + t;         // n*128+k, n<64
            int n = i >> 7, k = i & 127;
            w2t[n * HID + k] = f2bf(W2[k * OUT_DIM + n]);
        } else if (b < 104) {
            int i = (b - 96) * 256 + t;         // j*128+k, j<16
            int j = i >> 7, k = i & 127;
            int hh = j & 7;
            const float* a = (j < 8) ? as1 : ad1;
            float acc = 0.f;
            #pragma unroll
            for (int c = 0; c < C1; ++c)
                acc = fmaf(W1[k * HID + hh * C1 + c], a[hh * C1 + c], acc);
            p1t[j * IN_DIM + k] = f2bf(acc * LOG2E);
        } else {
            int i = (b - 104) * 256 + t;        // j*128+k, j<16
            int j = i >> 7, k = i & 127;
            if (j < 2) {
                const float* a = (j == 0) ? as2 : ad2;
                float acc = 0.f;
                #pragma unroll
                for (int c = 0; c < OUT_DIM; ++c)
                    acc = fmaf(W2[k * OUT_DIM + c], a[c], acc);
                p2t[j * HID + k] = f2bf(acc * LOG2E);
            } else {
                p2t[j * HID + k] = 0;
            }
        }
    }
}

// ---------------- bucket_scatter (scan fused in) ----------------

__global__ __launch_bounds__(256) void bucket_scatter(
        const int* __restrict__ src, const int* __restrict__ dst,
        const int* __restrict__ cnt, int* __restrict__ bucketStart,
        uint32* __restrict__ pairs) {
    __shared__ int lcur[NB];
    __shared__ int sscan[256];
    int t = threadIdx.x;
    int tile = blockIdx.x;

    int run = 0, total = 0;
    if (t < NB) {
        for (int k = 0; k < NT; ++k) {
            int c = cnt[k * NB + t];     // coalesced across t
            if (k < tile) run += c;
            total += c;
        }
    }
    sscan[t] = (t < NB) ? total : 0;
    __syncthreads();
    #pragma unroll
    for (int off = 1; off < 256; off <<= 1) {
        int add = (t >= off) ? sscan[t - off] : 0;
        __syncthreads();
        sscan[t] += add;
        __syncthreads();
    }
    int bstart = sscan[t] - total;       // exclusive prefix
    if (t < NB) {
        lcur[t] = bstart + run;
        if (tile == 0) bucketStart[t] = bstart;
    }
    if (tile == 0 && t == 0) bucketStart[NB] = ET;
    __syncthreads();

    int base = tile * TILE;
    #pragma unroll
    for (int it = 0; it < TILE / 256; ++it) {
        int i = base + it * 256 + t;
        if (i < ET) {
            int s, d;
            if (i < E_EDGES) { s = src[i]; d = dst[i]; }
            else             { s = d = i - E_EDGES; }
            int pos = atomicAdd(&lcur[d >> 8], 1);
            pairs[pos] = ((uint32)s << 8) | (uint32)(d & 255);
        }
    }
}

// ---------------- Mega-kernel B: bucket_build + l1_transform_mfma ----------------

__global__ __launch_bounds__(256) void build_l1t(
        const uint32* __restrict__ pairs, const int* __restrict__ bucketStart,
        int* __restrict__ row_start, int* __restrict__ csr_src,
        const unsigned short* __restrict__ xb, const unsigned short* __restrict__ w1t,
        const unsigned short* __restrict__ p1t, unsigned short* __restrict__ h1b,
        float* __restrict__ a_src, float* __restrict__ a_dst) {
    __shared__ int sdeg[256];
    __shared__ int sscan[256];
    int t = threadIdx.x;
    if (blockIdx.x < NB) {
        int b = blockIdx.x;
        int beg = bucketStart[b], end = bucketStart[b + 1];
        sdeg[t] = 0;
        __syncthreads();
        for (int j = beg + t; j < end; j += 256)
            atomicAdd(&sdeg[pairs[j] & 255u], 1);
        __syncthreads();
        int v = sdeg[t];
        sscan[t] = v;
        __syncthreads();
        #pragma unroll
        for (int off = 1; off < 256; off <<= 1) {
            int add = (t >= off) ? sscan[t - off] : 0;
            __syncthreads();
            sscan[t] += add;
            __syncthreads();
        }
        int pos0 = beg + sscan[t] - v;   // exclusive prefix within bucket
        int n = b * 256 + t;
        if (n < N_NODES) row_start[n] = pos0;
        if (b == 0 && t == 0) row_start[N_NODES] = ET;
        __syncthreads();
        sscan[t] = pos0;                 // reuse as cursor
        __syncthreads();
        for (int j = beg + t; j < end; j += 256) {
            uint32 p = pairs[j];
            int pos = atomicAdd(&sscan[p & 255u], 1);
            csr_src[pos] = (int)(p >> 8);
        }
        return;
    }
    // ---- layer-1 transform via MFMA, LDS-free ----
    int bb = blockIdx.x - NB;
    int w = t >> 6, lane = t & 63;
    int l15 = lane & 15, quad = lane >> 4;
    int n0 = bb * 64 + w * 16;
    int mrow = n0 + l15;
    int mload = (mrow < N_NODES) ? mrow : (N_NODES - 1);

    bf16x8 af[4];
    #pragma unroll
    for (int s = 0; s < 4; ++s)
        af[s] = *(const bf16x8*)&xb[(size_t)mload * IN_DIM + s * 32 + quad * 8];

    #pragma unroll
    for (int tt = 0; tt < 9; ++tt) {
        const unsigned short* Brow = (tt < 8) ? &w1t[(tt * 16 + l15) * IN_DIM]
                                              : &p1t[l15 * IN_DIM];
        f32x4 acc = {0.f, 0.f, 0.f, 0.f};
        #pragma unroll
        for (int s = 0; s < 4; ++s) {
            bf16x8 bf = *(const bf16x8*)&Brow[s * 32 + quad * 8];
            acc = __builtin_amdgcn_mfma_f32_16x16x32_bf16(af[s], bf, acc, 0, 0, 0);
        }
        int nodeb = n0 + quad * 4;
        if (tt < 8) {
            int ch = tt * 16 + l15;
            #pragma unroll
            for (int r = 0; r < 4; ++r)
                if (nodeb + r < N_NODES)
                    h1b[(size_t)(nodeb + r) * HID + ch] = f2bf(acc[r]);
        } else {
            #pragma unroll
            for (int r = 0; r < 4; ++r) {
                if (nodeb + r < N_NODES) {
                    if (l15 < 8) a_src[(nodeb + r) * HEADS + l15] = acc[r];
                    else         a_dst[(nodeb + r) * HEADS + (l15 - 8)] = acc[r];
                }
            }
        }
    }
}

// ---------------- Fused: layer-1 aggregate + layer-2 transform ----------------
// 512-thread block (8 waves) covers 32 nodes. Phase A: each wave aggregates
// 4 nodes in ONE pass (16 lanes/node, 8 bf16 ch/lane, uint4 gathers) -> full
// wave parallelism (12.5k waves) AND 4 blocks/CU co-residency (32 waves/CU).
// h_act lives in LDS (8 KB, XOR-swizzled granules). Phase B: wave
// (rg = w>>2, u = w&3) MFMAs output tile tt=u for row group rg; u==0 also
// does the tt=4 attention tile.

__global__ __launch_bounds__(512) void l1agg_l2t(
        const unsigned short* __restrict__ h1b, const float* __restrict__ a_src,
        const float* __restrict__ a_dst, const int* __restrict__ row_start,
        const int* __restrict__ csr_src, const float* __restrict__ b1,
        const unsigned short* __restrict__ w2t, const unsigned short* __restrict__ p2t,
        unsigned short* __restrict__ h2b, float* __restrict__ a_src2,
        float* __restrict__ a_dst2) {
    __shared__ unsigned short ha[32][128];   // 8 KB, swizzled granules
    int t = threadIdx.x;
    int w = t >> 6;              // 0..7
    uint32 lane = t & 63;
    uint32 quarter = lane >> 4;
    uint32 lane16 = lane & 15;
    int n0blk = blockIdx.x * 32;

    // ---------- phase A: 8 waves x 4 nodes (one pass) ----------
    {
        uint32 c0 = lane16 * 8u;     // 8 channels per lane
        uint32 h = lane16 >> 1;      // head = c0 >> 4
        int n_local = w * 4 + (int)quarter;
        int n = n0blk + n_local;
        int nc = (n < N_NODES) ? n : (N_NODES - 1);
        int beg = row_start[nc], end = row_start[nc + 1];
        int cnt = end - beg;
        int kmax = cnt;
        kmax = max(kmax, __shfl_xor(kmax, 16, 64));
        kmax = max(kmax, __shfl_xor(kmax, 32, 64));
        float adst = a_dst[nc * HEADS + h];
        float l = 0.f;
        float a0 = 0.f, a1 = 0.f, a2 = 0.f, a3 = 0.f;
        float a4 = 0.f, a5 = 0.f, a6 = 0.f, a7 = 0.f;

        for (int k = 0; k < kmax; k += 4) {
            uint32 ss[4]; float ee[4]; uint4 uu[4];
            #pragma unroll
            for (int q = 0; q < 4; ++q) {
                int j = beg + k + q;
                int jc = (j < end) ? j : (end - 1);    // cnt >= 1 (self loop)
                ss[q] = (uint32)csr_src[jc];
            }
            #pragma unroll
            for (int q = 0; q < 4; ++q) ee[q] = a_src[ss[q] * 8u + h];
            #pragma unroll
            for (int q = 0; q < 4; ++q) uu[q] = *(const uint4*)&h1b[(ss[q] << 7) + c0];
            #pragma unroll
            for (int q = 0; q < 4; ++q) {
                float e = ee[q] + adst;
                e = fmaxf(e, NEG_SLOPE * e);          // leaky relu (log2 domain)
                e = (k + q < cnt) ? e : -10000.f;     // masked lane -> p = 0
                float p = exp2f(e);
                l += p;
                a0 = fmaf(p, __uint_as_float(uu[q].x << 16), a0);
                a1 = fmaf(p, __uint_as_float(uu[q].x & 0xFFFF0000u), a1);
                a2 = fmaf(p, __uint_as_float(uu[q].y << 16), a2);
                a3 = fmaf(p, __uint_as_float(uu[q].y & 0xFFFF0000u), a3);
                a4 = fmaf(p, __uint_as_float(uu[q].z << 16), a4);
                a5 = fmaf(p, __uint_as_float(uu[q].z & 0xFFFF0000u), a5);
                a6 = fmaf(p, __uint_as_float(uu[q].w << 16), a6);
                a7 = fmaf(p, __uint_as_float(uu[q].w & 0xFFFF0000u), a7);
            }
        }

        float inv = 1.f / (l + 1e-16f);
        float v0 = a0 * inv + b1[c0 + 0];
        float v1 = a1 * inv + b1[c0 + 1];
        float v2 = a2 * inv + b1[c0 + 2];
        float v3 = a3 * inv + b1[c0 + 3];
        float v4 = a4 * inv + b1[c0 + 4];
        float v5 = a5 * inv + b1[c0 + 5];
        float v6 = a6 * inv + b1[c0 + 6];
        float v7 = a7 * inv + b1[c0 + 7];
        v0 = v0 > 0.f ? v0 : (__expf(v0) - 1.f);   // ELU
        v1 = v1 > 0.f ? v1 : (__expf(v1) - 1.f);
        v2 = v2 > 0.f ? v2 : (__expf(v2) - 1.f);
        v3 = v3 > 0.f ? v3 : (__expf(v3) - 1.f);
        v4 = v4 > 0.f ? v4 : (__expf(v4) - 1.f);
        v5 = v5 > 0.f ? v5 : (__expf(v5) - 1.f);
        v6 = v6 > 0.f ? v6 : (__expf(v6) - 1.f);
        v7 = v7 > 0.f ? v7 : (__expf(v7) - 1.f);
        uint4 packed;
        packed.x = (uint32)f2bf(v0) | ((uint32)f2bf(v1) << 16);
        packed.y = (uint32)f2bf(v2) | ((uint32)f2bf(v3) << 16);
        packed.z = (uint32)f2bf(v4) | ((uint32)f2bf(v5) << 16);
        packed.w = (uint32)f2bf(v6) | ((uint32)f2bf(v7) << 16);
        uint32 g = lane16 ^ ((uint32)n_local & 15u);   // swizzled granule
        *(uint4*)&ha[n_local][g * 8] = packed;
    }
    __syncthreads();

    // ---------- phase B: layer-2 transform from LDS, tt split across waves ----------
    {
        int rg = w >> 2, u = w & 3;
        int l15 = (int)lane16, quad = (int)quarter;
        int n0 = n0blk + rg * 16;
        int nloc = rg * 16 + l15;

        bf16x8 af[4];
        #pragma unroll
        for (int s = 0; s < 4; ++s) {
            uint32 g = (uint32)(s * 4 + quad) ^ (uint32)l15;
            af[s] = *(const bf16x8*)&ha[nloc][g * 8];
        }

        #pragma unroll
        for (int pass = 0; pass < 2; ++pass) {
            if (pass == 1 && u != 0) break;
            int tt = (pass == 0) ? u : 4;
            const unsigned short* Brow = (tt < 4) ? &w2t[(tt * 16 + l15) * HID]
                                                  : &p2t[l15 * HID];
            f32x4 acc = {0.f, 0.f, 0.f, 0.f};
            #pragma unroll
            for (int s = 0; s < 4; ++s) {
                bf16x8 bf = *(const bf16x8*)&Brow[s * 32 + quad * 8];
                acc = __builtin_amdgcn_mfma_f32_16x16x32_bf16(af[s], bf, acc, 0, 0, 0);
            }
            int nodeb = n0 + quad * 4;
            if (tt < 4) {
                int ch = tt * 16 + l15;
                #pragma unroll
                for (int r = 0; r < 4; ++r)
                    if (nodeb + r < N_NODES)
                        h2b[(size_t)(nodeb + r) * OUT_DIM + ch] = f2bf(acc[r]);
            } else {
                #pragma unroll
                for (int r = 0; r < 4; ++r) {
                    if (nodeb + r < N_NODES) {
                        if (l15 == 0) a_src2[nodeb + r] = acc[r];
                        else if (l15 == 1) a_dst2[nodeb + r] = acc[r];
                    }
                }
            }
        }
    }
}

// ---------------- Layer 2: aggregate + log_softmax ----------------
// 4 nodes per wave: 16 lanes per node, 4 channels/lane (uint2 gathers).

__global__ __launch_bounds__(128) void l2_aggregate(
        const unsigned short* __restrict__ h2b, const float* __restrict__ a_src2,
        const float* __restrict__ a_dst2, const int* __restrict__ row_start,
        const int* __restrict__ csr_src, const float* __restrict__ b2,
        float* __restrict__ out) {
    int t = threadIdx.x;
    int w = t >> 6;
    uint32 lane = t & 63;
    uint32 quarter = lane >> 4;
    uint32 lane16 = lane & 15;
    int n = blockIdx.x * 8 + w * 4 + (int)quarter;
    uint32 c0 = lane16 * 4u;
    int beg = row_start[n], end = row_start[n + 1];
    int cnt = end - beg;
    int kmax = cnt;
    kmax = max(kmax, __shfl_xor(kmax, 16, 64));
    kmax = max(kmax, __shfl_xor(kmax, 32, 64));
    float adst = a_dst2[n];
    float l = 0.f, a0 = 0.f, a1 = 0.f, a2 = 0.f, a3 = 0.f;

    for (int k = 0; k < kmax; k += 4) {
        uint32 ss[4]; float ee[4]; uint2 uu[4];
        #pragma unroll
        for (int q = 0; q < 4; ++q) {
            int j = beg + k + q;
            int jc = (j < end) ? j : (end - 1);
            ss[q] = (uint32)csr_src[jc];
        }
        #pragma unroll
        for (int q = 0; q < 4; ++q) ee[q] = a_src2[ss[q]];
        #pragma unroll
        for (int q = 0; q < 4; ++q) uu[q] = *(const uint2*)&h2b[(ss[q] << 6) + c0];
        #pragma unroll
        for (int q = 0; q < 4; ++q) {
            float e = ee[q] + adst;
            e = fmaxf(e, NEG_SLOPE * e);
            e = (k + q < cnt) ? e : -10000.f;   // masked lane -> p = 0
            float p = exp2f(e);
            l += p;
            a0 = fmaf(p, __uint_as_float(uu[q].x << 16), a0);
            a1 = fmaf(p, __uint_as_float(uu[q].x & 0xFFFF0000u), a1);
            a2 = fmaf(p, __uint_as_float(uu[q].y << 16), a2);
            a3 = fmaf(p, __uint_as_float(uu[q].y & 0xFFFF0000u), a3);
        }
    }

    float inv = 1.f / (l + 1e-16f);
    float o0 = a0 * inv + b2[c0 + 0];
    float o1 = a1 * inv + b2[c0 + 1];
    float o2 = a2 * inv + b2[c0 + 2];
    float o3 = a3 * inv + b2[c0 + 3];
    // log_softmax over 64 channels = 16 lanes x 4 (quarter-wave reduction)
    float mx = fmaxf(fmaxf(o0, o1), fmaxf(o2, o3));
    #pragma unroll
    for (int m = 8; m > 0; m >>= 1) mx = fmaxf(mx, __shfl_xor(mx, m, 16));
    float ex = __expf(o0 - mx) + __expf(o1 - mx) + __expf(o2 - mx) + __expf(o3 - mx);
    #pragma unroll
    for (int m = 8; m > 0; m >>= 1) ex += __shfl_xor(ex, m, 16);
    float lse = mx + __logf(ex);
    float4 o = make_float4(o0 - lse, o1 - lse, o2 - lse, o3 - lse);
    *(float4*)&out[(size_t)n * OUT_DIM + c0] = o;
}

// ---------------- launch ----------------

extern "C" void kernel_launch(void* const* d_in, const int* in_sizes, int n_in,
                              void* d_out, int out_size, void* d_ws, size_t ws_size,
                              hipStream_t stream) {
    const float* x   = (const float*)d_in[0];
    const int*   ei  = (const int*)d_in[1];
    const float* W1  = (const float*)d_in[2];
    const float* as1 = (const float*)d_in[3];
    const float* ad1 = (const float*)d_in[4];
    const float* b1  = (const float*)d_in[5];
    const float* W2  = (const float*)d_in[6];
    const float* as2 = (const float*)d_in[7];
    const float* ad2 = (const float*)d_in[8];
    const float* b2  = (const float*)d_in[9];
    float* out = (float*)d_out;

    const int* src = ei;             // row 0
    const int* dst = ei + E_EDGES;   // row 1

    char* ws = (char*)d_ws;
    size_t off = 0;
    auto alloc = [&](size_t bytes) -> void* {
        void* p = ws + off;
        off += (bytes + 255) & ~size_t(255);
        return p;
    };
    unsigned short* xb     = (unsigned short*)alloc((size_t)N_NODES * IN_DIM * 2);
    unsigned short* h1b    = (unsigned short*)alloc((size_t)N_NODES * HID * 2);
    unsigned short* h2b    = (unsigned short*)alloc((size_t)N_NODES * OUT_DIM * 2);
    unsigned short* w1t    = (unsigned short*)alloc((size_t)HID * IN_DIM * 2);
    unsigned short* p1t    = (unsigned short*)alloc((size_t)16 * IN_DIM * 2);
    unsigned short* w2t    = (unsigned short*)alloc((size_t)OUT_DIM * HID * 2);
    unsigned short* p2t    = (unsigned short*)alloc((size_t)16 * HID * 2);
    float* a_src1    = (float*)alloc((size_t)N_NODES * HEADS * 4);
    float* a_dst1    = (float*)alloc((size_t)N_NODES * HEADS * 4);
    float* a_src2    = (float*)alloc((size_t)N_NODES * 4);
    float* a_dst2    = (float*)alloc((size_t)N_NODES * 4);
    int*   row_start = (int*)alloc((size_t)(N_NODES + 1) * 4);
    int*   csr_src   = (int*)alloc((size_t)ET * 4);
    uint32* pairs    = (uint32*)alloc((size_t)ET * 4);
    int*   cnt       = (int*)alloc((size_t)NB * NT * 4);
    int*   bucketStart = (int*)alloc((size_t)(NB + 1) * 4);

    prep_all<<<MEGA_A, 256, 0, stream>>>(dst, cnt, x, xb, W1, as1, ad1,
                                         W2, as2, ad2, w1t, p1t, w2t, p2t);
    bucket_scatter<<<NT, 256, 0, stream>>>(src, dst, cnt, bucketStart, pairs);
    build_l1t<<<MEGA_B, 256, 0, stream>>>(pairs, bucketStart, row_start, csr_src,
                                          xb, w1t, p1t, h1b, a_src1, a_dst1);
    l1agg_l2t<<<FUSE_BLOCKS, 512, 0, stream>>>(h1b, a_src1, a_dst1, row_start, csr_src,
                                               b1, w2t, p2t, h2b, a_src2, a_dst2);
    l2_aggregate<<<N_NODES / 8, 128, 0, stream>>>(h2b, a_src2, a_dst2, row_start, csr_src, b2, out);
}

// Round 18
// 211.388 us; speedup vs baseline: 1.0494x; 1.0074x over previous
//
#include <hip/hip_runtime.h>
#include <math.h>

#define N_NODES 50000
#define E_EDGES 800000
#define ET      (E_EDGES + N_NODES)   // edges + self loops
#define IN_DIM  128
#define HID     128
#define HEADS   8
#define C1      16
#define OUT_DIM 64
#define NEG_SLOPE 0.2f
#define LOG2E   1.4426950408889634f

#define TILE    8192
#define NT      ((ET + TILE - 1) / TILE)      // 104 tiles
#define NB      ((N_NODES + 255) / 256)       // 196 buckets of 256 nodes

#define CONV_BLOCKS (N_NODES * IN_DIM / 4 / 256)   // 6250
#define PREP_BLOCKS 112
#define MEGA_A (NT + CONV_BLOCKS + PREP_BLOCKS)    // 6466
#define L1T_BLOCKS ((N_NODES + 63) / 64)           // 782
#define MEGA_B (NB + L1T_BLOCKS)                   // 978

typedef unsigned int uint32;
typedef __attribute__((ext_vector_type(8))) short bf16x8;
typedef __attribute__((ext_vector_type(4))) float f32x4;

static __device__ __forceinline__ unsigned short f2bf(float f) {
    uint32 u = __float_as_uint(f);
    u += 0x7FFFu + ((u >> 16) & 1u);   // round to nearest even
    return (unsigned short)(u >> 16);
}

// ---------------- Mega-kernel A: bucket_hist + convert_x + prep_weights ----------------

__global__ __launch_bounds__(256) void prep_all(
        const int* __restrict__ dst, int* __restrict__ cnt,
        const float* __restrict__ x, unsigned short* __restrict__ xb,
        const float* __restrict__ W1, const float* __restrict__ as1,
        const float* __restrict__ ad1, const float* __restrict__ W2,
        const float* __restrict__ as2, const float* __restrict__ ad2,
        unsigned short* __restrict__ w1t, unsigned short* __restrict__ p1t,
        unsigned short* __restrict__ w2t, unsigned short* __restrict__ p2t) {
    __shared__ int hist[NB];
    int blk = blockIdx.x, t = threadIdx.x;
    if (blk < NT) {
        for (int b = t; b < NB; b += 256) hist[b] = 0;
        __syncthreads();
        int base = blk * TILE;
        #pragma unroll
        for (int it = 0; it < TILE / 256; ++it) {
            int i = base + it * 256 + t;
            if (i < ET) {
                int d = (i < E_EDGES) ? dst[i] : (i - E_EDGES);
                atomicAdd(&hist[d >> 8], 1);
            }
        }
        __syncthreads();
        for (int b = t; b < NB; b += 256) cnt[blk * NB + b] = hist[b];
    } else if (blk < NT + CONV_BLOCKS) {
        int i = (blk - NT) * 256 + t;
        float4 v = ((const float4*)x)[i];
        ushort4 o;
        o.x = f2bf(v.x); o.y = f2bf(v.y); o.z = f2bf(v.z); o.w = f2bf(v.w);
        ((ushort4*)xb)[i] = o;
    } else {
        int b = blk - NT - CONV_BLOCKS;    // 0..111
        if (b < 64) {
            int i = b * 256 + t;                // n*128+k
            int n = i >> 7, k = i & 127;
            w1t[n * IN_DIM + k] = f2bf(W1[k * HID + n]);
        } else if (b < 96) {
            int i = (b - 64) * 256 + t;         // n*128+k, n<64
            int n = i >> 7, k = i & 127;
            w2t[n * HID + k] = f2bf(W2[k * OUT_DIM + n]);
        } else if (b < 104) {
            int i = (b - 96) * 256 + t;         // j*128+k, j<16
            int j = i >> 7, k = i & 127;
            int hh = j & 7;
            const float* a = (j < 8) ? as1 : ad1;
            float acc = 0.f;
            #pragma unroll
            for (int c = 0; c < C1; ++c)
                acc = fmaf(W1[k * HID + hh * C1 + c], a[hh * C1 + c], acc);
            p1t[j * IN_DIM + k] = f2bf(acc * LOG2E);
        } else {
            int i = (b - 104) * 256 + t;        // j*128+k, j<16
            int j = i >> 7, k = i & 127;
            if (j < 2) {
                const float* a = (j == 0) ? as2 : ad2;
                float acc = 0.f;
                #pragma unroll
                for (int c = 0; c < OUT_DIM; ++c)
                    acc = fmaf(W2[k * OUT_DIM + c], a[c], acc);
                p2t[j * HID + k] = f2bf(acc * LOG2E);
            } else {
                p2t[j * HID + k] = 0;
            }
        }
    }
}

// ---------------- bucket_scatter (scan fused in) ----------------

__global__ __launch_bounds__(256) void bucket_scatter(
        const int* __restrict__ src, const int* __restrict__ dst,
        const int* __restrict__ cnt, int* __restrict__ bucketStart,
        uint32* __restrict__ pairs) {
    __shared__ int lcur[NB];
    __shared__ int sscan[256];
    int t = threadIdx.x;
    int tile = blockIdx.x;

    int run = 0, total = 0;
    if (t < NB) {
        for (int k = 0; k < NT; ++k) {
            int c = cnt[k * NB + t];     // coalesced across t
            if (k < tile) run += c;
            total += c;
        }
    }
    sscan[t] = (t < NB) ? total : 0;
    __syncthreads();
    #pragma unroll
    for (int off = 1; off < 256; off <<= 1) {
        int add = (t >= off) ? sscan[t - off] : 0;
        __syncthreads();
        sscan[t] += add;
        __syncthreads();
    }
    int bstart = sscan[t] - total;       // exclusive prefix
    if (t < NB) {
        lcur[t] = bstart + run;
        if (tile == 0) bucketStart[t] = bstart;
    }
    if (tile == 0 && t == 0) bucketStart[NB] = ET;
    __syncthreads();

    int base = tile * TILE;
    #pragma unroll
    for (int it = 0; it < TILE / 256; ++it) {
        int i = base + it * 256 + t;
        if (i < ET) {
            int s, d;
            if (i < E_EDGES) { s = src[i]; d = dst[i]; }
            else             { s = d = i - E_EDGES; }
            int pos = atomicAdd(&lcur[d >> 8], 1);
            pairs[pos] = ((uint32)s << 8) | (uint32)(d & 255);
        }
    }
}

// ---------------- Mega-kernel B: bucket_build + l1_transform_mfma ----------------

__global__ __launch_bounds__(256) void build_l1t(
        const uint32* __restrict__ pairs, const int* __restrict__ bucketStart,
        int* __restrict__ row_start, int* __restrict__ csr_src,
        const unsigned short* __restrict__ xb, const unsigned short* __restrict__ w1t,
        const unsigned short* __restrict__ p1t, unsigned short* __restrict__ h1b,
        float* __restrict__ a_src, float* __restrict__ a_dst) {
    __shared__ int sdeg[256];
    __shared__ int sscan[256];
    int t = threadIdx.x;
    if (blockIdx.x < NB) {
        int b = blockIdx.x;
        int beg = bucketStart[b], end = bucketStart[b + 1];
        sdeg[t] = 0;
        __syncthreads();
        for (int j = beg + t; j < end; j += 256)
            atomicAdd(&sdeg[pairs[j] & 255u], 1);
        __syncthreads();
        int v = sdeg[t];
        sscan[t] = v;
        __syncthreads();
        #pragma unroll
        for (int off = 1; off < 256; off <<= 1) {
            int add = (t >= off) ? sscan[t - off] : 0;
            __syncthreads();
            sscan[t] += add;
            __syncthreads();
        }
        int pos0 = beg + sscan[t] - v;   // exclusive prefix within bucket
        int n = b * 256 + t;
        if (n < N_NODES) row_start[n] = pos0;
        if (b == 0 && t == 0) row_start[N_NODES] = ET;
        __syncthreads();
        sscan[t] = pos0;                 // reuse as cursor
        __syncthreads();
        for (int j = beg + t; j < end; j += 256) {
            uint32 p = pairs[j];
            int pos = atomicAdd(&sscan[p & 255u], 1);
            csr_src[pos] = (int)(p >> 8);
        }
        return;
    }
    // ---- layer-1 transform via MFMA, LDS-free ----
    int bb = blockIdx.x - NB;
    int w = t >> 6, lane = t & 63;
    int l15 = lane & 15, quad = lane >> 4;
    int n0 = bb * 64 + w * 16;
    int mrow = n0 + l15;
    int mload = (mrow < N_NODES) ? mrow : (N_NODES - 1);

    bf16x8 af[4];
    #pragma unroll
    for (int s = 0; s < 4; ++s)
        af[s] = *(const bf16x8*)&xb[(size_t)mload * IN_DIM + s * 32 + quad * 8];

    #pragma unroll
    for (int tt = 0; tt < 9; ++tt) {
        const unsigned short* Brow = (tt < 8) ? &w1t[(tt * 16 + l15) * IN_DIM]
                                              : &p1t[l15 * IN_DIM];
        f32x4 acc = {0.f, 0.f, 0.f, 0.f};
        #pragma unroll
        for (int s = 0; s < 4; ++s) {
            bf16x8 bf = *(const bf16x8*)&Brow[s * 32 + quad * 8];
            acc = __builtin_amdgcn_mfma_f32_16x16x32_bf16(af[s], bf, acc, 0, 0, 0);
        }
        int nodeb = n0 + quad * 4;
        if (tt < 8) {
            int ch = tt * 16 + l15;
            #pragma unroll
            for (int r = 0; r < 4; ++r)
                if (nodeb + r < N_NODES)
                    h1b[(size_t)(nodeb + r) * HID + ch] = f2bf(acc[r]);
        } else {
            #pragma unroll
            for (int r = 0; r < 4; ++r) {
                if (nodeb + r < N_NODES) {
                    if (l15 < 8) a_src[(nodeb + r) * HEADS + l15] = acc[r];
                    else         a_dst[(nodeb + r) * HEADS + (l15 - 8)] = acc[r];
                }
            }
        }
    }
}

// ---------------- Fused: layer-1 aggregate + layer-2 transform ----------------
// 256-thread block covers 64 nodes (r15 base). NEW: nodes are rank-sorted by
// degree within the tile; work unit u = pass*4+w handles rank-adjacent nodes
// perm[4u..4u+3] so kmax ~= deg (masked-lane waste removed) and wave loads
// balance. h_act lives in LDS (16 KB, XOR-swizzled granules); phase B MFMAs
// from LDS. Per-node math identical -> bitwise-same output.

__global__ __launch_bounds__(256) void l1agg_l2t(
        const unsigned short* __restrict__ h1b, const float* __restrict__ a_src,
        const float* __restrict__ a_dst, const int* __restrict__ row_start,
        const int* __restrict__ csr_src, const float* __restrict__ b1,
        const unsigned short* __restrict__ w2t, const unsigned short* __restrict__ p2t,
        unsigned short* __restrict__ h2b, float* __restrict__ a_src2,
        float* __restrict__ a_dst2) {
    __shared__ unsigned short ha[64][128];   // 16 KB, swizzled granules
    __shared__ int sdeg64[64];
    __shared__ unsigned char perm[64];
    int t = threadIdx.x;
    int w = t >> 6;
    uint32 lane = t & 63;
    uint32 quarter = lane >> 4;
    uint32 lane16 = lane & 15;
    int n0blk = blockIdx.x * 64;

    // ---- degree-rank the 64 nodes (once per block) ----
    if (t < 64) {
        int n = n0blk + t;
        int nc = (n < N_NODES) ? n : (N_NODES - 1);
        sdeg64[t] = row_start[nc + 1] - row_start[nc];
    }
    __syncthreads();
    if (t < 64) {
        int d = sdeg64[t];
        int r = 0;
        for (int j = 0; j < 64; ++j) {
            int dj = sdeg64[j];
            r += (dj < d) || (dj == d && j < t);
        }
        perm[r] = (unsigned char)t;
    }
    __syncthreads();

    // ---------- phase A: aggregate 64 nodes into LDS (rank-grouped) ----------
    {
        uint32 c0 = lane16 * 8u;     // 8 channels per lane
        uint32 h = lane16 >> 1;      // head = c0 >> 4
        #pragma unroll
        for (int pass = 0; pass < 4; ++pass) {
            int u = pass * 4 + w;                       // work unit 0..15
            int n_local = (int)perm[u * 4 + (int)quarter];
            int n = n0blk + n_local;
            int nc = (n < N_NODES) ? n : (N_NODES - 1);
            int beg = row_start[nc], end = row_start[nc + 1];
            int cnt = end - beg;
            int kmax = cnt;
            kmax = max(kmax, __shfl_xor(kmax, 16, 64));
            kmax = max(kmax, __shfl_xor(kmax, 32, 64));
            float adst = a_dst[nc * HEADS + h];
            float l = 0.f;
            float a0 = 0.f, a1 = 0.f, a2 = 0.f, a3 = 0.f;
            float a4 = 0.f, a5 = 0.f, a6 = 0.f, a7 = 0.f;

            for (int k = 0; k < kmax; k += 4) {
                uint32 ss[4]; float ee[4]; uint4 uu[4];
                #pragma unroll
                for (int q = 0; q < 4; ++q) {
                    int j = beg + k + q;
                    int jc = (j < end) ? j : (end - 1);    // cnt >= 1 (self loop)
                    ss[q] = (uint32)csr_src[jc];
                }
                #pragma unroll
                for (int q = 0; q < 4; ++q) ee[q] = a_src[ss[q] * 8u + h];
                #pragma unroll
                for (int q = 0; q < 4; ++q) uu[q] = *(const uint4*)&h1b[(ss[q] << 7) + c0];
                #pragma unroll
                for (int q = 0; q < 4; ++q) {
                    float e = ee[q] + adst;
                    e = fmaxf(e, NEG_SLOPE * e);          // leaky relu (log2 domain)
                    e = (k + q < cnt) ? e : -10000.f;     // masked lane -> p = 0
                    float p = exp2f(e);
                    l += p;
                    a0 = fmaf(p, __uint_as_float(uu[q].x << 16), a0);
                    a1 = fmaf(p, __uint_as_float(uu[q].x & 0xFFFF0000u), a1);
                    a2 = fmaf(p, __uint_as_float(uu[q].y << 16), a2);
                    a3 = fmaf(p, __uint_as_float(uu[q].y & 0xFFFF0000u), a3);
                    a4 = fmaf(p, __uint_as_float(uu[q].z << 16), a4);
                    a5 = fmaf(p, __uint_as_float(uu[q].z & 0xFFFF0000u), a5);
                    a6 = fmaf(p, __uint_as_float(uu[q].w << 16), a6);
                    a7 = fmaf(p, __uint_as_float(uu[q].w & 0xFFFF0000u), a7);
                }
            }

            float inv = 1.f / (l + 1e-16f);
            float v0 = a0 * inv + b1[c0 + 0];
            float v1 = a1 * inv + b1[c0 + 1];
            float v2 = a2 * inv + b1[c0 + 2];
            float v3 = a3 * inv + b1[c0 + 3];
            float v4 = a4 * inv + b1[c0 + 4];
            float v5 = a5 * inv + b1[c0 + 5];
            float v6 = a6 * inv + b1[c0 + 6];
            float v7 = a7 * inv + b1[c0 + 7];
            v0 = v0 > 0.f ? v0 : (__expf(v0) - 1.f);   // ELU
            v1 = v1 > 0.f ? v1 : (__expf(v1) - 1.f);
            v2 = v2 > 0.f ? v2 : (__expf(v2) - 1.f);
            v3 = v3 > 0.f ? v3 : (__expf(v3) - 1.f);
            v4 = v4 > 0.f ? v4 : (__expf(v4) - 1.f);
            v5 = v5 > 0.f ? v5 : (__expf(v5) - 1.f);
            v6 = v6 > 0.f ? v6 : (__expf(v6) - 1.f);
            v7 = v7 > 0.f ? v7 : (__expf(v7) - 1.f);
            uint4 packed;
            packed.x = (uint32)f2bf(v0) | ((uint32)f2bf(v1) << 16);
            packed.y = (uint32)f2bf(v2) | ((uint32)f2bf(v3) << 16);
            packed.z = (uint32)f2bf(v4) | ((uint32)f2bf(v5) << 16);
            packed.w = (uint32)f2bf(v6) | ((uint32)f2bf(v7) << 16);
            uint32 g = lane16 ^ ((uint32)n_local & 15u);   // swizzled granule
            *(uint4*)&ha[n_local][g * 8] = packed;
        }
    }
    __syncthreads();

    // ---------- phase B: layer-2 transform from LDS ----------
    {
        int l15 = (int)lane16, quad = (int)quarter;
        int n0 = n0blk + w * 16;
        int nloc = w * 16 + l15;

        bf16x8 af[4];
        #pragma unroll
        for (int s = 0; s < 4; ++s) {
            uint32 g = (uint32)(s * 4 + quad) ^ (uint32)l15;
            af[s] = *(const bf16x8*)&ha[nloc][g * 8];
        }

        #pragma unroll
        for (int tt = 0; tt < 5; ++tt) {
            const unsigned short* Brow = (tt < 4) ? &w2t[(tt * 16 + l15) * HID]
                                                  : &p2t[l15 * HID];
            f32x4 acc = {0.f, 0.f, 0.f, 0.f};
            #pragma unroll
            for (int s = 0; s < 4; ++s) {
                bf16x8 bf = *(const bf16x8*)&Brow[s * 32 + quad * 8];
                acc = __builtin_amdgcn_mfma_f32_16x16x32_bf16(af[s], bf, acc, 0, 0, 0);
            }
            int nodeb = n0 + quad * 4;
            if (tt < 4) {
                int ch = tt * 16 + l15;
                #pragma unroll
                for (int r = 0; r < 4; ++r)
                    if (nodeb + r < N_NODES)
                        h2b[(size_t)(nodeb + r) * OUT_DIM + ch] = f2bf(acc[r]);
            } else {
                #pragma unroll
                for (int r = 0; r < 4; ++r) {
                    if (nodeb + r < N_NODES) {
                        if (l15 == 0) a_src2[nodeb + r] = acc[r];
                        else if (l15 == 1) a_dst2[nodeb + r] = acc[r];
                    }
                }
            }
        }
    }
}

// ---------------- Layer 2: aggregate + log_softmax ----------------
// 4 nodes per wave (16 lanes/node, 4 ch/lane, uint2 gathers); 8 nodes/block
// rank-sorted by degree so each wave gets rank-adjacent nodes.

__global__ __launch_bounds__(128) void l2_aggregate(
        const unsigned short* __restrict__ h2b, const float* __restrict__ a_src2,
        const float* __restrict__ a_dst2, const int* __restrict__ row_start,
        const int* __restrict__ csr_src, const float* __restrict__ b2,
        float* __restrict__ out) {
    __shared__ int sdeg8[8];
    __shared__ int perm8[8];
    int t = threadIdx.x;
    int w = t >> 6;
    uint32 lane = t & 63;
    uint32 quarter = lane >> 4;
    uint32 lane16 = lane & 15;
    int nbase = blockIdx.x * 8;
    if (t < 8)
        sdeg8[t] = row_start[nbase + t + 1] - row_start[nbase + t];
    __syncthreads();
    if (t < 8) {
        int d = sdeg8[t];
        int r = 0;
        #pragma unroll
        for (int j = 0; j < 8; ++j) {
            int dj = sdeg8[j];
            r += (dj < d) || (dj == d && j < t);
        }
        perm8[r] = t;
    }
    __syncthreads();
    int n = nbase + perm8[w * 4 + (int)quarter];
    uint32 c0 = lane16 * 4u;
    int beg = row_start[n], end = row_start[n + 1];
    int cnt = end - beg;
    int kmax = cnt;
    kmax = max(kmax, __shfl_xor(kmax, 16, 64));
    kmax = max(kmax, __shfl_xor(kmax, 32, 64));
    float adst = a_dst2[n];
    float l = 0.f, a0 = 0.f, a1 = 0.f, a2 = 0.f, a3 = 0.f;

    for (int k = 0; k < kmax; k += 4) {
        uint32 ss[4]; float ee[4]; uint2 uu[4];
        #pragma unroll
        for (int q = 0; q < 4; ++q) {
            int j = beg + k + q;
            int jc = (j < end) ? j : (end - 1);
            ss[q] = (uint32)csr_src[jc];
        }
        #pragma unroll
        for (int q = 0; q < 4; ++q) ee[q] = a_src2[ss[q]];
        #pragma unroll
        for (int q = 0; q < 4; ++q) uu[q] = *(const uint2*)&h2b[(ss[q] << 6) + c0];
        #pragma unroll
        for (int q = 0; q < 4; ++q) {
            float e = ee[q] + adst;
            e = fmaxf(e, NEG_SLOPE * e);
            e = (k + q < cnt) ? e : -10000.f;   // masked lane -> p = 0
            float p = exp2f(e);
            l += p;
            a0 = fmaf(p, __uint_as_float(uu[q].x << 16), a0);
            a1 = fmaf(p, __uint_as_float(uu[q].x & 0xFFFF0000u), a1);
            a2 = fmaf(p, __uint_as_float(uu[q].y << 16), a2);
            a3 = fmaf(p, __uint_as_float(uu[q].y & 0xFFFF0000u), a3);
        }
    }

    float inv = 1.f / (l + 1e-16f);
    float o0 = a0 * inv + b2[c0 + 0];
    float o1 = a1 * inv + b2[c0 + 1];
    float o2 = a2 * inv + b2[c0 + 2];
    float o3 = a3 * inv + b2[c0 + 3];
    // log_softmax over 64 channels = 16 lanes x 4 (quarter-wave reduction)
    float mx = fmaxf(fmaxf(o0, o1), fmaxf(o2, o3));
    #pragma unroll
    for (int m = 8; m > 0; m >>= 1) mx = fmaxf(mx, __shfl_xor(mx, m, 16));
    float ex = __expf(o0 - mx) + __expf(o1 - mx) + __expf(o2 - mx) + __expf(o3 - mx);
    #pragma unroll
    for (int m = 8; m > 0; m >>= 1) ex += __shfl_xor(ex, m, 16);
    float lse = mx + __logf(ex);
    float4 o = make_float4(o0 - lse, o1 - lse, o2 - lse, o3 - lse);
    *(float4*)&out[(size_t)n * OUT_DIM + c0] = o;
}

// ---------------- launch ----------------

extern "C" void kernel_launch(void* const* d_in, const int* in_sizes, int n_in,
                              void* d_out, int out_size, void* d_ws, size_t ws_size,
                              hipStream_t stream) {
    const float* x   = (const float*)d_in[0];
    const int*   ei  = (const int*)d_in[1];
    const float* W1  = (const float*)d_in[2];
    const float* as1 = (const float*)d_in[3];
    const float* ad1 = (const float*)d_in[4];
    const float* b1  = (const float*)d_in[5];
    const float* W2  = (const float*)d_in[6];
    const float* as2 = (const float*)d_in[7];
    const float* ad2 = (const float*)d_in[8];
    const float* b2  = (const float*)d_in[9];
    float* out = (float*)d_out;

    const int* src = ei;             // row 0
    const int* dst = ei + E_EDGES;   // row 1

    char* ws = (char*)d_ws;
    size_t off = 0;
    auto alloc = [&](size_t bytes) -> void* {
        void* p = ws + off;
        off += (bytes + 255) & ~size_t(255);
        return p;
    };
    unsigned short* xb     = (unsigned short*)alloc((size_t)N_NODES * IN_DIM * 2);
    unsigned short* h1b    = (unsigned short*)alloc((size_t)N_NODES * HID * 2);
    unsigned short* h2b    = (unsigned short*)alloc((size_t)N_NODES * OUT_DIM * 2);
    unsigned short* w1t    = (unsigned short*)alloc((size_t)HID * IN_DIM * 2);
    unsigned short* p1t    = (unsigned short*)alloc((size_t)16 * IN_DIM * 2);
    unsigned short* w2t    = (unsigned short*)alloc((size_t)OUT_DIM * HID * 2);
    unsigned short* p2t    = (unsigned short*)alloc((size_t)16 * HID * 2);
    float* a_src1    = (float*)alloc((size_t)N_NODES * HEADS * 4);
    float* a_dst1    = (float*)alloc((size_t)N_NODES * HEADS * 4);
    float* a_src2    = (float*)alloc((size_t)N_NODES * 4);
    float* a_dst2    = (float*)alloc((size_t)N_NODES * 4);
    int*   row_start = (int*)alloc((size_t)(N_NODES + 1) * 4);
    int*   csr_src   = (int*)alloc((size_t)ET * 4);
    uint32* pairs    = (uint32*)alloc((size_t)ET * 4);
    int*   cnt       = (int*)alloc((size_t)NB * NT * 4);
    int*   bucketStart = (int*)alloc((size_t)(NB + 1) * 4);

    prep_all<<<MEGA_A, 256, 0, stream>>>(dst, cnt, x, xb, W1, as1, ad1,
                                         W2, as2, ad2, w1t, p1t, w2t, p2t);
    bucket_scatter<<<NT, 256, 0, stream>>>(src, dst, cnt, bucketStart, pairs);
    build_l1t<<<MEGA_B, 256, 0, stream>>>(pairs, bucketStart, row_start, csr_src,
                                          xb, w1t, p1t, h1b, a_src1, a_dst1);
    l1agg_l2t<<<L1T_BLOCKS, 256, 0, stream>>>(h1b, a_src1, a_dst1, row_start, csr_src,
                                              b1, w2t, p2t, h2b, a_src2, a_dst2);
    l2_aggregate<<<N_NODES / 8, 128, 0, stream>>>(h2b, a_src2, a_dst2, row_start, csr_src, b2, out);
}

// Round 19
// 207.405 us; speedup vs baseline: 1.0695x; 1.0192x over previous
//
#include <hip/hip_runtime.h>
#include <math.h>

#define N_NODES 50000
#define E_EDGES 800000
#define ET      (E_EDGES + N_NODES)   // edges + self loops
#define IN_DIM  128
#define HID     128
#define HEADS   8
#define C1      16
#define OUT_DIM 64
#define NEG_SLOPE 0.2f
#define LOG2E   1.4426950408889634f

#define TILE    8192
#define NT      ((ET + TILE - 1) / TILE)      // 104 tiles
#define NB      ((N_NODES + 255) / 256)       // 196 buckets of 256 nodes

#define CONV_BLOCKS (N_NODES * IN_DIM / 4 / 256)   // 6250
#define PREP_BLOCKS 112
#define MEGA_A (NT + CONV_BLOCKS + PREP_BLOCKS)    // 6466
#define L1T_BLOCKS ((N_NODES + 63) / 64)           // 782
#define MEGA_B (NB + L1T_BLOCKS)                   // 978
#define FUSE_BLOCKS ((N_NODES + 31) / 32)          // 1563

typedef unsigned int uint32;
typedef __attribute__((ext_vector_type(8))) short bf16x8;
typedef __attribute__((ext_vector_type(4))) float f32x4;

static __device__ __forceinline__ unsigned short f2bf(float f) {
    uint32 u = __float_as_uint(f);
    u += 0x7FFFu + ((u >> 16) & 1u);   // round to nearest even
    return (unsigned short)(u >> 16);
}

// ---------------- Mega-kernel A: bucket_hist + convert_x + prep_weights ----------------

__global__ __launch_bounds__(256) void prep_all(
        const int* __restrict__ dst, int* __restrict__ cnt,
        const float* __restrict__ x, unsigned short* __restrict__ xb,
        const float* __restrict__ W1, const float* __restrict__ as1,
        const float* __restrict__ ad1, const float* __restrict__ W2,
        const float* __restrict__ as2, const float* __restrict__ ad2,
        unsigned short* __restrict__ w1t, unsigned short* __restrict__ p1t,
        unsigned short* __restrict__ w2t, unsigned short* __restrict__ p2t) {
    __shared__ int hist[NB];
    int blk = blockIdx.x, t = threadIdx.x;
    if (blk < NT) {
        for (int b = t; b < NB; b += 256) hist[b] = 0;
        __syncthreads();
        int base = blk * TILE;
        #pragma unroll
        for (int it = 0; it < TILE / 256; ++it) {
            int i = base + it * 256 + t;
            if (i < ET) {
                int d = (i < E_EDGES) ? dst[i] : (i - E_EDGES);
                atomicAdd(&hist[d >> 8], 1);
            }
        }
        __syncthreads();
        for (int b = t; b < NB; b += 256) cnt[blk * NB + b] = hist[b];
    } else if (blk < NT + CONV_BLOCKS) {
        int i = (blk - NT) * 256 + t;
        float4 v = ((const float4*)x)[i];
        ushort4 o;
        o.x = f2bf(v.x); o.y = f2bf(v.y); o.z = f2bf(v.z); o.w = f2bf(v.w);
        ((ushort4*)xb)[i] = o;
    } else {
        int b = blk - NT - CONV_BLOCKS;    // 0..111
        if (b < 64) {
            int i = b * 256 + t;                // n*128+k
            int n = i >> 7, k = i & 127;
            w1t[n * IN_DIM + k] = f2bf(W1[k * HID + n]);
        } else if (b < 96) {
            int i = (b - 64) * 256 + t;         // n*128+k, n<64
            int n = i >> 7, k = i & 127;
            w2t[n * HID + k] = f2bf(W2[k * OUT_DIM + n]);
        } else if (b < 104) {
            int i = (b - 96) * 256 + t;         // j*128+k, j<16
            int j = i >> 7, k = i & 127;
            int hh = j & 7;
            const float* a = (j < 8) ? as1 : ad1;
            float acc = 0.f;
            #pragma unroll
            for (int c = 0; c < C1; ++c)
                acc = fmaf(W1[k * HID + hh * C1 + c], a[hh * C1 + c], acc);
            p1t[j * IN_DIM + k] = f2bf(acc * LOG2E);
        } else {
            int i = (b - 104) * 256 + t;        // j*128+k, j<16
            int j = i >> 7, k = i & 127;
            if (j < 2) {
                const float* a = (j == 0) ? as2 : ad2;
                float acc = 0.f;
                #pragma unroll
                for (int c = 0; c < OUT_DIM; ++c)
                    acc = fmaf(W2[k * OUT_DIM + c], a[c], acc);
                p2t[j * HID + k] = f2bf(acc * LOG2E);
            } else {
                p2t[j * HID + k] = 0;
            }
        }
    }
}

// ---------------- bucket_scatter (scan fused in) ----------------

__global__ __launch_bounds__(256) void bucket_scatter(
        const int* __restrict__ src, const int* __restrict__ dst,
        const int* __restrict__ cnt, int* __restrict__ bucketStart,
        uint32* __restrict__ pairs) {
    __shared__ int lcur[NB];
    __shared__ int sscan[256];
    int t = threadIdx.x;
    int tile = blockIdx.x;

    int run = 0, total = 0;
    if (t < NB) {
        for (int k = 0; k < NT; ++k) {
            int c = cnt[k * NB + t];     // coalesced across t
            if (k < tile) run += c;
            total += c;
        }
    }
    sscan[t] = (t < NB) ? total : 0;
    __syncthreads();
    #pragma unroll
    for (int off = 1; off < 256; off <<= 1) {
        int add = (t >= off) ? sscan[t - off] : 0;
        __syncthreads();
        sscan[t] += add;
        __syncthreads();
    }
    int bstart = sscan[t] - total;       // exclusive prefix
    if (t < NB) {
        lcur[t] = bstart + run;
        if (tile == 0) bucketStart[t] = bstart;
    }
    if (tile == 0 && t == 0) bucketStart[NB] = ET;
    __syncthreads();

    int base = tile * TILE;
    #pragma unroll
    for (int it = 0; it < TILE / 256; ++it) {
        int i = base + it * 256 + t;
        if (i < ET) {
            int s, d;
            if (i < E_EDGES) { s = src[i]; d = dst[i]; }
            else             { s = d = i - E_EDGES; }
            int pos = atomicAdd(&lcur[d >> 8], 1);
            pairs[pos] = ((uint32)s << 8) | (uint32)(d & 255);
        }
    }
}

// ---------------- Mega-kernel B: bucket_build + l1_transform_mfma ----------------

__global__ __launch_bounds__(256) void build_l1t(
        const uint32* __restrict__ pairs, const int* __restrict__ bucketStart,
        int* __restrict__ row_start, int* __restrict__ csr_src,
        const unsigned short* __restrict__ xb, const unsigned short* __restrict__ w1t,
        const unsigned short* __restrict__ p1t, unsigned short* __restrict__ h1b,
        float* __restrict__ a_src, float* __restrict__ a_dst) {
    __shared__ int sdeg[256];
    __shared__ int sscan[256];
    int t = threadIdx.x;
    if (blockIdx.x < NB) {
        int b = blockIdx.x;
        int beg = bucketStart[b], end = bucketStart[b + 1];
        sdeg[t] = 0;
        __syncthreads();
        for (int j = beg + t; j < end; j += 256)
            atomicAdd(&sdeg[pairs[j] & 255u], 1);
        __syncthreads();
        int v = sdeg[t];
        sscan[t] = v;
        __syncthreads();
        #pragma unroll
        for (int off = 1; off < 256; off <<= 1) {
            int add = (t >= off) ? sscan[t - off] : 0;
            __syncthreads();
            sscan[t] += add;
            __syncthreads();
        }
        int pos0 = beg + sscan[t] - v;   // exclusive prefix within bucket
        int n = b * 256 + t;
        if (n < N_NODES) row_start[n] = pos0;
        if (b == 0 && t == 0) row_start[N_NODES] = ET;
        __syncthreads();
        sscan[t] = pos0;                 // reuse as cursor
        __syncthreads();
        for (int j = beg + t; j < end; j += 256) {
            uint32 p = pairs[j];
            int pos = atomicAdd(&sscan[p & 255u], 1);
            csr_src[pos] = (int)(p >> 8);
        }
        return;
    }
    // ---- layer-1 transform via MFMA, LDS-free ----
    int bb = blockIdx.x - NB;
    int w = t >> 6, lane = t & 63;
    int l15 = lane & 15, quad = lane >> 4;
    int n0 = bb * 64 + w * 16;
    int mrow = n0 + l15;
    int mload = (mrow < N_NODES) ? mrow : (N_NODES - 1);

    bf16x8 af[4];
    #pragma unroll
    for (int s = 0; s < 4; ++s)
        af[s] = *(const bf16x8*)&xb[(size_t)mload * IN_DIM + s * 32 + quad * 8];

    #pragma unroll
    for (int tt = 0; tt < 9; ++tt) {
        const unsigned short* Brow = (tt < 8) ? &w1t[(tt * 16 + l15) * IN_DIM]
                                              : &p1t[l15 * IN_DIM];
        f32x4 acc = {0.f, 0.f, 0.f, 0.f};
        #pragma unroll
        for (int s = 0; s < 4; ++s) {
            bf16x8 bf = *(const bf16x8*)&Brow[s * 32 + quad * 8];
            acc = __builtin_amdgcn_mfma_f32_16x16x32_bf16(af[s], bf, acc, 0, 0, 0);
        }
        int nodeb = n0 + quad * 4;
        if (tt < 8) {
            int ch = tt * 16 + l15;
            #pragma unroll
            for (int r = 0; r < 4; ++r)
                if (nodeb + r < N_NODES)
                    h1b[(size_t)(nodeb + r) * HID + ch] = f2bf(acc[r]);
        } else {
            #pragma unroll
            for (int r = 0; r < 4; ++r) {
                if (nodeb + r < N_NODES) {
                    if (l15 < 8) a_src[(nodeb + r) * HEADS + l15] = acc[r];
                    else         a_dst[(nodeb + r) * HEADS + (l15 - 8)] = acc[r];
                }
            }
        }
    }
}

// ---------------- Fused: layer-1 aggregate + layer-2 transform ----------------
// 128-thread block (2 waves) covers 32 nodes -> 1563 blocks (~6/CU, fine
// packing, small barrier sets). Phase A: 4 passes, rank-grouped nodes, 8-deep
// edge unroll (24 loads in flight/wave). h_act in LDS (8 KB, XOR-swizzled).
// Phase B: wave w MFMAs rows w*16..w*16+15, all 5 tt tiles.

__global__ __launch_bounds__(128) void l1agg_l2t(
        const unsigned short* __restrict__ h1b, const float* __restrict__ a_src,
        const float* __restrict__ a_dst, const int* __restrict__ row_start,
        const int* __restrict__ csr_src, const float* __restrict__ b1,
        const unsigned short* __restrict__ w2t, const unsigned short* __restrict__ p2t,
        unsigned short* __restrict__ h2b, float* __restrict__ a_src2,
        float* __restrict__ a_dst2) {
    __shared__ unsigned short ha[32][128];   // 8 KB, swizzled granules
    __shared__ int sdeg32[32];
    __shared__ unsigned char perm[32];
    int t = threadIdx.x;
    int w = t >> 6;              // 0..1
    uint32 lane = t & 63;
    uint32 quarter = lane >> 4;
    uint32 lane16 = lane & 15;
    int n0blk = blockIdx.x * 32;

    // ---- degree-rank the 32 nodes (once per block) ----
    if (t < 32) {
        int n = n0blk + t;
        int nc = (n < N_NODES) ? n : (N_NODES - 1);
        sdeg32[t] = row_start[nc + 1] - row_start[nc];
    }
    __syncthreads();
    if (t < 32) {
        int d = sdeg32[t];
        int r = 0;
        #pragma unroll
        for (int j = 0; j < 32; ++j) {
            int dj = sdeg32[j];
            r += (dj < d) || (dj == d && j < t);
        }
        perm[r] = (unsigned char)t;
    }
    __syncthreads();

    // ---------- phase A: aggregate 32 nodes into LDS (rank-grouped, 8-deep) ----------
    {
        uint32 c0 = lane16 * 8u;     // 8 channels per lane
        uint32 h = lane16 >> 1;      // head = c0 >> 4
        #pragma unroll
        for (int pass = 0; pass < 4; ++pass) {
            int u = pass * 2 + w;                       // work unit 0..7
            int n_local = (int)perm[u * 4 + (int)quarter];
            int n = n0blk + n_local;
            int nc = (n < N_NODES) ? n : (N_NODES - 1);
            int beg = row_start[nc], end = row_start[nc + 1];
            int cnt = end - beg;
            int kmax = cnt;
            kmax = max(kmax, __shfl_xor(kmax, 16, 64));
            kmax = max(kmax, __shfl_xor(kmax, 32, 64));
            float adst = a_dst[nc * HEADS + h];
            float l = 0.f;
            float a0 = 0.f, a1 = 0.f, a2 = 0.f, a3 = 0.f;
            float a4 = 0.f, a5 = 0.f, a6 = 0.f, a7 = 0.f;

            auto edge = [&](float e0, uint4 u0, bool live) {
                float e = e0 + adst;
                e = fmaxf(e, NEG_SLOPE * e);          // leaky relu (log2 domain)
                e = live ? e : -10000.f;              // masked lane -> p = 0
                float p = exp2f(e);
                l += p;
                a0 = fmaf(p, __uint_as_float(u0.x << 16), a0);
                a1 = fmaf(p, __uint_as_float(u0.x & 0xFFFF0000u), a1);
                a2 = fmaf(p, __uint_as_float(u0.y << 16), a2);
                a3 = fmaf(p, __uint_as_float(u0.y & 0xFFFF0000u), a3);
                a4 = fmaf(p, __uint_as_float(u0.z << 16), a4);
                a5 = fmaf(p, __uint_as_float(u0.z & 0xFFFF0000u), a5);
                a6 = fmaf(p, __uint_as_float(u0.w << 16), a6);
                a7 = fmaf(p, __uint_as_float(u0.w & 0xFFFF0000u), a7);
            };

            int k = 0;
            for (; k + 8 <= kmax; k += 8) {
                uint32 ss[8]; float ee[8]; uint4 uu[8];
                #pragma unroll
                for (int q = 0; q < 8; ++q) {
                    int j = beg + k + q;
                    int jc = (j < end) ? j : (end - 1);    // cnt >= 1 (self loop)
                    ss[q] = (uint32)csr_src[jc];
                }
                #pragma unroll
                for (int q = 0; q < 8; ++q) ee[q] = a_src[ss[q] * 8u + h];
                #pragma unroll
                for (int q = 0; q < 8; ++q) uu[q] = *(const uint4*)&h1b[(ss[q] << 7) + c0];
                #pragma unroll
                for (int q = 0; q < 8; ++q) edge(ee[q], uu[q], k + q < cnt);
            }
            for (; k < kmax; k += 4) {
                uint32 ss[4]; float ee[4]; uint4 uu[4];
                #pragma unroll
                for (int q = 0; q < 4; ++q) {
                    int j = beg + k + q;
                    int jc = (j < end) ? j : (end - 1);
                    ss[q] = (uint32)csr_src[jc];
                }
                #pragma unroll
                for (int q = 0; q < 4; ++q) ee[q] = a_src[ss[q] * 8u + h];
                #pragma unroll
                for (int q = 0; q < 4; ++q) uu[q] = *(const uint4*)&h1b[(ss[q] << 7) + c0];
                #pragma unroll
                for (int q = 0; q < 4; ++q) edge(ee[q], uu[q], k + q < cnt);
            }

            float inv = 1.f / (l + 1e-16f);
            float v0 = a0 * inv + b1[c0 + 0];
            float v1 = a1 * inv + b1[c0 + 1];
            float v2 = a2 * inv + b1[c0 + 2];
            float v3 = a3 * inv + b1[c0 + 3];
            float v4 = a4 * inv + b1[c0 + 4];
            float v5 = a5 * inv + b1[c0 + 5];
            float v6 = a6 * inv + b1[c0 + 6];
            float v7 = a7 * inv + b1[c0 + 7];
            v0 = v0 > 0.f ? v0 : (__expf(v0) - 1.f);   // ELU
            v1 = v1 > 0.f ? v1 : (__expf(v1) - 1.f);
            v2 = v2 > 0.f ? v2 : (__expf(v2) - 1.f);
            v3 = v3 > 0.f ? v3 : (__expf(v3) - 1.f);
            v4 = v4 > 0.f ? v4 : (__expf(v4) - 1.f);
            v5 = v5 > 0.f ? v5 : (__expf(v5) - 1.f);
            v6 = v6 > 0.f ? v6 : (__expf(v6) - 1.f);
            v7 = v7 > 0.f ? v7 : (__expf(v7) - 1.f);
            uint4 packed;
            packed.x = (uint32)f2bf(v0) | ((uint32)f2bf(v1) << 16);
            packed.y = (uint32)f2bf(v2) | ((uint32)f2bf(v3) << 16);
            packed.z = (uint32)f2bf(v4) | ((uint32)f2bf(v5) << 16);
            packed.w = (uint32)f2bf(v6) | ((uint32)f2bf(v7) << 16);
            uint32 g = lane16 ^ ((uint32)n_local & 15u);   // swizzled granule
            *(uint4*)&ha[n_local][g * 8] = packed;
        }
    }
    __syncthreads();

    // ---------- phase B: layer-2 transform from LDS ----------
    {
        int l15 = (int)lane16, quad = (int)quarter;
        int n0 = n0blk + w * 16;
        int nloc = w * 16 + l15;

        bf16x8 af[4];
        #pragma unroll
        for (int s = 0; s < 4; ++s) {
            uint32 g = (uint32)(s * 4 + quad) ^ (uint32)l15;
            af[s] = *(const bf16x8*)&ha[nloc][g * 8];
        }

        #pragma unroll
        for (int tt = 0; tt < 5; ++tt) {
            const unsigned short* Brow = (tt < 4) ? &w2t[(tt * 16 + l15) * HID]
                                                  : &p2t[l15 * HID];
            f32x4 acc = {0.f, 0.f, 0.f, 0.f};
            #pragma unroll
            for (int s = 0; s < 4; ++s) {
                bf16x8 bf = *(const bf16x8*)&Brow[s * 32 + quad * 8];
                acc = __builtin_amdgcn_mfma_f32_16x16x32_bf16(af[s], bf, acc, 0, 0, 0);
            }
            int nodeb = n0 + quad * 4;
            if (tt < 4) {
                int ch = tt * 16 + l15;
                #pragma unroll
                for (int r = 0; r < 4; ++r)
                    if (nodeb + r < N_NODES)
                        h2b[(size_t)(nodeb + r) * OUT_DIM + ch] = f2bf(acc[r]);
            } else {
                #pragma unroll
                for (int r = 0; r < 4; ++r) {
                    if (nodeb + r < N_NODES) {
                        if (l15 == 0) a_src2[nodeb + r] = acc[r];
                        else if (l15 == 1) a_dst2[nodeb + r] = acc[r];
                    }
                }
            }
        }
    }
}

// ---------------- Layer 2: aggregate + log_softmax ----------------
// 4 nodes per wave (16 lanes/node, 4 ch/lane, uint2 gathers); 8 nodes/block
// rank-sorted by degree so each wave gets rank-adjacent nodes.

__global__ __launch_bounds__(128) void l2_aggregate(
        const unsigned short* __restrict__ h2b, const float* __restrict__ a_src2,
        const float* __restrict__ a_dst2, const int* __restrict__ row_start,
        const int* __restrict__ csr_src, const float* __restrict__ b2,
        float* __restrict__ out) {
    __shared__ int sdeg8[8];
    __shared__ int perm8[8];
    int t = threadIdx.x;
    int w = t >> 6;
    uint32 lane = t & 63;
    uint32 quarter = lane >> 4;
    uint32 lane16 = lane & 15;
    int nbase = blockIdx.x * 8;
    if (t < 8)
        sdeg8[t] = row_start[nbase + t + 1] - row_start[nbase + t];
    __syncthreads();
    if (t < 8) {
        int d = sdeg8[t];
        int r = 0;
        #pragma unroll
        for (int j = 0; j < 8; ++j) {
            int dj = sdeg8[j];
            r += (dj < d) || (dj == d && j < t);
        }
        perm8[r] = t;
    }
    __syncthreads();
    int n = nbase + perm8[w * 4 + (int)quarter];
    uint32 c0 = lane16 * 4u;
    int beg = row_start[n], end = row_start[n + 1];
    int cnt = end - beg;
    int kmax = cnt;
    kmax = max(kmax, __shfl_xor(kmax, 16, 64));
    kmax = max(kmax, __shfl_xor(kmax, 32, 64));
    float adst = a_dst2[n];
    float l = 0.f, a0 = 0.f, a1 = 0.f, a2 = 0.f, a3 = 0.f;

    for (int k = 0; k < kmax; k += 4) {
        uint32 ss[4]; float ee[4]; uint2 uu[4];
        #pragma unroll
        for (int q = 0; q < 4; ++q) {
            int j = beg + k + q;
            int jc = (j < end) ? j : (end - 1);
            ss[q] = (uint32)csr_src[jc];
        }
        #pragma unroll
        for (int q = 0; q < 4; ++q) ee[q] = a_src2[ss[q]];
        #pragma unroll
        for (int q = 0; q < 4; ++q) uu[q] = *(const uint2*)&h2b[(ss[q] << 6) + c0];
        #pragma unroll
        for (int q = 0; q < 4; ++q) {
            float e = ee[q] + adst;
            e = fmaxf(e, NEG_SLOPE * e);
            e = (k + q < cnt) ? e : -10000.f;   // masked lane -> p = 0
            float p = exp2f(e);
            l += p;
            a0 = fmaf(p, __uint_as_float(uu[q].x << 16), a0);
            a1 = fmaf(p, __uint_as_float(uu[q].x & 0xFFFF0000u), a1);
            a2 = fmaf(p, __uint_as_float(uu[q].y << 16), a2);
            a3 = fmaf(p, __uint_as_float(uu[q].y & 0xFFFF0000u), a3);
        }
    }

    float inv = 1.f / (l + 1e-16f);
    float o0 = a0 * inv + b2[c0 + 0];
    float o1 = a1 * inv + b2[c0 + 1];
    float o2 = a2 * inv + b2[c0 + 2];
    float o3 = a3 * inv + b2[c0 + 3];
    // log_softmax over 64 channels = 16 lanes x 4 (quarter-wave reduction)
    float mx = fmaxf(fmaxf(o0, o1), fmaxf(o2, o3));
    #pragma unroll
    for (int m = 8; m > 0; m >>= 1) mx = fmaxf(mx, __shfl_xor(mx, m, 16));
    float ex = __expf(o0 - mx) + __expf(o1 - mx) + __expf(o2 - mx) + __expf(o3 - mx);
    #pragma unroll
    for (int m = 8; m > 0; m >>= 1) ex += __shfl_xor(ex, m, 16);
    float lse = mx + __logf(ex);
    float4 o = make_float4(o0 - lse, o1 - lse, o2 - lse, o3 - lse);
    *(float4*)&out[(size_t)n * OUT_DIM + c0] = o;
}

// ---------------- launch ----------------

extern "C" void kernel_launch(void* const* d_in, const int* in_sizes, int n_in,
                              void* d_out, int out_size, void* d_ws, size_t ws_size,
                              hipStream_t stream) {
    const float* x   = (const float*)d_in[0];
    const int*   ei  = (const int*)d_in[1];
    const float* W1  = (const float*)d_in[2];
    const float* as1 = (const float*)d_in[3];
    const float* ad1 = (const float*)d_in[4];
    const float* b1  = (const float*)d_in[5];
    const float* W2  = (const float*)d_in[6];
    const float* as2 = (const float*)d_in[7];
    const float* ad2 = (const float*)d_in[8];
    const float* b2  = (const float*)d_in[9];
    float* out = (float*)d_out;

    const int* src = ei;             // row 0
    const int* dst = ei + E_EDGES;   // row 1

    char* ws = (char*)d_ws;
    size_t off = 0;
    auto alloc = [&](size_t bytes) -> void* {
        void* p = ws + off;
        off += (bytes + 255) & ~size_t(255);
        return p;
    };
    unsigned short* xb     = (unsigned short*)alloc((size_t)N_NODES * IN_DIM * 2);
    unsigned short* h1b    = (unsigned short*)alloc((size_t)N_NODES * HID * 2);
    unsigned short* h2b    = (unsigned short*)alloc((size_t)N_NODES * OUT_DIM * 2);
    unsigned short* w1t    = (unsigned short*)alloc((size_t)HID * IN_DIM * 2);
    unsigned short* p1t    = (unsigned short*)alloc((size_t)16 * IN_DIM * 2);
    unsigned short* w2t    = (unsigned short*)alloc((size_t)OUT_DIM * HID * 2);
    unsigned short* p2t    = (unsigned short*)alloc((size_t)16 * HID * 2);
    float* a_src1    = (float*)alloc((size_t)N_NODES * HEADS * 4);
    float* a_dst1    = (float*)alloc((size_t)N_NODES * HEADS * 4);
    float* a_src2    = (float*)alloc((size_t)N_NODES * 4);
    float* a_dst2    = (float*)alloc((size_t)N_NODES * 4);
    int*   row_start = (int*)alloc((size_t)(N_NODES + 1) * 4);
    int*   csr_src   = (int*)alloc((size_t)ET * 4);
    uint32* pairs    = (uint32*)alloc((size_t)ET * 4);
    int*   cnt       = (int*)alloc((size_t)NB * NT * 4);
    int*   bucketStart = (int*)alloc((size_t)(NB + 1) * 4);

    prep_all<<<MEGA_A, 256, 0, stream>>>(dst, cnt, x, xb, W1, as1, ad1,
                                         W2, as2, ad2, w1t, p1t, w2t, p2t);
    bucket_scatter<<<NT, 256, 0, stream>>>(src, dst, cnt, bucketStart, pairs);
    build_l1t<<<MEGA_B, 256, 0, stream>>>(pairs, bucketStart, row_start, csr_src,
                                          xb, w1t, p1t, h1b, a_src1, a_dst1);
    l1agg_l2t<<<FUSE_BLOCKS, 128, 0, stream>>>(h1b, a_src1, a_dst1, row_start, csr_src,
                                               b1, w2t, p2t, h2b, a_src2, a_dst2);
    l2_aggregate<<<N_NODES / 8, 128, 0, stream>>>(h2b, a_src2, a_dst2, row_start, csr_src, b2, out);
}

// Round 20
// 199.011 us; speedup vs baseline: 1.1146x; 1.0422x over previous
//
#include <hip/hip_runtime.h>
#include <math.h>

#define N_NODES 50000
#define E_EDGES 800000
#define ET      (E_EDGES + N_NODES)   // edges + self loops
#define IN_DIM  128
#define HID     128
#define HEADS   8
#define C1      16
#define OUT_DIM 64
#define NEG_SLOPE 0.2f
#define LOG2E   1.4426950408889634f

#define TILE    8192
#define NT      ((ET + TILE - 1) / TILE)      // 104 tiles
#define NB      ((N_NODES + 255) / 256)       // 196 buckets of 256 nodes

#define CONV_BLOCKS (N_NODES * IN_DIM / 4 / 256)   // 6250
#define PREP_BLOCKS 112
#define MEGA_A (NT + CONV_BLOCKS + PREP_BLOCKS)    // 6466
#define L1T_BLOCKS ((N_NODES + 63) / 64)           // 782
#define MEGA_B (NB + L1T_BLOCKS)                   // 978
#define FUSE_BLOCKS ((N_NODES + 31) / 32)          // 1563

typedef unsigned int uint32;
typedef __attribute__((ext_vector_type(8))) short bf16x8;
typedef __attribute__((ext_vector_type(4))) float f32x4;
typedef __attribute__((ext_vector_type(2))) float f32x2;

static __device__ __forceinline__ unsigned short f2bf(float f) {
    uint32 u = __float_as_uint(f);
    u += 0x7FFFu + ((u >> 16) & 1u);   // round to nearest even
    return (unsigned short)(u >> 16);
}

static __device__ __forceinline__ unsigned char f2fp8(float f) {
    int pk = __builtin_amdgcn_cvt_pk_fp8_f32(f, f, 0, false);   // RNE, OCP e4m3
    return (unsigned char)(pk & 0xFF);
}

// ---------------- Mega-kernel A: bucket_hist + convert_x + prep_weights ----------------

__global__ __launch_bounds__(256) void prep_all(
        const int* __restrict__ dst, int* __restrict__ cnt,
        const float* __restrict__ x, unsigned short* __restrict__ xb,
        const float* __restrict__ W1, const float* __restrict__ as1,
        const float* __restrict__ ad1, const float* __restrict__ W2,
        const float* __restrict__ as2, const float* __restrict__ ad2,
        unsigned short* __restrict__ w1t, unsigned short* __restrict__ p1t,
        unsigned short* __restrict__ w2t, unsigned short* __restrict__ p2t) {
    __shared__ int hist[NB];
    int blk = blockIdx.x, t = threadIdx.x;
    if (blk < NT) {
        for (int b = t; b < NB; b += 256) hist[b] = 0;
        __syncthreads();
        int base = blk * TILE;
        #pragma unroll
        for (int it = 0; it < TILE / 256; ++it) {
            int i = base + it * 256 + t;
            if (i < ET) {
                int d = (i < E_EDGES) ? dst[i] : (i - E_EDGES);
                atomicAdd(&hist[d >> 8], 1);
            }
        }
        __syncthreads();
        for (int b = t; b < NB; b += 256) cnt[blk * NB + b] = hist[b];
    } else if (blk < NT + CONV_BLOCKS) {
        int i = (blk - NT) * 256 + t;
        float4 v = ((const float4*)x)[i];
        ushort4 o;
        o.x = f2bf(v.x); o.y = f2bf(v.y); o.z = f2bf(v.z); o.w = f2bf(v.w);
        ((ushort4*)xb)[i] = o;
    } else {
        int b = blk - NT - CONV_BLOCKS;    // 0..111
        if (b < 64) {
            int i = b * 256 + t;                // n*128+k
            int n = i >> 7, k = i & 127;
            w1t[n * IN_DIM + k] = f2bf(W1[k * HID + n]);
        } else if (b < 96) {
            int i = (b - 64) * 256 + t;         // n*128+k, n<64
            int n = i >> 7, k = i & 127;
            w2t[n * HID + k] = f2bf(W2[k * OUT_DIM + n]);
        } else if (b < 104) {
            int i = (b - 96) * 256 + t;         // j*128+k, j<16
            int j = i >> 7, k = i & 127;
            int hh = j & 7;
            const float* a = (j < 8) ? as1 : ad1;
            float acc = 0.f;
            #pragma unroll
            for (int c = 0; c < C1; ++c)
                acc = fmaf(W1[k * HID + hh * C1 + c], a[hh * C1 + c], acc);
            p1t[j * IN_DIM + k] = f2bf(acc * LOG2E);
        } else {
            int i = (b - 104) * 256 + t;        // j*128+k, j<16
            int j = i >> 7, k = i & 127;
            if (j < 2) {
                const float* a = (j == 0) ? as2 : ad2;
                float acc = 0.f;
                #pragma unroll
                for (int c = 0; c < OUT_DIM; ++c)
                    acc = fmaf(W2[k * OUT_DIM + c], a[c], acc);
                p2t[j * HID + k] = f2bf(acc * LOG2E);
            } else {
                p2t[j * HID + k] = 0;
            }
        }
    }
}

// ---------------- bucket_scatter (scan fused in) ----------------

__global__ __launch_bounds__(256) void bucket_scatter(
        const int* __restrict__ src, const int* __restrict__ dst,
        const int* __restrict__ cnt, int* __restrict__ bucketStart,
        uint32* __restrict__ pairs) {
    __shared__ int lcur[NB];
    __shared__ int sscan[256];
    int t = threadIdx.x;
    int tile = blockIdx.x;

    int run = 0, total = 0;
    if (t < NB) {
        for (int k = 0; k < NT; ++k) {
            int c = cnt[k * NB + t];     // coalesced across t
            if (k < tile) run += c;
            total += c;
        }
    }
    sscan[t] = (t < NB) ? total : 0;
    __syncthreads();
    #pragma unroll
    for (int off = 1; off < 256; off <<= 1) {
        int add = (t >= off) ? sscan[t - off] : 0;
        __syncthreads();
        sscan[t] += add;
        __syncthreads();
    }
    int bstart = sscan[t] - total;       // exclusive prefix
    if (t < NB) {
        lcur[t] = bstart + run;
        if (tile == 0) bucketStart[t] = bstart;
    }
    if (tile == 0 && t == 0) bucketStart[NB] = ET;
    __syncthreads();

    int base = tile * TILE;
    #pragma unroll
    for (int it = 0; it < TILE / 256; ++it) {
        int i = base + it * 256 + t;
        if (i < ET) {
            int s, d;
            if (i < E_EDGES) { s = src[i]; d = dst[i]; }
            else             { s = d = i - E_EDGES; }
            int pos = atomicAdd(&lcur[d >> 8], 1);
            pairs[pos] = ((uint32)s << 8) | (uint32)(d & 255);
        }
    }
}

// ---------------- Mega-kernel B: bucket_build + l1_transform_mfma ----------------
// h1 payload now stored as fp8 e4m3 (HW cvt, RNE): 128 B/node.

__global__ __launch_bounds__(256) void build_l1t(
        const uint32* __restrict__ pairs, const int* __restrict__ bucketStart,
        int* __restrict__ row_start, int* __restrict__ csr_src,
        const unsigned short* __restrict__ xb, const unsigned short* __restrict__ w1t,
        const unsigned short* __restrict__ p1t, unsigned char* __restrict__ h1f,
        float* __restrict__ a_src, float* __restrict__ a_dst) {
    __shared__ int sdeg[256];
    __shared__ int sscan[256];
    int t = threadIdx.x;
    if (blockIdx.x < NB) {
        int b = blockIdx.x;
        int beg = bucketStart[b], end = bucketStart[b + 1];
        sdeg[t] = 0;
        __syncthreads();
        for (int j = beg + t; j < end; j += 256)
            atomicAdd(&sdeg[pairs[j] & 255u], 1);
        __syncthreads();
        int v = sdeg[t];
        sscan[t] = v;
        __syncthreads();
        #pragma unroll
        for (int off = 1; off < 256; off <<= 1) {
            int add = (t >= off) ? sscan[t - off] : 0;
            __syncthreads();
            sscan[t] += add;
            __syncthreads();
        }
        int pos0 = beg + sscan[t] - v;   // exclusive prefix within bucket
        int n = b * 256 + t;
        if (n < N_NODES) row_start[n] = pos0;
        if (b == 0 && t == 0) row_start[N_NODES] = ET;
        __syncthreads();
        sscan[t] = pos0;                 // reuse as cursor
        __syncthreads();
        for (int j = beg + t; j < end; j += 256) {
            uint32 p = pairs[j];
            int pos = atomicAdd(&sscan[p & 255u], 1);
            csr_src[pos] = (int)(p >> 8);
        }
        return;
    }
    // ---- layer-1 transform via MFMA, LDS-free ----
    int bb = blockIdx.x - NB;
    int w = t >> 6, lane = t & 63;
    int l15 = lane & 15, quad = lane >> 4;
    int n0 = bb * 64 + w * 16;
    int mrow = n0 + l15;
    int mload = (mrow < N_NODES) ? mrow : (N_NODES - 1);

    bf16x8 af[4];
    #pragma unroll
    for (int s = 0; s < 4; ++s)
        af[s] = *(const bf16x8*)&xb[(size_t)mload * IN_DIM + s * 32 + quad * 8];

    #pragma unroll
    for (int tt = 0; tt < 9; ++tt) {
        const unsigned short* Brow = (tt < 8) ? &w1t[(tt * 16 + l15) * IN_DIM]
                                              : &p1t[l15 * IN_DIM];
        f32x4 acc = {0.f, 0.f, 0.f, 0.f};
        #pragma unroll
        for (int s = 0; s < 4; ++s) {
            bf16x8 bf = *(const bf16x8*)&Brow[s * 32 + quad * 8];
            acc = __builtin_amdgcn_mfma_f32_16x16x32_bf16(af[s], bf, acc, 0, 0, 0);
        }
        int nodeb = n0 + quad * 4;
        if (tt < 8) {
            int ch = tt * 16 + l15;
            #pragma unroll
            for (int r = 0; r < 4; ++r)
                if (nodeb + r < N_NODES)
                    h1f[(size_t)(nodeb + r) * HID + ch] = f2fp8(acc[r]);
        } else {
            #pragma unroll
            for (int r = 0; r < 4; ++r) {
                if (nodeb + r < N_NODES) {
                    if (l15 < 8) a_src[(nodeb + r) * HEADS + l15] = acc[r];
                    else         a_dst[(nodeb + r) * HEADS + (l15 - 8)] = acc[r];
                }
            }
        }
    }
}

// ---------------- Fused: layer-1 aggregate + layer-2 transform ----------------
// 128-thread block (2 waves), 32 nodes/block, rank-grouped, 8-deep unroll.
// h1 gathers are fp8 (8 B/lane/edge, HW cvt_pk_f32_fp8 unpack). h_act in LDS
// (bf16, XOR-swizzled); phase B MFMAs from LDS.

__global__ __launch_bounds__(128) void l1agg_l2t(
        const unsigned char* __restrict__ h1f, const float* __restrict__ a_src,
        const float* __restrict__ a_dst, const int* __restrict__ row_start,
        const int* __restrict__ csr_src, const float* __restrict__ b1,
        const unsigned short* __restrict__ w2t, const unsigned short* __restrict__ p2t,
        unsigned short* __restrict__ h2b, float* __restrict__ a_src2,
        float* __restrict__ a_dst2) {
    __shared__ unsigned short ha[32][128];   // 8 KB, swizzled granules
    __shared__ int sdeg32[32];
    __shared__ unsigned char perm[32];
    int t = threadIdx.x;
    int w = t >> 6;              // 0..1
    uint32 lane = t & 63;
    uint32 quarter = lane >> 4;
    uint32 lane16 = lane & 15;
    int n0blk = blockIdx.x * 32;

    // ---- degree-rank the 32 nodes (once per block) ----
    if (t < 32) {
        int n = n0blk + t;
        int nc = (n < N_NODES) ? n : (N_NODES - 1);
        sdeg32[t] = row_start[nc + 1] - row_start[nc];
    }
    __syncthreads();
    if (t < 32) {
        int d = sdeg32[t];
        int r = 0;
        #pragma unroll
        for (int j = 0; j < 32; ++j) {
            int dj = sdeg32[j];
            r += (dj < d) || (dj == d && j < t);
        }
        perm[r] = (unsigned char)t;
    }
    __syncthreads();

    // ---------- phase A: aggregate 32 nodes into LDS (rank-grouped, 8-deep) ----------
    {
        uint32 c0 = lane16 * 8u;     // 8 channels per lane (8 fp8 bytes)
        uint32 h = lane16 >> 1;      // head = c0 >> 4
        #pragma unroll
        for (int pass = 0; pass < 4; ++pass) {
            int u = pass * 2 + w;                       // work unit 0..7
            int n_local = (int)perm[u * 4 + (int)quarter];
            int n = n0blk + n_local;
            int nc = (n < N_NODES) ? n : (N_NODES - 1);
            int beg = row_start[nc], end = row_start[nc + 1];
            int cnt = end - beg;
            int kmax = cnt;
            kmax = max(kmax, __shfl_xor(kmax, 16, 64));
            kmax = max(kmax, __shfl_xor(kmax, 32, 64));
            float adst = a_dst[nc * HEADS + h];
            float l = 0.f;
            float a0 = 0.f, a1 = 0.f, a2 = 0.f, a3 = 0.f;
            float a4 = 0.f, a5 = 0.f, a6 = 0.f, a7 = 0.f;

            auto edge = [&](float e0, uint2 u0, bool live) {
                float e = e0 + adst;
                e = fmaxf(e, NEG_SLOPE * e);          // leaky relu (log2 domain)
                e = live ? e : -10000.f;              // masked lane -> p = 0
                float p = exp2f(e);
                l += p;
                f32x2 f01 = __builtin_amdgcn_cvt_pk_f32_fp8((int)u0.x, false);
                f32x2 f23 = __builtin_amdgcn_cvt_pk_f32_fp8((int)u0.x, true);
                f32x2 f45 = __builtin_amdgcn_cvt_pk_f32_fp8((int)u0.y, false);
                f32x2 f67 = __builtin_amdgcn_cvt_pk_f32_fp8((int)u0.y, true);
                a0 = fmaf(p, f01[0], a0);
                a1 = fmaf(p, f01[1], a1);
                a2 = fmaf(p, f23[0], a2);
                a3 = fmaf(p, f23[1], a3);
                a4 = fmaf(p, f45[0], a4);
                a5 = fmaf(p, f45[1], a5);
                a6 = fmaf(p, f67[0], a6);
                a7 = fmaf(p, f67[1], a7);
            };

            int k = 0;
            for (; k + 8 <= kmax; k += 8) {
                uint32 ss[8]; float ee[8]; uint2 uu[8];
                #pragma unroll
                for (int q = 0; q < 8; ++q) {
                    int j = beg + k + q;
                    int jc = (j < end) ? j : (end - 1);    // cnt >= 1 (self loop)
                    ss[q] = (uint32)csr_src[jc];
                }
                #pragma unroll
                for (int q = 0; q < 8; ++q) ee[q] = a_src[ss[q] * 8u + h];
                #pragma unroll
                for (int q = 0; q < 8; ++q) uu[q] = *(const uint2*)&h1f[(ss[q] << 7) + c0];
                #pragma unroll
                for (int q = 0; q < 8; ++q) edge(ee[q], uu[q], k + q < cnt);
            }
            for (; k < kmax; k += 4) {
                uint32 ss[4]; float ee[4]; uint2 uu[4];
                #pragma unroll
                for (int q = 0; q < 4; ++q) {
                    int j = beg + k + q;
                    int jc = (j < end) ? j : (end - 1);
                    ss[q] = (uint32)csr_src[jc];
                }
                #pragma unroll
                for (int q = 0; q < 4; ++q) ee[q] = a_src[ss[q] * 8u + h];
                #pragma unroll
                for (int q = 0; q < 4; ++q) uu[q] = *(const uint2*)&h1f[(ss[q] << 7) + c0];
                #pragma unroll
                for (int q = 0; q < 4; ++q) edge(ee[q], uu[q], k + q < cnt);
            }

            float inv = 1.f / (l + 1e-16f);
            float v0 = a0 * inv + b1[c0 + 0];
            float v1 = a1 * inv + b1[c0 + 1];
            float v2 = a2 * inv + b1[c0 + 2];
            float v3 = a3 * inv + b1[c0 + 3];
            float v4 = a4 * inv + b1[c0 + 4];
            float v5 = a5 * inv + b1[c0 + 5];
            float v6 = a6 * inv + b1[c0 + 6];
            float v7 = a7 * inv + b1[c0 + 7];
            v0 = v0 > 0.f ? v0 : (__expf(v0) - 1.f);   // ELU
            v1 = v1 > 0.f ? v1 : (__expf(v1) - 1.f);
            v2 = v2 > 0.f ? v2 : (__expf(v2) - 1.f);
            v3 = v3 > 0.f ? v3 : (__expf(v3) - 1.f);
            v4 = v4 > 0.f ? v4 : (__expf(v4) - 1.f);
            v5 = v5 > 0.f ? v5 : (__expf(v5) - 1.f);
            v6 = v6 > 0.f ? v6 : (__expf(v6) - 1.f);
            v7 = v7 > 0.f ? v7 : (__expf(v7) - 1.f);
            uint4 packed;
            packed.x = (uint32)f2bf(v0) | ((uint32)f2bf(v1) << 16);
            packed.y = (uint32)f2bf(v2) | ((uint32)f2bf(v3) << 16);
            packed.z = (uint32)f2bf(v4) | ((uint32)f2bf(v5) << 16);
            packed.w = (uint32)f2bf(v6) | ((uint32)f2bf(v7) << 16);
            uint32 g = lane16 ^ ((uint32)n_local & 15u);   // swizzled granule
            *(uint4*)&ha[n_local][g * 8] = packed;
        }
    }
    __syncthreads();

    // ---------- phase B: layer-2 transform from LDS ----------
    {
        int l15 = (int)lane16, quad = (int)quarter;
        int n0 = n0blk + w * 16;
        int nloc = w * 16 + l15;

        bf16x8 af[4];
        #pragma unroll
        for (int s = 0; s < 4; ++s) {
            uint32 g = (uint32)(s * 4 + quad) ^ (uint32)l15;
            af[s] = *(const bf16x8*)&ha[nloc][g * 8];
        }

        #pragma unroll
        for (int tt = 0; tt < 5; ++tt) {
            const unsigned short* Brow = (tt < 4) ? &w2t[(tt * 16 + l15) * HID]
                                                  : &p2t[l15 * HID];
            f32x4 acc = {0.f, 0.f, 0.f, 0.f};
            #pragma unroll
            for (int s = 0; s < 4; ++s) {
                bf16x8 bf = *(const bf16x8*)&Brow[s * 32 + quad * 8];
                acc = __builtin_amdgcn_mfma_f32_16x16x32_bf16(af[s], bf, acc, 0, 0, 0);
            }
            int nodeb = n0 + quad * 4;
            if (tt < 4) {
                int ch = tt * 16 + l15;
                #pragma unroll
                for (int r = 0; r < 4; ++r)
                    if (nodeb + r < N_NODES)
                        h2b[(size_t)(nodeb + r) * OUT_DIM + ch] = f2bf(acc[r]);
            } else {
                #pragma unroll
                for (int r = 0; r < 4; ++r) {
                    if (nodeb + r < N_NODES) {
                        if (l15 == 0) a_src2[nodeb + r] = acc[r];
                        else if (l15 == 1) a_dst2[nodeb + r] = acc[r];
                    }
                }
            }
        }
    }
}

// ---------------- Layer 2: aggregate + log_softmax ----------------
// 4 nodes per wave (16 lanes/node, 4 ch/lane, uint2 gathers); 8 nodes/block
// rank-sorted by degree so each wave gets rank-adjacent nodes.

__global__ __launch_bounds__(128) void l2_aggregate(
        const unsigned short* __restrict__ h2b, const float* __restrict__ a_src2,
        const float* __restrict__ a_dst2, const int* __restrict__ row_start,
        const int* __restrict__ csr_src, const float* __restrict__ b2,
        float* __restrict__ out) {
    __shared__ int sdeg8[8];
    __shared__ int perm8[8];
    int t = threadIdx.x;
    int w = t >> 6;
    uint32 lane = t & 63;
    uint32 quarter = lane >> 4;
    uint32 lane16 = lane & 15;
    int nbase = blockIdx.x * 8;
    if (t < 8)
        sdeg8[t] = row_start[nbase + t + 1] - row_start[nbase + t];
    __syncthreads();
    if (t < 8) {
        int d = sdeg8[t];
        int r = 0;
        #pragma unroll
        for (int j = 0; j < 8; ++j) {
            int dj = sdeg8[j];
            r += (dj < d) || (dj == d && j < t);
        }
        perm8[r] = t;
    }
    __syncthreads();
    int n = nbase + perm8[w * 4 + (int)quarter];
    uint32 c0 = lane16 * 4u;
    int beg = row_start[n], end = row_start[n + 1];
    int cnt = end - beg;
    int kmax = cnt;
    kmax = max(kmax, __shfl_xor(kmax, 16, 64));
    kmax = max(kmax, __shfl_xor(kmax, 32, 64));
    float adst = a_dst2[n];
    float l = 0.f, a0 = 0.f, a1 = 0.f, a2 = 0.f, a3 = 0.f;

    for (int k = 0; k < kmax; k += 4) {
        uint32 ss[4]; float ee[4]; uint2 uu[4];
        #pragma unroll
        for (int q = 0; q < 4; ++q) {
            int j = beg + k + q;
            int jc = (j < end) ? j : (end - 1);
            ss[q] = (uint32)csr_src[jc];
        }
        #pragma unroll
        for (int q = 0; q < 4; ++q) ee[q] = a_src2[ss[q]];
        #pragma unroll
        for (int q = 0; q < 4; ++q) uu[q] = *(const uint2*)&h2b[(ss[q] << 6) + c0];
        #pragma unroll
        for (int q = 0; q < 4; ++q) {
            float e = ee[q] + adst;
            e = fmaxf(e, NEG_SLOPE * e);
            e = (k + q < cnt) ? e : -10000.f;   // masked lane -> p = 0
            float p = exp2f(e);
            l += p;
            a0 = fmaf(p, __uint_as_float(uu[q].x << 16), a0);
            a1 = fmaf(p, __uint_as_float(uu[q].x & 0xFFFF0000u), a1);
            a2 = fmaf(p, __uint_as_float(uu[q].y << 16), a2);
            a3 = fmaf(p, __uint_as_float(uu[q].y & 0xFFFF0000u), a3);
        }
    }

    float inv = 1.f / (l + 1e-16f);
    float o0 = a0 * inv + b2[c0 + 0];
    float o1 = a1 * inv + b2[c0 + 1];
    float o2 = a2 * inv + b2[c0 + 2];
    float o3 = a3 * inv + b2[c0 + 3];
    // log_softmax over 64 channels = 16 lanes x 4 (quarter-wave reduction)
    float mx = fmaxf(fmaxf(o0, o1), fmaxf(o2, o3));
    #pragma unroll
    for (int m = 8; m > 0; m >>= 1) mx = fmaxf(mx, __shfl_xor(mx, m, 16));
    float ex = __expf(o0 - mx) + __expf(o1 - mx) + __expf(o2 - mx) + __expf(o3 - mx);
    #pragma unroll
    for (int m = 8; m > 0; m >>= 1) ex += __shfl_xor(ex, m, 16);
    float lse = mx + __logf(ex);
    float4 o = make_float4(o0 - lse, o1 - lse, o2 - lse, o3 - lse);
    *(float4*)&out[(size_t)n * OUT_DIM + c0] = o;
}

// ---------------- launch ----------------

extern "C" void kernel_launch(void* const* d_in, const int* in_sizes, int n_in,
                              void* d_out, int out_size, void* d_ws, size_t ws_size,
                              hipStream_t stream) {
    const float* x   = (const float*)d_in[0];
    const int*   ei  = (const int*)d_in[1];
    const float* W1  = (const float*)d_in[2];
    const float* as1 = (const float*)d_in[3];
    const float* ad1 = (const float*)d_in[4];
    const float* b1  = (const float*)d_in[5];
    const float* W2  = (const float*)d_in[6];
    const float* as2 = (const float*)d_in[7];
    const float* ad2 = (const float*)d_in[8];
    const float* b2  = (const float*)d_in[9];
    float* out = (float*)d_out;

    const int* src = ei;             // row 0
    const int* dst = ei + E_EDGES;   // row 1

    char* ws = (char*)d_ws;
    size_t off = 0;
    auto alloc = [&](size_t bytes) -> void* {
        void* p = ws + off;
        off += (bytes + 255) & ~size_t(255);
        return p;
    };
    unsigned short* xb     = (unsigned short*)alloc((size_t)N_NODES * IN_DIM * 2);
    unsigned char*  h1f    = (unsigned char*)alloc((size_t)N_NODES * HID);
    unsigned short* h2b    = (unsigned short*)alloc((size_t)N_NODES * OUT_DIM * 2);
    unsigned short* w1t    = (unsigned short*)alloc((size_t)HID * IN_DIM * 2);
    unsigned short* p1t    = (unsigned short*)alloc((size_t)16 * IN_DIM * 2);
    unsigned short* w2t    = (unsigned short*)alloc((size_t)OUT_DIM * HID * 2);
    unsigned short* p2t    = (unsigned short*)alloc((size_t)16 * HID * 2);
    float* a_src1    = (float*)alloc((size_t)N_NODES * HEADS * 4);
    float* a_dst1    = (float*)alloc((size_t)N_NODES * HEADS * 4);
    float* a_src2    = (float*)alloc((size_t)N_NODES * 4);
    float* a_dst2    = (float*)alloc((size_t)N_NODES * 4);
    int*   row_start = (int*)alloc((size_t)(N_NODES + 1) * 4);
    int*   csr_src   = (int*)alloc((size_t)ET * 4);
    uint32* pairs    = (uint32*)alloc((size_t)ET * 4);
    int*   cnt       = (int*)alloc((size_t)NB * NT * 4);
    int*   bucketStart = (int*)alloc((size_t)(NB + 1) * 4);

    prep_all<<<MEGA_A, 256, 0, stream>>>(dst, cnt, x, xb, W1, as1, ad1,
                                         W2, as2, ad2, w1t, p1t, w2t, p2t);
    bucket_scatter<<<NT, 256, 0, stream>>>(src, dst, cnt, bucketStart, pairs);
    build_l1t<<<MEGA_B, 256, 0, stream>>>(pairs, bucketStart, row_start, csr_src,
                                          xb, w1t, p1t, h1f, a_src1, a_dst1);
    l1agg_l2t<<<FUSE_BLOCKS, 128, 0, stream>>>(h1f, a_src1, a_dst1, row_start, csr_src,
                                               b1, w2t, p2t, h2b, a_src2, a_dst2);
    l2_aggregate<<<N_NODES / 8, 128, 0, stream>>>(h2b, a_src2, a_dst2, row_start, csr_src, b2, out);
}

// Round 21
// 196.539 us; speedup vs baseline: 1.1287x; 1.0126x over previous
//
#include <hip/hip_runtime.h>
#include <math.h>

#define N_NODES 50000
#define E_EDGES 800000
#define ET      (E_EDGES + N_NODES)   // edges + self loops
#define IN_DIM  128
#define HID     128
#define HEADS   8
#define C1      16
#define OUT_DIM 64
#define NEG_SLOPE 0.2f
#define LOG2E   1.4426950408889634f

#define TILE    8192
#define NT      ((ET + TILE - 1) / TILE)      // 104 tiles
#define NB      ((N_NODES + 255) / 256)       // 196 buckets of 256 nodes

#define CONV_BLOCKS (N_NODES * IN_DIM / 4 / 256)   // 6250
#define PREP_BLOCKS 112
#define MEGA_A (NT + CONV_BLOCKS + PREP_BLOCKS)    // 6466
#define L1T_BLOCKS ((N_NODES + 63) / 64)           // 782
#define MEGA_B (NB + L1T_BLOCKS)                   // 978
#define FUSE_BLOCKS ((N_NODES + 31) / 32)          // 1563

typedef unsigned int uint32;
typedef __attribute__((ext_vector_type(8))) short bf16x8;
typedef __attribute__((ext_vector_type(4))) float f32x4;
typedef __attribute__((ext_vector_type(2))) float f32x2;

static __device__ __forceinline__ unsigned short f2bf(float f) {
    uint32 u = __float_as_uint(f);
    u += 0x7FFFu + ((u >> 16) & 1u);   // round to nearest even
    return (unsigned short)(u >> 16);
}

static __device__ __forceinline__ unsigned char f2fp8(float f) {
    int pk = __builtin_amdgcn_cvt_pk_fp8_f32(f, f, 0, false);   // RNE, OCP e4m3
    return (unsigned char)(pk & 0xFF);
}

// ---------------- Mega-kernel A: bucket_hist + convert_x + prep_weights ----------------

__global__ __launch_bounds__(256) void prep_all(
        const int* __restrict__ dst, int* __restrict__ cnt,
        const float* __restrict__ x, unsigned short* __restrict__ xb,
        const float* __restrict__ W1, const float* __restrict__ as1,
        const float* __restrict__ ad1, const float* __restrict__ W2,
        const float* __restrict__ as2, const float* __restrict__ ad2,
        unsigned short* __restrict__ w1t, unsigned short* __restrict__ p1t,
        unsigned short* __restrict__ w2t, unsigned short* __restrict__ p2t) {
    __shared__ int hist[NB];
    int blk = blockIdx.x, t = threadIdx.x;
    if (blk < NT) {
        for (int b = t; b < NB; b += 256) hist[b] = 0;
        __syncthreads();
        int base = blk * TILE;
        #pragma unroll
        for (int it = 0; it < TILE / 256; ++it) {
            int i = base + it * 256 + t;
            if (i < ET) {
                int d = (i < E_EDGES) ? dst[i] : (i - E_EDGES);
                atomicAdd(&hist[d >> 8], 1);
            }
        }
        __syncthreads();
        for (int b = t; b < NB; b += 256) cnt[blk * NB + b] = hist[b];
    } else if (blk < NT + CONV_BLOCKS) {
        int i = (blk - NT) * 256 + t;
        float4 v = ((const float4*)x)[i];
        ushort4 o;
        o.x = f2bf(v.x); o.y = f2bf(v.y); o.z = f2bf(v.z); o.w = f2bf(v.w);
        ((ushort4*)xb)[i] = o;
    } else {
        int b = blk - NT - CONV_BLOCKS;    // 0..111
        if (b < 64) {
            int i = b * 256 + t;                // n*128+k
            int n = i >> 7, k = i & 127;
            w1t[n * IN_DIM + k] = f2bf(W1[k * HID + n]);
        } else if (b < 96) {
            int i = (b - 64) * 256 + t;         // n*128+k, n<64
            int n = i >> 7, k = i & 127;
            w2t[n * HID + k] = f2bf(W2[k * OUT_DIM + n]);
        } else if (b < 104) {
            int i = (b - 96) * 256 + t;         // j*128+k, j<16
            int j = i >> 7, k = i & 127;
            int hh = j & 7;
            const float* a = (j < 8) ? as1 : ad1;
            float acc = 0.f;
            #pragma unroll
            for (int c = 0; c < C1; ++c)
                acc = fmaf(W1[k * HID + hh * C1 + c], a[hh * C1 + c], acc);
            p1t[j * IN_DIM + k] = f2bf(acc * LOG2E);
        } else {
            int i = (b - 104) * 256 + t;        // j*128+k, j<16
            int j = i >> 7, k = i & 127;
            if (j < 2) {
                const float* a = (j == 0) ? as2 : ad2;
                float acc = 0.f;
                #pragma unroll
                for (int c = 0; c < OUT_DIM; ++c)
                    acc = fmaf(W2[k * OUT_DIM + c], a[c], acc);
                p2t[j * HID + k] = f2bf(acc * LOG2E);
            } else {
                p2t[j * HID + k] = 0;
            }
        }
    }
}

// ---------------- bucket_scatter (scan fused in) ----------------

__global__ __launch_bounds__(256) void bucket_scatter(
        const int* __restrict__ src, const int* __restrict__ dst,
        const int* __restrict__ cnt, int* __restrict__ bucketStart,
        uint32* __restrict__ pairs) {
    __shared__ int lcur[NB];
    __shared__ int sscan[256];
    int t = threadIdx.x;
    int tile = blockIdx.x;

    int run = 0, total = 0;
    if (t < NB) {
        for (int k = 0; k < NT; ++k) {
            int c = cnt[k * NB + t];     // coalesced across t
            if (k < tile) run += c;
            total += c;
        }
    }
    sscan[t] = (t < NB) ? total : 0;
    __syncthreads();
    #pragma unroll
    for (int off = 1; off < 256; off <<= 1) {
        int add = (t >= off) ? sscan[t - off] : 0;
        __syncthreads();
        sscan[t] += add;
        __syncthreads();
    }
    int bstart = sscan[t] - total;       // exclusive prefix
    if (t < NB) {
        lcur[t] = bstart + run;
        if (tile == 0) bucketStart[t] = bstart;
    }
    if (tile == 0 && t == 0) bucketStart[NB] = ET;
    __syncthreads();

    int base = tile * TILE;
    #pragma unroll
    for (int it = 0; it < TILE / 256; ++it) {
        int i = base + it * 256 + t;
        if (i < ET) {
            int s, d;
            if (i < E_EDGES) { s = src[i]; d = dst[i]; }
            else             { s = d = i - E_EDGES; }
            int pos = atomicAdd(&lcur[d >> 8], 1);
            pairs[pos] = ((uint32)s << 8) | (uint32)(d & 255);
        }
    }
}

// ---------------- Mega-kernel B: bucket_build + l1_transform_mfma ----------------
// h1 payload stored as fp8 e4m3 (HW cvt, RNE): 128 B/node.

__global__ __launch_bounds__(256) void build_l1t(
        const uint32* __restrict__ pairs, const int* __restrict__ bucketStart,
        int* __restrict__ row_start, int* __restrict__ csr_src,
        const unsigned short* __restrict__ xb, const unsigned short* __restrict__ w1t,
        const unsigned short* __restrict__ p1t, unsigned char* __restrict__ h1f,
        float* __restrict__ a_src, float* __restrict__ a_dst) {
    __shared__ int sdeg[256];
    __shared__ int sscan[256];
    int t = threadIdx.x;
    if (blockIdx.x < NB) {
        int b = blockIdx.x;
        int beg = bucketStart[b], end = bucketStart[b + 1];
        sdeg[t] = 0;
        __syncthreads();
        for (int j = beg + t; j < end; j += 256)
            atomicAdd(&sdeg[pairs[j] & 255u], 1);
        __syncthreads();
        int v = sdeg[t];
        sscan[t] = v;
        __syncthreads();
        #pragma unroll
        for (int off = 1; off < 256; off <<= 1) {
            int add = (t >= off) ? sscan[t - off] : 0;
            __syncthreads();
            sscan[t] += add;
            __syncthreads();
        }
        int pos0 = beg + sscan[t] - v;   // exclusive prefix within bucket
        int n = b * 256 + t;
        if (n < N_NODES) row_start[n] = pos0;
        if (b == 0 && t == 0) row_start[N_NODES] = ET;
        __syncthreads();
        sscan[t] = pos0;                 // reuse as cursor
        __syncthreads();
        for (int j = beg + t; j < end; j += 256) {
            uint32 p = pairs[j];
            int pos = atomicAdd(&sscan[p & 255u], 1);
            csr_src[pos] = (int)(p >> 8);
        }
        return;
    }
    // ---- layer-1 transform via MFMA, LDS-free ----
    int bb = blockIdx.x - NB;
    int w = t >> 6, lane = t & 63;
    int l15 = lane & 15, quad = lane >> 4;
    int n0 = bb * 64 + w * 16;
    int mrow = n0 + l15;
    int mload = (mrow < N_NODES) ? mrow : (N_NODES - 1);

    bf16x8 af[4];
    #pragma unroll
    for (int s = 0; s < 4; ++s)
        af[s] = *(const bf16x8*)&xb[(size_t)mload * IN_DIM + s * 32 + quad * 8];

    #pragma unroll
    for (int tt = 0; tt < 9; ++tt) {
        const unsigned short* Brow = (tt < 8) ? &w1t[(tt * 16 + l15) * IN_DIM]
                                              : &p1t[l15 * IN_DIM];
        f32x4 acc = {0.f, 0.f, 0.f, 0.f};
        #pragma unroll
        for (int s = 0; s < 4; ++s) {
            bf16x8 bf = *(const bf16x8*)&Brow[s * 32 + quad * 8];
            acc = __builtin_amdgcn_mfma_f32_16x16x32_bf16(af[s], bf, acc, 0, 0, 0);
        }
        int nodeb = n0 + quad * 4;
        if (tt < 8) {
            int ch = tt * 16 + l15;
            #pragma unroll
            for (int r = 0; r < 4; ++r)
                if (nodeb + r < N_NODES)
                    h1f[(size_t)(nodeb + r) * HID + ch] = f2fp8(acc[r]);
        } else {
            #pragma unroll
            for (int r = 0; r < 4; ++r) {
                if (nodeb + r < N_NODES) {
                    if (l15 < 8) a_src[(nodeb + r) * HEADS + l15] = acc[r];
                    else         a_dst[(nodeb + r) * HEADS + (l15 - 8)] = acc[r];
                }
            }
        }
    }
}

// ---------------- Fused: layer-1 aggregate + layer-2 transform ----------------
// 256-thread block (4 waves) on a 32-node tile: phase A = 2 passes/wave
// (8 nodes serial per wave -> 6250 waves, ~24 waves/CU). Rank-grouped nodes,
// 8-deep unroll, fp8 gathers. Phase B: rg = w>>1, u = w&1; wave u=0 does
// tiles {0,2,4}, u=1 does {1,3} for its 16-row group.

__global__ __launch_bounds__(256) void l1agg_l2t(
        const unsigned char* __restrict__ h1f, const float* __restrict__ a_src,
        const float* __restrict__ a_dst, const int* __restrict__ row_start,
        const int* __restrict__ csr_src, const float* __restrict__ b1,
        const unsigned short* __restrict__ w2t, const unsigned short* __restrict__ p2t,
        unsigned short* __restrict__ h2b, float* __restrict__ a_src2,
        float* __restrict__ a_dst2) {
    __shared__ unsigned short ha[32][128];   // 8 KB, swizzled granules
    __shared__ int sdeg32[32];
    __shared__ unsigned char perm[32];
    int t = threadIdx.x;
    int w = t >> 6;              // 0..3
    uint32 lane = t & 63;
    uint32 quarter = lane >> 4;
    uint32 lane16 = lane & 15;
    int n0blk = blockIdx.x * 32;

    // ---- degree-rank the 32 nodes (once per block) ----
    if (t < 32) {
        int n = n0blk + t;
        int nc = (n < N_NODES) ? n : (N_NODES - 1);
        sdeg32[t] = row_start[nc + 1] - row_start[nc];
    }
    __syncthreads();
    if (t < 32) {
        int d = sdeg32[t];
        int r = 0;
        #pragma unroll
        for (int j = 0; j < 32; ++j) {
            int dj = sdeg32[j];
            r += (dj < d) || (dj == d && j < t);
        }
        perm[r] = (unsigned char)t;
    }
    __syncthreads();

    // ---------- phase A: 4 waves x 2 passes x 4 nodes ----------
    {
        uint32 c0 = lane16 * 8u;     // 8 channels per lane (8 fp8 bytes)
        uint32 h = lane16 >> 1;      // head = c0 >> 4
        #pragma unroll
        for (int pass = 0; pass < 2; ++pass) {
            int u = pass * 4 + w;                       // work unit 0..7
            int n_local = (int)perm[u * 4 + (int)quarter];
            int n = n0blk + n_local;
            int nc = (n < N_NODES) ? n : (N_NODES - 1);
            int beg = row_start[nc], end = row_start[nc + 1];
            int cnt = end - beg;
            int kmax = cnt;
            kmax = max(kmax, __shfl_xor(kmax, 16, 64));
            kmax = max(kmax, __shfl_xor(kmax, 32, 64));
            float adst = a_dst[nc * HEADS + h];
            float l = 0.f;
            float a0 = 0.f, a1 = 0.f, a2 = 0.f, a3 = 0.f;
            float a4 = 0.f, a5 = 0.f, a6 = 0.f, a7 = 0.f;

            auto edge = [&](float e0, uint2 u0, bool live) {
                float e = e0 + adst;
                e = fmaxf(e, NEG_SLOPE * e);          // leaky relu (log2 domain)
                e = live ? e : -10000.f;              // masked lane -> p = 0
                float p = exp2f(e);
                l += p;
                f32x2 f01 = __builtin_amdgcn_cvt_pk_f32_fp8((int)u0.x, false);
                f32x2 f23 = __builtin_amdgcn_cvt_pk_f32_fp8((int)u0.x, true);
                f32x2 f45 = __builtin_amdgcn_cvt_pk_f32_fp8((int)u0.y, false);
                f32x2 f67 = __builtin_amdgcn_cvt_pk_f32_fp8((int)u0.y, true);
                a0 = fmaf(p, f01[0], a0);
                a1 = fmaf(p, f01[1], a1);
                a2 = fmaf(p, f23[0], a2);
                a3 = fmaf(p, f23[1], a3);
                a4 = fmaf(p, f45[0], a4);
                a5 = fmaf(p, f45[1], a5);
                a6 = fmaf(p, f67[0], a6);
                a7 = fmaf(p, f67[1], a7);
            };

            int k = 0;
            for (; k + 8 <= kmax; k += 8) {
                uint32 ss[8]; float ee[8]; uint2 uu[8];
                #pragma unroll
                for (int q = 0; q < 8; ++q) {
                    int j = beg + k + q;
                    int jc = (j < end) ? j : (end - 1);    // cnt >= 1 (self loop)
                    ss[q] = (uint32)csr_src[jc];
                }
                #pragma unroll
                for (int q = 0; q < 8; ++q) ee[q] = a_src[ss[q] * 8u + h];
                #pragma unroll
                for (int q = 0; q < 8; ++q) uu[q] = *(const uint2*)&h1f[(ss[q] << 7) + c0];
                #pragma unroll
                for (int q = 0; q < 8; ++q) edge(ee[q], uu[q], k + q < cnt);
            }
            for (; k < kmax; k += 4) {
                uint32 ss[4]; float ee[4]; uint2 uu[4];
                #pragma unroll
                for (int q = 0; q < 4; ++q) {
                    int j = beg + k + q;
                    int jc = (j < end) ? j : (end - 1);
                    ss[q] = (uint32)csr_src[jc];
                }
                #pragma unroll
                for (int q = 0; q < 4; ++q) ee[q] = a_src[ss[q] * 8u + h];
                #pragma unroll
                for (int q = 0; q < 4; ++q) uu[q] = *(const uint2*)&h1f[(ss[q] << 7) + c0];
                #pragma unroll
                for (int q = 0; q < 4; ++q) edge(ee[q], uu[q], k + q < cnt);
            }

            float inv = 1.f / (l + 1e-16f);
            float v0 = a0 * inv + b1[c0 + 0];
            float v1 = a1 * inv + b1[c0 + 1];
            float v2 = a2 * inv + b1[c0 + 2];
            float v3 = a3 * inv + b1[c0 + 3];
            float v4 = a4 * inv + b1[c0 + 4];
            float v5 = a5 * inv + b1[c0 + 5];
            float v6 = a6 * inv + b1[c0 + 6];
            float v7 = a7 * inv + b1[c0 + 7];
            v0 = v0 > 0.f ? v0 : (__expf(v0) - 1.f);   // ELU
            v1 = v1 > 0.f ? v1 : (__expf(v1) - 1.f);
            v2 = v2 > 0.f ? v2 : (__expf(v2) - 1.f);
            v3 = v3 > 0.f ? v3 : (__expf(v3) - 1.f);
            v4 = v4 > 0.f ? v4 : (__expf(v4) - 1.f);
            v5 = v5 > 0.f ? v5 : (__expf(v5) - 1.f);
            v6 = v6 > 0.f ? v6 : (__expf(v6) - 1.f);
            v7 = v7 > 0.f ? v7 : (__expf(v7) - 1.f);
            uint4 packed;
            packed.x = (uint32)f2bf(v0) | ((uint32)f2bf(v1) << 16);
            packed.y = (uint32)f2bf(v2) | ((uint32)f2bf(v3) << 16);
            packed.z = (uint32)f2bf(v4) | ((uint32)f2bf(v5) << 16);
            packed.w = (uint32)f2bf(v6) | ((uint32)f2bf(v7) << 16);
            uint32 g = lane16 ^ ((uint32)n_local & 15u);   // swizzled granule
            *(uint4*)&ha[n_local][g * 8] = packed;
        }
    }
    __syncthreads();

    // ---------- phase B: layer-2 transform from LDS, tt split across wave pairs ----------
    {
        int rg = w >> 1, u = w & 1;
        int l15 = (int)lane16, quad = (int)quarter;
        int n0 = n0blk + rg * 16;
        int nloc = rg * 16 + l15;

        bf16x8 af[4];
        #pragma unroll
        for (int s = 0; s < 4; ++s) {
            uint32 g = (uint32)(s * 4 + quad) ^ (uint32)l15;
            af[s] = *(const bf16x8*)&ha[nloc][g * 8];
        }

        #pragma unroll
        for (int pass = 0; pass < 3; ++pass) {
            int tt;
            if (pass == 0) tt = u;
            else if (pass == 1) tt = u + 2;
            else { if (u != 0) break; tt = 4; }
            const unsigned short* Brow = (tt < 4) ? &w2t[(tt * 16 + l15) * HID]
                                                  : &p2t[l15 * HID];
            f32x4 acc = {0.f, 0.f, 0.f, 0.f};
            #pragma unroll
            for (int s = 0; s < 4; ++s) {
                bf16x8 bf = *(const bf16x8*)&Brow[s * 32 + quad * 8];
                acc = __builtin_amdgcn_mfma_f32_16x16x32_bf16(af[s], bf, acc, 0, 0, 0);
            }
            int nodeb = n0 + quad * 4;
            if (tt < 4) {
                int ch = tt * 16 + l15;
                #pragma unroll
                for (int r = 0; r < 4; ++r)
                    if (nodeb + r < N_NODES)
                        h2b[(size_t)(nodeb + r) * OUT_DIM + ch] = f2bf(acc[r]);
            } else {
                #pragma unroll
                for (int r = 0; r < 4; ++r) {
                    if (nodeb + r < N_NODES) {
                        if (l15 == 0) a_src2[nodeb + r] = acc[r];
                        else if (l15 == 1) a_dst2[nodeb + r] = acc[r];
                    }
                }
            }
        }
    }
}

// ---------------- Layer 2: aggregate + log_softmax ----------------
// 4 nodes per wave (16 lanes/node, 4 ch/lane, uint2 gathers); 8 nodes/block
// rank-sorted by degree so each wave gets rank-adjacent nodes.

__global__ __launch_bounds__(128) void l2_aggregate(
        const unsigned short* __restrict__ h2b, const float* __restrict__ a_src2,
        const float* __restrict__ a_dst2, const int* __restrict__ row_start,
        const int* __restrict__ csr_src, const float* __restrict__ b2,
        float* __restrict__ out) {
    __shared__ int sdeg8[8];
    __shared__ int perm8[8];
    int t = threadIdx.x;
    int w = t >> 6;
    uint32 lane = t & 63;
    uint32 quarter = lane >> 4;
    uint32 lane16 = lane & 15;
    int nbase = blockIdx.x * 8;
    if (t < 8)
        sdeg8[t] = row_start[nbase + t + 1] - row_start[nbase + t];
    __syncthreads();
    if (t < 8) {
        int d = sdeg8[t];
        int r = 0;
        #pragma unroll
        for (int j = 0; j < 8; ++j) {
            int dj = sdeg8[j];
            r += (dj < d) || (dj == d && j < t);
        }
        perm8[r] = t;
    }
    __syncthreads();
    int n = nbase + perm8[w * 4 + (int)quarter];
    uint32 c0 = lane16 * 4u;
    int beg = row_start[n], end = row_start[n + 1];
    int cnt = end - beg;
    int kmax = cnt;
    kmax = max(kmax, __shfl_xor(kmax, 16, 64));
    kmax = max(kmax, __shfl_xor(kmax, 32, 64));
    float adst = a_dst2[n];
    float l = 0.f, a0 = 0.f, a1 = 0.f, a2 = 0.f, a3 = 0.f;

    for (int k = 0; k < kmax; k += 4) {
        uint32 ss[4]; float ee[4]; uint2 uu[4];
        #pragma unroll
        for (int q = 0; q < 4; ++q) {
            int j = beg + k + q;
            int jc = (j < end) ? j : (end - 1);
            ss[q] = (uint32)csr_src[jc];
        }
        #pragma unroll
        for (int q = 0; q < 4; ++q) ee[q] = a_src2[ss[q]];
        #pragma unroll
        for (int q = 0; q < 4; ++q) uu[q] = *(const uint2*)&h2b[(ss[q] << 6) + c0];
        #pragma unroll
        for (int q = 0; q < 4; ++q) {
            float e = ee[q] + adst;
            e = fmaxf(e, NEG_SLOPE * e);
            e = (k + q < cnt) ? e : -10000.f;   // masked lane -> p = 0
            float p = exp2f(e);
            l += p;
            a0 = fmaf(p, __uint_as_float(uu[q].x << 16), a0);
            a1 = fmaf(p, __uint_as_float(uu[q].x & 0xFFFF0000u), a1);
            a2 = fmaf(p, __uint_as_float(uu[q].y << 16), a2);
            a3 = fmaf(p, __uint_as_float(uu[q].y & 0xFFFF0000u), a3);
        }
    }

    float inv = 1.f / (l + 1e-16f);
    float o0 = a0 * inv + b2[c0 + 0];
    float o1 = a1 * inv + b2[c0 + 1];
    float o2 = a2 * inv + b2[c0 + 2];
    float o3 = a3 * inv + b2[c0 + 3];
    // log_softmax over 64 channels = 16 lanes x 4 (quarter-wave reduction)
    float mx = fmaxf(fmaxf(o0, o1), fmaxf(o2, o3));
    #pragma unroll
    for (int m = 8; m > 0; m >>= 1) mx = fmaxf(mx, __shfl_xor(mx, m, 16));
    float ex = __expf(o0 - mx) + __expf(o1 - mx) + __expf(o2 - mx) + __expf(o3 - mx);
    #pragma unroll
    for (int m = 8; m > 0; m >>= 1) ex += __shfl_xor(ex, m, 16);
    float lse = mx + __logf(ex);
    float4 o = make_float4(o0 - lse, o1 - lse, o2 - lse, o3 - lse);
    *(float4*)&out[(size_t)n * OUT_DIM + c0] = o;
}

// ---------------- launch ----------------

extern "C" void kernel_launch(void* const* d_in, const int* in_sizes, int n_in,
                              void* d_out, int out_size, void* d_ws, size_t ws_size,
                              hipStream_t stream) {
    const float* x   = (const float*)d_in[0];
    const int*   ei  = (const int*)d_in[1];
    const float* W1  = (const float*)d_in[2];
    const float* as1 = (const float*)d_in[3];
    const float* ad1 = (const float*)d_in[4];
    const float* b1  = (const float*)d_in[5];
    const float* W2  = (const float*)d_in[6];
    const float* as2 = (const float*)d_in[7];
    const float* ad2 = (const float*)d_in[8];
    const float* b2  = (const float*)d_in[9];
    float* out = (float*)d_out;

    const int* src = ei;             // row 0
    const int* dst = ei + E_EDGES;   // row 1

    char* ws = (char*)d_ws;
    size_t off = 0;
    auto alloc = [&](size_t bytes) -> void* {
        void* p = ws + off;
        off += (bytes + 255) & ~size_t(255);
        return p;
    };
    unsigned short* xb     = (unsigned short*)alloc((size_t)N_NODES * IN_DIM * 2);
    unsigned char*  h1f    = (unsigned char*)alloc((size_t)N_NODES * HID);
    unsigned short* h2b    = (unsigned short*)alloc((size_t)N_NODES * OUT_DIM * 2);
    unsigned short* w1t    = (unsigned short*)alloc((size_t)HID * IN_DIM * 2);
    unsigned short* p1t    = (unsigned short*)alloc((size_t)16 * IN_DIM * 2);
    unsigned short* w2t    = (unsigned short*)alloc((size_t)OUT_DIM * HID * 2);
    unsigned short* p2t    = (unsigned short*)alloc((size_t)16 * HID * 2);
    float* a_src1    = (float*)alloc((size_t)N_NODES * HEADS * 4);
    float* a_dst1    = (float*)alloc((size_t)N_NODES * HEADS * 4);
    float* a_src2    = (float*)alloc((size_t)N_NODES * 4);
    float* a_dst2    = (float*)alloc((size_t)N_NODES * 4);
    int*   row_start = (int*)alloc((size_t)(N_NODES + 1) * 4);
    int*   csr_src   = (int*)alloc((size_t)ET * 4);
    uint32* pairs    = (uint32*)alloc((size_t)ET * 4);
    int*   cnt       = (int*)alloc((size_t)NB * NT * 4);
    int*   bucketStart = (int*)alloc((size_t)(NB + 1) * 4);

    prep_all<<<MEGA_A, 256, 0, stream>>>(dst, cnt, x, xb, W1, as1, ad1,
                                         W2, as2, ad2, w1t, p1t, w2t, p2t);
    bucket_scatter<<<NT, 256, 0, stream>>>(src, dst, cnt, bucketStart, pairs);
    build_l1t<<<MEGA_B, 256, 0, stream>>>(pairs, bucketStart, row_start, csr_src,
                                          xb, w1t, p1t, h1f, a_src1, a_dst1);
    l1agg_l2t<<<FUSE_BLOCKS, 256, 0, stream>>>(h1f, a_src1, a_dst1, row_start, csr_src,
                                               b1, w2t, p2t, h2b, a_src2, a_dst2);
    l2_aggregate<<<N_NODES / 8, 128, 0, stream>>>(h2b, a_src2, a_dst2, row_start, csr_src, b2, out);
}

// Round 22
// 193.735 us; speedup vs baseline: 1.1450x; 1.0145x over previous
//
#include <hip/hip_runtime.h>
#include <math.h>

#define N_NODES 50000
#define E_EDGES 800000
#define ET      (E_EDGES + N_NODES)   // edges + self loops
#define IN_DIM  128
#define HID     128
#define HEADS   8
#define C1      16
#define OUT_DIM 64
#define NEG_SLOPE 0.2f
#define LOG2E   1.4426950408889634f

#define TILE    8192
#define NT      ((ET + TILE - 1) / TILE)      // 104 tiles
#define NB      ((N_NODES + 255) / 256)       // 196 buckets of 256 nodes

#define CONV_BLOCKS (N_NODES * IN_DIM / 4 / 256)   // 6250
#define PREP_BLOCKS 112
#define MEGA_A (NT + CONV_BLOCKS + PREP_BLOCKS)    // 6466
#define L1T_BLOCKS ((N_NODES + 63) / 64)           // 782
#define MEGA_B (NB + L1T_BLOCKS)                   // 978
#define FUSE_BLOCKS ((N_NODES + 15) / 16)          // 3125

typedef unsigned int uint32;
typedef __attribute__((ext_vector_type(8))) short bf16x8;
typedef __attribute__((ext_vector_type(4))) float f32x4;
typedef __attribute__((ext_vector_type(2))) float f32x2;

static __device__ __forceinline__ unsigned short f2bf(float f) {
    uint32 u = __float_as_uint(f);
    u += 0x7FFFu + ((u >> 16) & 1u);   // round to nearest even
    return (unsigned short)(u >> 16);
}

static __device__ __forceinline__ unsigned char f2fp8(float f) {
    int pk = __builtin_amdgcn_cvt_pk_fp8_f32(f, f, 0, false);   // RNE, OCP e4m3
    return (unsigned char)(pk & 0xFF);
}

// ---------------- Mega-kernel A: bucket_hist + convert_x + prep_weights ----------------

__global__ __launch_bounds__(256) void prep_all(
        const int* __restrict__ dst, int* __restrict__ cnt,
        const float* __restrict__ x, unsigned short* __restrict__ xb,
        const float* __restrict__ W1, const float* __restrict__ as1,
        const float* __restrict__ ad1, const float* __restrict__ W2,
        const float* __restrict__ as2, const float* __restrict__ ad2,
        unsigned short* __restrict__ w1t, unsigned short* __restrict__ p1t,
        unsigned short* __restrict__ w2t, unsigned short* __restrict__ p2t) {
    __shared__ int hist[NB];
    int blk = blockIdx.x, t = threadIdx.x;
    if (blk < NT) {
        for (int b = t; b < NB; b += 256) hist[b] = 0;
        __syncthreads();
        int base = blk * TILE;
        #pragma unroll
        for (int it = 0; it < TILE / 256; ++it) {
            int i = base + it * 256 + t;
            if (i < ET) {
                int d = (i < E_EDGES) ? dst[i] : (i - E_EDGES);
                atomicAdd(&hist[d >> 8], 1);
            }
        }
        __syncthreads();
        for (int b = t; b < NB; b += 256) cnt[blk * NB + b] = hist[b];
    } else if (blk < NT + CONV_BLOCKS) {
        int i = (blk - NT) * 256 + t;
        float4 v = ((const float4*)x)[i];
        ushort4 o;
        o.x = f2bf(v.x); o.y = f2bf(v.y); o.z = f2bf(v.z); o.w = f2bf(v.w);
        ((ushort4*)xb)[i] = o;
    } else {
        int b = blk - NT - CONV_BLOCKS;    // 0..111
        if (b < 64) {
            int i = b * 256 + t;                // n*128+k
            int n = i >> 7, k = i & 127;
            w1t[n * IN_DIM + k] = f2bf(W1[k * HID + n]);
        } else if (b < 96) {
            int i = (b - 64) * 256 + t;         // n*128+k, n<64
            int n = i >> 7, k = i & 127;
            w2t[n * HID + k] = f2bf(W2[k * OUT_DIM + n]);
        } else if (b < 104) {
            int i = (b - 96) * 256 + t;         // j*128+k, j<16
            int j = i >> 7, k = i & 127;
            int hh = j & 7;
            const float* a = (j < 8) ? as1 : ad1;
            float acc = 0.f;
            #pragma unroll
            for (int c = 0; c < C1; ++c)
                acc = fmaf(W1[k * HID + hh * C1 + c], a[hh * C1 + c], acc);
            p1t[j * IN_DIM + k] = f2bf(acc * LOG2E);
        } else {
            int i = (b - 104) * 256 + t;        // j*128+k, j<16
            int j = i >> 7, k = i & 127;
            if (j < 2) {
                const float* a = (j == 0) ? as2 : ad2;
                float acc = 0.f;
                #pragma unroll
                for (int c = 0; c < OUT_DIM; ++c)
                    acc = fmaf(W2[k * OUT_DIM + c], a[c], acc);
                p2t[j * HID + k] = f2bf(acc * LOG2E);
            } else {
                p2t[j * HID + k] = 0;
            }
        }
    }
}

// ---------------- bucket_scatter (scan fused in) ----------------

__global__ __launch_bounds__(256) void bucket_scatter(
        const int* __restrict__ src, const int* __restrict__ dst,
        const int* __restrict__ cnt, int* __restrict__ bucketStart,
        uint32* __restrict__ pairs) {
    __shared__ int lcur[NB];
    __shared__ int sscan[256];
    int t = threadIdx.x;
    int tile = blockIdx.x;

    int run = 0, total = 0;
    if (t < NB) {
        for (int k = 0; k < NT; ++k) {
            int c = cnt[k * NB + t];     // coalesced across t
            if (k < tile) run += c;
            total += c;
        }
    }
    sscan[t] = (t < NB) ? total : 0;
    __syncthreads();
    #pragma unroll
    for (int off = 1; off < 256; off <<= 1) {
        int add = (t >= off) ? sscan[t - off] : 0;
        __syncthreads();
        sscan[t] += add;
        __syncthreads();
    }
    int bstart = sscan[t] - total;       // exclusive prefix
    if (t < NB) {
        lcur[t] = bstart + run;
        if (tile == 0) bucketStart[t] = bstart;
    }
    if (tile == 0 && t == 0) bucketStart[NB] = ET;
    __syncthreads();

    int base = tile * TILE;
    #pragma unroll
    for (int it = 0; it < TILE / 256; ++it) {
        int i = base + it * 256 + t;
        if (i < ET) {
            int s, d;
            if (i < E_EDGES) { s = src[i]; d = dst[i]; }
            else             { s = d = i - E_EDGES; }
            int pos = atomicAdd(&lcur[d >> 8], 1);
            pairs[pos] = ((uint32)s << 8) | (uint32)(d & 255);
        }
    }
}

// ---------------- Mega-kernel B: bucket_build + l1_transform_mfma ----------------
// h1 payload stored as fp8 e4m3 (HW cvt, RNE): 128 B/node.

__global__ __launch_bounds__(256) void build_l1t(
        const uint32* __restrict__ pairs, const int* __restrict__ bucketStart,
        int* __restrict__ row_start, int* __restrict__ csr_src,
        const unsigned short* __restrict__ xb, const unsigned short* __restrict__ w1t,
        const unsigned short* __restrict__ p1t, unsigned char* __restrict__ h1f,
        float* __restrict__ a_src, float* __restrict__ a_dst) {
    __shared__ int sdeg[256];
    __shared__ int sscan[256];
    int t = threadIdx.x;
    if (blockIdx.x < NB) {
        int b = blockIdx.x;
        int beg = bucketStart[b], end = bucketStart[b + 1];
        sdeg[t] = 0;
        __syncthreads();
        for (int j = beg + t; j < end; j += 256)
            atomicAdd(&sdeg[pairs[j] & 255u], 1);
        __syncthreads();
        int v = sdeg[t];
        sscan[t] = v;
        __syncthreads();
        #pragma unroll
        for (int off = 1; off < 256; off <<= 1) {
            int add = (t >= off) ? sscan[t - off] : 0;
            __syncthreads();
            sscan[t] += add;
            __syncthreads();
        }
        int pos0 = beg + sscan[t] - v;   // exclusive prefix within bucket
        int n = b * 256 + t;
        if (n < N_NODES) row_start[n] = pos0;
        if (b == 0 && t == 0) row_start[N_NODES] = ET;
        __syncthreads();
        sscan[t] = pos0;                 // reuse as cursor
        __syncthreads();
        for (int j = beg + t; j < end; j += 256) {
            uint32 p = pairs[j];
            int pos = atomicAdd(&sscan[p & 255u], 1);
            csr_src[pos] = (int)(p >> 8);
        }
        return;
    }
    // ---- layer-1 transform via MFMA, LDS-free ----
    int bb = blockIdx.x - NB;
    int w = t >> 6, lane = t & 63;
    int l15 = lane & 15, quad = lane >> 4;
    int n0 = bb * 64 + w * 16;
    int mrow = n0 + l15;
    int mload = (mrow < N_NODES) ? mrow : (N_NODES - 1);

    bf16x8 af[4];
    #pragma unroll
    for (int s = 0; s < 4; ++s)
        af[s] = *(const bf16x8*)&xb[(size_t)mload * IN_DIM + s * 32 + quad * 8];

    #pragma unroll
    for (int tt = 0; tt < 9; ++tt) {
        const unsigned short* Brow = (tt < 8) ? &w1t[(tt * 16 + l15) * IN_DIM]
                                              : &p1t[l15 * IN_DIM];
        f32x4 acc = {0.f, 0.f, 0.f, 0.f};
        #pragma unroll
        for (int s = 0; s < 4; ++s) {
            bf16x8 bf = *(const bf16x8*)&Brow[s * 32 + quad * 8];
            acc = __builtin_amdgcn_mfma_f32_16x16x32_bf16(af[s], bf, acc, 0, 0, 0);
        }
        int nodeb = n0 + quad * 4;
        if (tt < 8) {
            int ch = tt * 16 + l15;
            #pragma unroll
            for (int r = 0; r < 4; ++r)
                if (nodeb + r < N_NODES)
                    h1f[(size_t)(nodeb + r) * HID + ch] = f2fp8(acc[r]);
        } else {
            #pragma unroll
            for (int r = 0; r < 4; ++r) {
                if (nodeb + r < N_NODES) {
                    if (l15 < 8) a_src[(nodeb + r) * HEADS + l15] = acc[r];
                    else         a_dst[(nodeb + r) * HEADS + (l15 - 8)] = acc[r];
                }
            }
        }
    }
}

// ---------------- Fused: layer-1 aggregate + layer-2 transform ----------------
// 256-thread block (4 waves) on a 16-node tile: phase A = ONE pass/wave
// (4 rank-adjacent nodes, 16 lanes/node, fp8 uint2 gathers, 8-deep unroll)
// -> 12.5k independent waves, 4-wave barrier sets, 4 KB LDS (8 blocks/CU).
// Phase B: all waves share the 16 rows; wave w does output tile tt=w,
// wave 0 also does the attention tile tt=4.

__global__ __launch_bounds__(256) void l1agg_l2t(
        const unsigned char* __restrict__ h1f, const float* __restrict__ a_src,
        const float* __restrict__ a_dst, const int* __restrict__ row_start,
        const int* __restrict__ csr_src, const float* __restrict__ b1,
        const unsigned short* __restrict__ w2t, const unsigned short* __restrict__ p2t,
        unsigned short* __restrict__ h2b, float* __restrict__ a_src2,
        float* __restrict__ a_dst2) {
    __shared__ unsigned short ha[16][128];   // 4 KB, swizzled granules
    __shared__ int sdeg16[16];
    __shared__ unsigned char perm[16];
    int t = threadIdx.x;
    int w = t >> 6;              // 0..3
    uint32 lane = t & 63;
    uint32 quarter = lane >> 4;
    uint32 lane16 = lane & 15;
    int n0blk = blockIdx.x * 16;

    // ---- degree-rank the 16 nodes (once per block) ----
    if (t < 16) {
        int n = n0blk + t;
        int nc = (n < N_NODES) ? n : (N_NODES - 1);
        sdeg16[t] = row_start[nc + 1] - row_start[nc];
    }
    __syncthreads();
    if (t < 16) {
        int d = sdeg16[t];
        int r = 0;
        #pragma unroll
        for (int j = 0; j < 16; ++j) {
            int dj = sdeg16[j];
            r += (dj < d) || (dj == d && j < t);
        }
        perm[r] = (unsigned char)t;
    }
    __syncthreads();

    // ---------- phase A: 4 waves x 4 nodes, one pass ----------
    {
        uint32 c0 = lane16 * 8u;     // 8 channels per lane (8 fp8 bytes)
        uint32 h = lane16 >> 1;      // head = c0 >> 4
        int n_local = (int)perm[w * 4 + (int)quarter];
        int n = n0blk + n_local;
        int nc = (n < N_NODES) ? n : (N_NODES - 1);
        int beg = row_start[nc], end = row_start[nc + 1];
        int cnt = end - beg;
        int kmax = cnt;
        kmax = max(kmax, __shfl_xor(kmax, 16, 64));
        kmax = max(kmax, __shfl_xor(kmax, 32, 64));
        float adst = a_dst[nc * HEADS + h];
        float l = 0.f;
        float a0 = 0.f, a1 = 0.f, a2 = 0.f, a3 = 0.f;
        float a4 = 0.f, a5 = 0.f, a6 = 0.f, a7 = 0.f;

        auto edge = [&](float e0, uint2 u0, bool live) {
            float e = e0 + adst;
            e = fmaxf(e, NEG_SLOPE * e);          // leaky relu (log2 domain)
            e = live ? e : -10000.f;              // masked lane -> p = 0
            float p = exp2f(e);
            l += p;
            f32x2 f01 = __builtin_amdgcn_cvt_pk_f32_fp8((int)u0.x, false);
            f32x2 f23 = __builtin_amdgcn_cvt_pk_f32_fp8((int)u0.x, true);
            f32x2 f45 = __builtin_amdgcn_cvt_pk_f32_fp8((int)u0.y, false);
            f32x2 f67 = __builtin_amdgcn_cvt_pk_f32_fp8((int)u0.y, true);
            a0 = fmaf(p, f01[0], a0);
            a1 = fmaf(p, f01[1], a1);
            a2 = fmaf(p, f23[0], a2);
            a3 = fmaf(p, f23[1], a3);
            a4 = fmaf(p, f45[0], a4);
            a5 = fmaf(p, f45[1], a5);
            a6 = fmaf(p, f67[0], a6);
            a7 = fmaf(p, f67[1], a7);
        };

        int k = 0;
        for (; k + 8 <= kmax; k += 8) {
            uint32 ss[8]; float ee[8]; uint2 uu[8];
            #pragma unroll
            for (int q = 0; q < 8; ++q) {
                int j = beg + k + q;
                int jc = (j < end) ? j : (end - 1);    // cnt >= 1 (self loop)
                ss[q] = (uint32)csr_src[jc];
            }
            #pragma unroll
            for (int q = 0; q < 8; ++q) ee[q] = a_src[ss[q] * 8u + h];
            #pragma unroll
            for (int q = 0; q < 8; ++q) uu[q] = *(const uint2*)&h1f[(ss[q] << 7) + c0];
            #pragma unroll
            for (int q = 0; q < 8; ++q) edge(ee[q], uu[q], k + q < cnt);
        }
        for (; k < kmax; k += 4) {
            uint32 ss[4]; float ee[4]; uint2 uu[4];
            #pragma unroll
            for (int q = 0; q < 4; ++q) {
                int j = beg + k + q;
                int jc = (j < end) ? j : (end - 1);
                ss[q] = (uint32)csr_src[jc];
            }
            #pragma unroll
            for (int q = 0; q < 4; ++q) ee[q] = a_src[ss[q] * 8u + h];
            #pragma unroll
            for (int q = 0; q < 4; ++q) uu[q] = *(const uint2*)&h1f[(ss[q] << 7) + c0];
            #pragma unroll
            for (int q = 0; q < 4; ++q) edge(ee[q], uu[q], k + q < cnt);
        }

        float inv = 1.f / (l + 1e-16f);
        float v0 = a0 * inv + b1[c0 + 0];
        float v1 = a1 * inv + b1[c0 + 1];
        float v2 = a2 * inv + b1[c0 + 2];
        float v3 = a3 * inv + b1[c0 + 3];
        float v4 = a4 * inv + b1[c0 + 4];
        float v5 = a5 * inv + b1[c0 + 5];
        float v6 = a6 * inv + b1[c0 + 6];
        float v7 = a7 * inv + b1[c0 + 7];
        v0 = v0 > 0.f ? v0 : (__expf(v0) - 1.f);   // ELU
        v1 = v1 > 0.f ? v1 : (__expf(v1) - 1.f);
        v2 = v2 > 0.f ? v2 : (__expf(v2) - 1.f);
        v3 = v3 > 0.f ? v3 : (__expf(v3) - 1.f);
        v4 = v4 > 0.f ? v4 : (__expf(v4) - 1.f);
        v5 = v5 > 0.f ? v5 : (__expf(v5) - 1.f);
        v6 = v6 > 0.f ? v6 : (__expf(v6) - 1.f);
        v7 = v7 > 0.f ? v7 : (__expf(v7) - 1.f);
        uint4 packed;
        packed.x = (uint32)f2bf(v0) | ((uint32)f2bf(v1) << 16);
        packed.y = (uint32)f2bf(v2) | ((uint32)f2bf(v3) << 16);
        packed.z = (uint32)f2bf(v4) | ((uint32)f2bf(v5) << 16);
        packed.w = (uint32)f2bf(v6) | ((uint32)f2bf(v7) << 16);
        uint32 g = lane16 ^ ((uint32)n_local & 15u);   // swizzled granule
        *(uint4*)&ha[n_local][g * 8] = packed;
    }
    __syncthreads();

    // ---------- phase B: layer-2 transform from LDS, tt = wave id ----------
    {
        int l15 = (int)lane16, quad = (int)quarter;
        int n0 = n0blk;
        int nloc = l15;

        bf16x8 af[4];
        #pragma unroll
        for (int s = 0; s < 4; ++s) {
            uint32 g = (uint32)(s * 4 + quad) ^ (uint32)l15;
            af[s] = *(const bf16x8*)&ha[nloc][g * 8];
        }

        #pragma unroll
        for (int pass = 0; pass < 2; ++pass) {
            if (pass == 1 && w != 0) break;
            int tt = (pass == 0) ? w : 4;
            const unsigned short* Brow = (tt < 4) ? &w2t[(tt * 16 + l15) * HID]
                                                  : &p2t[l15 * HID];
            f32x4 acc = {0.f, 0.f, 0.f, 0.f};
            #pragma unroll
            for (int s = 0; s < 4; ++s) {
                bf16x8 bf = *(const bf16x8*)&Brow[s * 32 + quad * 8];
                acc = __builtin_amdgcn_mfma_f32_16x16x32_bf16(af[s], bf, acc, 0, 0, 0);
            }
            int nodeb = n0 + quad * 4;
            if (tt < 4) {
                int ch = tt * 16 + l15;
                #pragma unroll
                for (int r = 0; r < 4; ++r)
                    if (nodeb + r < N_NODES)
                        h2b[(size_t)(nodeb + r) * OUT_DIM + ch] = f2bf(acc[r]);
            } else {
                #pragma unroll
                for (int r = 0; r < 4; ++r) {
                    if (nodeb + r < N_NODES) {
                        if (l15 == 0) a_src2[nodeb + r] = acc[r];
                        else if (l15 == 1) a_dst2[nodeb + r] = acc[r];
                    }
                }
            }
        }
    }
}

// ---------------- Layer 2: aggregate + log_softmax ----------------
// 4 nodes per wave (16 lanes/node, 4 ch/lane, uint2 gathers); 8 nodes/block
// rank-sorted by degree so each wave gets rank-adjacent nodes.

__global__ __launch_bounds__(128) void l2_aggregate(
        const unsigned short* __restrict__ h2b, const float* __restrict__ a_src2,
        const float* __restrict__ a_dst2, const int* __restrict__ row_start,
        const int* __restrict__ csr_src, const float* __restrict__ b2,
        float* __restrict__ out) {
    __shared__ int sdeg8[8];
    __shared__ int perm8[8];
    int t = threadIdx.x;
    int w = t >> 6;
    uint32 lane = t & 63;
    uint32 quarter = lane >> 4;
    uint32 lane16 = lane & 15;
    int nbase = blockIdx.x * 8;
    if (t < 8)
        sdeg8[t] = row_start[nbase + t + 1] - row_start[nbase + t];
    __syncthreads();
    if (t < 8) {
        int d = sdeg8[t];
        int r = 0;
        #pragma unroll
        for (int j = 0; j < 8; ++j) {
            int dj = sdeg8[j];
            r += (dj < d) || (dj == d && j < t);
        }
        perm8[r] = t;
    }
    __syncthreads();
    int n = nbase + perm8[w * 4 + (int)quarter];
    uint32 c0 = lane16 * 4u;
    int beg = row_start[n], end = row_start[n + 1];
    int cnt = end - beg;
    int kmax = cnt;
    kmax = max(kmax, __shfl_xor(kmax, 16, 64));
    kmax = max(kmax, __shfl_xor(kmax, 32, 64));
    float adst = a_dst2[n];
    float l = 0.f, a0 = 0.f, a1 = 0.f, a2 = 0.f, a3 = 0.f;

    for (int k = 0; k < kmax; k += 4) {
        uint32 ss[4]; float ee[4]; uint2 uu[4];
        #pragma unroll
        for (int q = 0; q < 4; ++q) {
            int j = beg + k + q;
            int jc = (j < end) ? j : (end - 1);
            ss[q] = (uint32)csr_src[jc];
        }
        #pragma unroll
        for (int q = 0; q < 4; ++q) ee[q] = a_src2[ss[q]];
        #pragma unroll
        for (int q = 0; q < 4; ++q) uu[q] = *(const uint2*)&h2b[(ss[q] << 6) + c0];
        #pragma unroll
        for (int q = 0; q < 4; ++q) {
            float e = ee[q] + adst;
            e = fmaxf(e, NEG_SLOPE * e);
            e = (k + q < cnt) ? e : -10000.f;   // masked lane -> p = 0
            float p = exp2f(e);
            l += p;
            a0 = fmaf(p, __uint_as_float(uu[q].x << 16), a0);
            a1 = fmaf(p, __uint_as_float(uu[q].x & 0xFFFF0000u), a1);
            a2 = fmaf(p, __uint_as_float(uu[q].y << 16), a2);
            a3 = fmaf(p, __uint_as_float(uu[q].y & 0xFFFF0000u), a3);
        }
    }

    float inv = 1.f / (l + 1e-16f);
    float o0 = a0 * inv + b2[c0 + 0];
    float o1 = a1 * inv + b2[c0 + 1];
    float o2 = a2 * inv + b2[c0 + 2];
    float o3 = a3 * inv + b2[c0 + 3];
    // log_softmax over 64 channels = 16 lanes x 4 (quarter-wave reduction)
    float mx = fmaxf(fmaxf(o0, o1), fmaxf(o2, o3));
    #pragma unroll
    for (int m = 8; m > 0; m >>= 1) mx = fmaxf(mx, __shfl_xor(mx, m, 16));
    float ex = __expf(o0 - mx) + __expf(o1 - mx) + __expf(o2 - mx) + __expf(o3 - mx);
    #pragma unroll
    for (int m = 8; m > 0; m >>= 1) ex += __shfl_xor(ex, m, 16);
    float lse = mx + __logf(ex);
    float4 o = make_float4(o0 - lse, o1 - lse, o2 - lse, o3 - lse);
    *(float4*)&out[(size_t)n * OUT_DIM + c0] = o;
}

// ---------------- launch ----------------

extern "C" void kernel_launch(void* const* d_in, const int* in_sizes, int n_in,
                              void* d_out, int out_size, void* d_ws, size_t ws_size,
                              hipStream_t stream) {
    const float* x   = (const float*)d_in[0];
    const int*   ei  = (const int*)d_in[1];
    const float* W1  = (const float*)d_in[2];
    const float* as1 = (const float*)d_in[3];
    const float* ad1 = (const float*)d_in[4];
    const float* b1  = (const float*)d_in[5];
    const float* W2  = (const float*)d_in[6];
    const float* as2 = (const float*)d_in[7];
    const float* ad2 = (const float*)d_in[8];
    const float* b2  = (const float*)d_in[9];
    float* out = (float*)d_out;

    const int* src = ei;             // row 0
    const int* dst = ei + E_EDGES;   // row 1

    char* ws = (char*)d_ws;
    size_t off = 0;
    auto alloc = [&](size_t bytes) -> void* {
        void* p = ws + off;
        off += (bytes + 255) & ~size_t(255);
        return p;
    };
    unsigned short* xb     = (unsigned short*)alloc((size_t)N_NODES * IN_DIM * 2);
    unsigned char*  h1f    = (unsigned char*)alloc((size_t)N_NODES * HID);
    unsigned short* h2b    = (unsigned short*)alloc((size_t)N_NODES * OUT_DIM * 2);
    unsigned short* w1t    = (unsigned short*)alloc((size_t)HID * IN_DIM * 2);
    unsigned short* p1t    = (unsigned short*)alloc((size_t)16 * IN_DIM * 2);
    unsigned short* w2t    = (unsigned short*)alloc((size_t)OUT_DIM * HID * 2);
    unsigned short* p2t    = (unsigned short*)alloc((size_t)16 * HID * 2);
    float* a_src1    = (float*)alloc((size_t)N_NODES * HEADS * 4);
    float* a_dst1    = (float*)alloc((size_t)N_NODES * HEADS * 4);
    float* a_src2    = (float*)alloc((size_t)N_NODES * 4);
    float* a_dst2    = (float*)alloc((size_t)N_NODES * 4);
    int*   row_start = (int*)alloc((size_t)(N_NODES + 1) * 4);
    int*   csr_src   = (int*)alloc((size_t)ET * 4);
    uint32* pairs    = (uint32*)alloc((size_t)ET * 4);
    int*   cnt       = (int*)alloc((size_t)NB * NT * 4);
    int*   bucketStart = (int*)alloc((size_t)(NB + 1) * 4);

    prep_all<<<MEGA_A, 256, 0, stream>>>(dst, cnt, x, xb, W1, as1, ad1,
                                         W2, as2, ad2, w1t, p1t, w2t, p2t);
    bucket_scatter<<<NT, 256, 0, stream>>>(src, dst, cnt, bucketStart, pairs);
    build_l1t<<<MEGA_B, 256, 0, stream>>>(pairs, bucketStart, row_start, csr_src,
                                          xb, w1t, p1t, h1f, a_src1, a_dst1);
    l1agg_l2t<<<FUSE_BLOCKS, 256, 0, stream>>>(h1f, a_src1, a_dst1, row_start, csr_src,
                                               b1, w2t, p2t, h2b, a_src2, a_dst2);
    l2_aggregate<<<N_NODES / 8, 128, 0, stream>>>(h2b, a_src2, a_dst2, row_start, csr_src, b2, out);
}

// Round 23
// 189.603 us; speedup vs baseline: 1.1700x; 1.0218x over previous
//
#include <hip/hip_runtime.h>
#include <math.h>

#define N_NODES 50000
#define E_EDGES 800000
#define ET      (E_EDGES + N_NODES)   // edges + self loops
#define IN_DIM  128
#define HID     128
#define HEADS   8
#define C1      16
#define OUT_DIM 64
#define NEG_SLOPE 0.2f
#define LOG2E   1.4426950408889634f

#define TILE    8192
#define NT      ((ET + TILE - 1) / TILE)      // 104 tiles
#define NB      ((N_NODES + 255) / 256)       // 196 buckets of 256 nodes

#define CONV_BLOCKS (N_NODES * IN_DIM / 4 / 256)   // 6250
#define PREP_BLOCKS 112
#define MEGA_A (NT + CONV_BLOCKS + PREP_BLOCKS)    // 6466
#define L1T_BLOCKS ((N_NODES + 63) / 64)           // 782
#define MEGA_B (NB + L1T_BLOCKS)                   // 978
#define FUSE_BLOCKS ((N_NODES + 15) / 16)          // 3125

typedef unsigned int uint32;
typedef __attribute__((ext_vector_type(8))) short bf16x8;
typedef __attribute__((ext_vector_type(4))) float f32x4;
typedef __attribute__((ext_vector_type(2))) float f32x2;

static __device__ __forceinline__ unsigned short f2bf(float f) {
    uint32 u = __float_as_uint(f);
    u += 0x7FFFu + ((u >> 16) & 1u);   // round to nearest even
    return (unsigned short)(u >> 16);
}

static __device__ __forceinline__ unsigned char f2fp8(float f) {
    int pk = __builtin_amdgcn_cvt_pk_fp8_f32(f, f, 0, false);   // RNE, OCP e4m3
    return (unsigned char)(pk & 0xFF);
}

// ---------------- Mega-kernel A: bucket_hist + convert_x + prep_weights ----------------

__global__ __launch_bounds__(256) void prep_all(
        const int* __restrict__ dst, int* __restrict__ cnt,
        const float* __restrict__ x, unsigned short* __restrict__ xb,
        const float* __restrict__ W1, const float* __restrict__ as1,
        const float* __restrict__ ad1, const float* __restrict__ W2,
        const float* __restrict__ as2, const float* __restrict__ ad2,
        unsigned short* __restrict__ w1t, unsigned short* __restrict__ p1t,
        unsigned short* __restrict__ w2t, unsigned short* __restrict__ p2t) {
    __shared__ int hist[NB];
    int blk = blockIdx.x, t = threadIdx.x;
    if (blk < NT) {
        for (int b = t; b < NB; b += 256) hist[b] = 0;
        __syncthreads();
        int base = blk * TILE;
        #pragma unroll
        for (int it = 0; it < TILE / 256; ++it) {
            int i = base + it * 256 + t;
            if (i < ET) {
                int d = (i < E_EDGES) ? dst[i] : (i - E_EDGES);
                atomicAdd(&hist[d >> 8], 1);
            }
        }
        __syncthreads();
        for (int b = t; b < NB; b += 256) cnt[blk * NB + b] = hist[b];
    } else if (blk < NT + CONV_BLOCKS) {
        int i = (blk - NT) * 256 + t;
        float4 v = ((const float4*)x)[i];
        ushort4 o;
        o.x = f2bf(v.x); o.y = f2bf(v.y); o.z = f2bf(v.z); o.w = f2bf(v.w);
        ((ushort4*)xb)[i] = o;
    } else {
        int b = blk - NT - CONV_BLOCKS;    // 0..111
        if (b < 64) {
            int i = b * 256 + t;                // n*128+k
            int n = i >> 7, k = i & 127;
            w1t[n * IN_DIM + k] = f2bf(W1[k * HID + n]);
        } else if (b < 96) {
            int i = (b - 64) * 256 + t;         // n*128+k, n<64
            int n = i >> 7, k = i & 127;
            w2t[n * HID + k] = f2bf(W2[k * OUT_DIM + n]);
        } else if (b < 104) {
            int i = (b - 96) * 256 + t;         // j*128+k, j<16
            int j = i >> 7, k = i & 127;
            int hh = j & 7;
            const float* a = (j < 8) ? as1 : ad1;
            float acc = 0.f;
            #pragma unroll
            for (int c = 0; c < C1; ++c)
                acc = fmaf(W1[k * HID + hh * C1 + c], a[hh * C1 + c], acc);
            p1t[j * IN_DIM + k] = f2bf(acc * LOG2E);
        } else {
            int i = (b - 104) * 256 + t;        // j*128+k, j<16
            int j = i >> 7, k = i & 127;
            if (j < 2) {
                const float* a = (j == 0) ? as2 : ad2;
                float acc = 0.f;
                #pragma unroll
                for (int c = 0; c < OUT_DIM; ++c)
                    acc = fmaf(W2[k * OUT_DIM + c], a[c], acc);
                p2t[j * HID + k] = f2bf(acc * LOG2E);
            } else {
                p2t[j * HID + k] = 0;
            }
        }
    }
}

// ---------------- bucket_scatter (scan fused in) ----------------

__global__ __launch_bounds__(256) void bucket_scatter(
        const int* __restrict__ src, const int* __restrict__ dst,
        const int* __restrict__ cnt, int* __restrict__ bucketStart,
        uint32* __restrict__ pairs) {
    __shared__ int lcur[NB];
    __shared__ int sscan[256];
    int t = threadIdx.x;
    int tile = blockIdx.x;

    int run = 0, total = 0;
    if (t < NB) {
        for (int k = 0; k < NT; ++k) {
            int c = cnt[k * NB + t];     // coalesced across t
            if (k < tile) run += c;
            total += c;
        }
    }
    sscan[t] = (t < NB) ? total : 0;
    __syncthreads();
    #pragma unroll
    for (int off = 1; off < 256; off <<= 1) {
        int add = (t >= off) ? sscan[t - off] : 0;
        __syncthreads();
        sscan[t] += add;
        __syncthreads();
    }
    int bstart = sscan[t] - total;       // exclusive prefix
    if (t < NB) {
        lcur[t] = bstart + run;
        if (tile == 0) bucketStart[t] = bstart;
    }
    if (tile == 0 && t == 0) bucketStart[NB] = ET;
    __syncthreads();

    int base = tile * TILE;
    #pragma unroll
    for (int it = 0; it < TILE / 256; ++it) {
        int i = base + it * 256 + t;
        if (i < ET) {
            int s, d;
            if (i < E_EDGES) { s = src[i]; d = dst[i]; }
            else             { s = d = i - E_EDGES; }
            int pos = atomicAdd(&lcur[d >> 8], 1);
            pairs[pos] = ((uint32)s << 8) | (uint32)(d & 255);
        }
    }
}

// ---------------- Mega-kernel B: bucket_build + l1_transform_mfma ----------------
// h1 payload stored as fp8 e4m3 (HW cvt, RNE): 128 B/node.

__global__ __launch_bounds__(256) void build_l1t(
        const uint32* __restrict__ pairs, const int* __restrict__ bucketStart,
        int* __restrict__ row_start, int* __restrict__ csr_src,
        const unsigned short* __restrict__ xb, const unsigned short* __restrict__ w1t,
        const unsigned short* __restrict__ p1t, unsigned char* __restrict__ h1f,
        float* __restrict__ a_src, float* __restrict__ a_dst) {
    __shared__ int sdeg[256];
    __shared__ int sscan[256];
    int t = threadIdx.x;
    if (blockIdx.x < NB) {
        int b = blockIdx.x;
        int beg = bucketStart[b], end = bucketStart[b + 1];
        sdeg[t] = 0;
        __syncthreads();
        for (int j = beg + t; j < end; j += 256)
            atomicAdd(&sdeg[pairs[j] & 255u], 1);
        __syncthreads();
        int v = sdeg[t];
        sscan[t] = v;
        __syncthreads();
        #pragma unroll
        for (int off = 1; off < 256; off <<= 1) {
            int add = (t >= off) ? sscan[t - off] : 0;
            __syncthreads();
            sscan[t] += add;
            __syncthreads();
        }
        int pos0 = beg + sscan[t] - v;   // exclusive prefix within bucket
        int n = b * 256 + t;
        if (n < N_NODES) row_start[n] = pos0;
        if (b == 0 && t == 0) row_start[N_NODES] = ET;
        __syncthreads();
        sscan[t] = pos0;                 // reuse as cursor
        __syncthreads();
        for (int j = beg + t; j < end; j += 256) {
            uint32 p = pairs[j];
            int pos = atomicAdd(&sscan[p & 255u], 1);
            csr_src[pos] = (int)(p >> 8);
        }
        return;
    }
    // ---- layer-1 transform via MFMA, LDS-free ----
    int bb = blockIdx.x - NB;
    int w = t >> 6, lane = t & 63;
    int l15 = lane & 15, quad = lane >> 4;
    int n0 = bb * 64 + w * 16;
    int mrow = n0 + l15;
    int mload = (mrow < N_NODES) ? mrow : (N_NODES - 1);

    bf16x8 af[4];
    #pragma unroll
    for (int s = 0; s < 4; ++s)
        af[s] = *(const bf16x8*)&xb[(size_t)mload * IN_DIM + s * 32 + quad * 8];

    #pragma unroll
    for (int tt = 0; tt < 9; ++tt) {
        const unsigned short* Brow = (tt < 8) ? &w1t[(tt * 16 + l15) * IN_DIM]
                                              : &p1t[l15 * IN_DIM];
        f32x4 acc = {0.f, 0.f, 0.f, 0.f};
        #pragma unroll
        for (int s = 0; s < 4; ++s) {
            bf16x8 bf = *(const bf16x8*)&Brow[s * 32 + quad * 8];
            acc = __builtin_amdgcn_mfma_f32_16x16x32_bf16(af[s], bf, acc, 0, 0, 0);
        }
        int nodeb = n0 + quad * 4;
        if (tt < 8) {
            int ch = tt * 16 + l15;
            #pragma unroll
            for (int r = 0; r < 4; ++r)
                if (nodeb + r < N_NODES)
                    h1f[(size_t)(nodeb + r) * HID + ch] = f2fp8(acc[r]);
        } else {
            #pragma unroll
            for (int r = 0; r < 4; ++r) {
                if (nodeb + r < N_NODES) {
                    if (l15 < 8) a_src[(nodeb + r) * HEADS + l15] = acc[r];
                    else         a_dst[(nodeb + r) * HEADS + (l15 - 8)] = acc[r];
                }
            }
        }
    }
}

// ---------------- Fused: layer-1 aggregate + layer-2 transform ----------------
// 256-thread block (4 waves) on a 16-node tile: phase A = ONE pass/wave
// (4 rank-adjacent nodes, 16 lanes/node, fp8 uint2 gathers, 8-deep unroll).
// Phase B: wave w does output tile tt=w (h2 stored fp8), wave 0 also tt=4.

__global__ __launch_bounds__(256) void l1agg_l2t(
        const unsigned char* __restrict__ h1f, const float* __restrict__ a_src,
        const float* __restrict__ a_dst, const int* __restrict__ row_start,
        const int* __restrict__ csr_src, const float* __restrict__ b1,
        const unsigned short* __restrict__ w2t, const unsigned short* __restrict__ p2t,
        unsigned char* __restrict__ h2f, float* __restrict__ a_src2,
        float* __restrict__ a_dst2) {
    __shared__ unsigned short ha[16][128];   // 4 KB, swizzled granules
    __shared__ int sdeg16[16];
    __shared__ unsigned char perm[16];
    int t = threadIdx.x;
    int w = t >> 6;              // 0..3
    uint32 lane = t & 63;
    uint32 quarter = lane >> 4;
    uint32 lane16 = lane & 15;
    int n0blk = blockIdx.x * 16;

    // ---- degree-rank the 16 nodes (once per block) ----
    if (t < 16) {
        int n = n0blk + t;
        int nc = (n < N_NODES) ? n : (N_NODES - 1);
        sdeg16[t] = row_start[nc + 1] - row_start[nc];
    }
    __syncthreads();
    if (t < 16) {
        int d = sdeg16[t];
        int r = 0;
        #pragma unroll
        for (int j = 0; j < 16; ++j) {
            int dj = sdeg16[j];
            r += (dj < d) || (dj == d && j < t);
        }
        perm[r] = (unsigned char)t;
    }
    __syncthreads();

    // ---------- phase A: 4 waves x 4 nodes, one pass ----------
    {
        uint32 c0 = lane16 * 8u;     // 8 channels per lane (8 fp8 bytes)
        uint32 h = lane16 >> 1;      // head = c0 >> 4
        int n_local = (int)perm[w * 4 + (int)quarter];
        int n = n0blk + n_local;
        int nc = (n < N_NODES) ? n : (N_NODES - 1);
        int beg = row_start[nc], end = row_start[nc + 1];
        int cnt = end - beg;
        int kmax = cnt;
        kmax = max(kmax, __shfl_xor(kmax, 16, 64));
        kmax = max(kmax, __shfl_xor(kmax, 32, 64));
        float adst = a_dst[nc * HEADS + h];
        float l = 0.f;
        float a0 = 0.f, a1 = 0.f, a2 = 0.f, a3 = 0.f;
        float a4 = 0.f, a5 = 0.f, a6 = 0.f, a7 = 0.f;

        auto edge = [&](float e0, uint2 u0, bool live) {
            float e = e0 + adst;
            e = fmaxf(e, NEG_SLOPE * e);          // leaky relu (log2 domain)
            e = live ? e : -10000.f;              // masked lane -> p = 0
            float p = exp2f(e);
            l += p;
            f32x2 f01 = __builtin_amdgcn_cvt_pk_f32_fp8((int)u0.x, false);
            f32x2 f23 = __builtin_amdgcn_cvt_pk_f32_fp8((int)u0.x, true);
            f32x2 f45 = __builtin_amdgcn_cvt_pk_f32_fp8((int)u0.y, false);
            f32x2 f67 = __builtin_amdgcn_cvt_pk_f32_fp8((int)u0.y, true);
            a0 = fmaf(p, f01[0], a0);
            a1 = fmaf(p, f01[1], a1);
            a2 = fmaf(p, f23[0], a2);
            a3 = fmaf(p, f23[1], a3);
            a4 = fmaf(p, f45[0], a4);
            a5 = fmaf(p, f45[1], a5);
            a6 = fmaf(p, f67[0], a6);
            a7 = fmaf(p, f67[1], a7);
        };

        int k = 0;
        for (; k + 8 <= kmax; k += 8) {
            uint32 ss[8]; float ee[8]; uint2 uu[8];
            #pragma unroll
            for (int q = 0; q < 8; ++q) {
                int j = beg + k + q;
                int jc = (j < end) ? j : (end - 1);    // cnt >= 1 (self loop)
                ss[q] = (uint32)csr_src[jc];
            }
            #pragma unroll
            for (int q = 0; q < 8; ++q) ee[q] = a_src[ss[q] * 8u + h];
            #pragma unroll
            for (int q = 0; q < 8; ++q) uu[q] = *(const uint2*)&h1f[(ss[q] << 7) + c0];
            #pragma unroll
            for (int q = 0; q < 8; ++q) edge(ee[q], uu[q], k + q < cnt);
        }
        for (; k < kmax; k += 4) {
            uint32 ss[4]; float ee[4]; uint2 uu[4];
            #pragma unroll
            for (int q = 0; q < 4; ++q) {
                int j = beg + k + q;
                int jc = (j < end) ? j : (end - 1);
                ss[q] = (uint32)csr_src[jc];
            }
            #pragma unroll
            for (int q = 0; q < 4; ++q) ee[q] = a_src[ss[q] * 8u + h];
            #pragma unroll
            for (int q = 0; q < 4; ++q) uu[q] = *(const uint2*)&h1f[(ss[q] << 7) + c0];
            #pragma unroll
            for (int q = 0; q < 4; ++q) edge(ee[q], uu[q], k + q < cnt);
        }

        float inv = 1.f / (l + 1e-16f);
        float v0 = a0 * inv + b1[c0 + 0];
        float v1 = a1 * inv + b1[c0 + 1];
        float v2 = a2 * inv + b1[c0 + 2];
        float v3 = a3 * inv + b1[c0 + 3];
        float v4 = a4 * inv + b1[c0 + 4];
        float v5 = a5 * inv + b1[c0 + 5];
        float v6 = a6 * inv + b1[c0 + 6];
        float v7 = a7 * inv + b1[c0 + 7];
        v0 = v0 > 0.f ? v0 : (__expf(v0) - 1.f);   // ELU
        v1 = v1 > 0.f ? v1 : (__expf(v1) - 1.f);
        v2 = v2 > 0.f ? v2 : (__expf(v2) - 1.f);
        v3 = v3 > 0.f ? v3 : (__expf(v3) - 1.f);
        v4 = v4 > 0.f ? v4 : (__expf(v4) - 1.f);
        v5 = v5 > 0.f ? v5 : (__expf(v5) - 1.f);
        v6 = v6 > 0.f ? v6 : (__expf(v6) - 1.f);
        v7 = v7 > 0.f ? v7 : (__expf(v7) - 1.f);
        uint4 packed;
        packed.x = (uint32)f2bf(v0) | ((uint32)f2bf(v1) << 16);
        packed.y = (uint32)f2bf(v2) | ((uint32)f2bf(v3) << 16);
        packed.z = (uint32)f2bf(v4) | ((uint32)f2bf(v5) << 16);
        packed.w = (uint32)f2bf(v6) | ((uint32)f2bf(v7) << 16);
        uint32 g = lane16 ^ ((uint32)n_local & 15u);   // swizzled granule
        *(uint4*)&ha[n_local][g * 8] = packed;
    }
    __syncthreads();

    // ---------- phase B: layer-2 transform from LDS, tt = wave id ----------
    {
        int l15 = (int)lane16, quad = (int)quarter;
        int n0 = n0blk;
        int nloc = l15;

        bf16x8 af[4];
        #pragma unroll
        for (int s = 0; s < 4; ++s) {
            uint32 g = (uint32)(s * 4 + quad) ^ (uint32)l15;
            af[s] = *(const bf16x8*)&ha[nloc][g * 8];
        }

        #pragma unroll
        for (int pass = 0; pass < 2; ++pass) {
            if (pass == 1 && w != 0) break;
            int tt = (pass == 0) ? w : 4;
            const unsigned short* Brow = (tt < 4) ? &w2t[(tt * 16 + l15) * HID]
                                                  : &p2t[l15 * HID];
            f32x4 acc = {0.f, 0.f, 0.f, 0.f};
            #pragma unroll
            for (int s = 0; s < 4; ++s) {
                bf16x8 bf = *(const bf16x8*)&Brow[s * 32 + quad * 8];
                acc = __builtin_amdgcn_mfma_f32_16x16x32_bf16(af[s], bf, acc, 0, 0, 0);
            }
            int nodeb = n0 + quad * 4;
            if (tt < 4) {
                int ch = tt * 16 + l15;
                #pragma unroll
                for (int r = 0; r < 4; ++r)
                    if (nodeb + r < N_NODES)
                        h2f[(size_t)(nodeb + r) * OUT_DIM + ch] = f2fp8(acc[r]);
            } else {
                #pragma unroll
                for (int r = 0; r < 4; ++r) {
                    if (nodeb + r < N_NODES) {
                        if (l15 == 0) a_src2[nodeb + r] = acc[r];
                        else if (l15 == 1) a_dst2[nodeb + r] = acc[r];
                    }
                }
            }
        }
    }
}

// ---------------- Layer 2: aggregate + log_softmax ----------------
// 4 nodes per wave (16 lanes/node, 4 ch/lane, fp8 uint32 gathers);
// 8 nodes/block rank-sorted by degree.

__global__ __launch_bounds__(128) void l2_aggregate(
        const unsigned char* __restrict__ h2f, const float* __restrict__ a_src2,
        const float* __restrict__ a_dst2, const int* __restrict__ row_start,
        const int* __restrict__ csr_src, const float* __restrict__ b2,
        float* __restrict__ out) {
    __shared__ int sdeg8[8];
    __shared__ int perm8[8];
    int t = threadIdx.x;
    int w = t >> 6;
    uint32 lane = t & 63;
    uint32 quarter = lane >> 4;
    uint32 lane16 = lane & 15;
    int nbase = blockIdx.x * 8;
    if (t < 8)
        sdeg8[t] = row_start[nbase + t + 1] - row_start[nbase + t];
    __syncthreads();
    if (t < 8) {
        int d = sdeg8[t];
        int r = 0;
        #pragma unroll
        for (int j = 0; j < 8; ++j) {
            int dj = sdeg8[j];
            r += (dj < d) || (dj == d && j < t);
        }
        perm8[r] = t;
    }
    __syncthreads();
    int n = nbase + perm8[w * 4 + (int)quarter];
    uint32 c0 = lane16 * 4u;
    int beg = row_start[n], end = row_start[n + 1];
    int cnt = end - beg;
    int kmax = cnt;
    kmax = max(kmax, __shfl_xor(kmax, 16, 64));
    kmax = max(kmax, __shfl_xor(kmax, 32, 64));
    float adst = a_dst2[n];
    float l = 0.f, a0 = 0.f, a1 = 0.f, a2 = 0.f, a3 = 0.f;

    for (int k = 0; k < kmax; k += 4) {
        uint32 ss[4]; float ee[4]; uint32 uu[4];
        #pragma unroll
        for (int q = 0; q < 4; ++q) {
            int j = beg + k + q;
            int jc = (j < end) ? j : (end - 1);
            ss[q] = (uint32)csr_src[jc];
        }
        #pragma unroll
        for (int q = 0; q < 4; ++q) ee[q] = a_src2[ss[q]];
        #pragma unroll
        for (int q = 0; q < 4; ++q) uu[q] = *(const uint32*)&h2f[(ss[q] << 6) + c0];
        #pragma unroll
        for (int q = 0; q < 4; ++q) {
            float e = ee[q] + adst;
            e = fmaxf(e, NEG_SLOPE * e);
            e = (k + q < cnt) ? e : -10000.f;   // masked lane -> p = 0
            float p = exp2f(e);
            l += p;
            f32x2 f01 = __builtin_amdgcn_cvt_pk_f32_fp8((int)uu[q], false);
            f32x2 f23 = __builtin_amdgcn_cvt_pk_f32_fp8((int)uu[q], true);
            a0 = fmaf(p, f01[0], a0);
            a1 = fmaf(p, f01[1], a1);
            a2 = fmaf(p, f23[0], a2);
            a3 = fmaf(p, f23[1], a3);
        }
    }

    float inv = 1.f / (l + 1e-16f);
    float o0 = a0 * inv + b2[c0 + 0];
    float o1 = a1 * inv + b2[c0 + 1];
    float o2 = a2 * inv + b2[c0 + 2];
    float o3 = a3 * inv + b2[c0 + 3];
    // log_softmax over 64 channels = 16 lanes x 4 (quarter-wave reduction)
    float mx = fmaxf(fmaxf(o0, o1), fmaxf(o2, o3));
    #pragma unroll
    for (int m = 8; m > 0; m >>= 1) mx = fmaxf(mx, __shfl_xor(mx, m, 16));
    float ex = __expf(o0 - mx) + __expf(o1 - mx) + __expf(o2 - mx) + __expf(o3 - mx);
    #pragma unroll
    for (int m = 8; m > 0; m >>= 1) ex += __shfl_xor(ex, m, 16);
    float lse = mx + __logf(ex);
    float4 o = make_float4(o0 - lse, o1 - lse, o2 - lse, o3 - lse);
    *(float4*)&out[(size_t)n * OUT_DIM + c0] = o;
}

// ---------------- launch ----------------

extern "C" void kernel_launch(void* const* d_in, const int* in_sizes, int n_in,
                              void* d_out, int out_size, void* d_ws, size_t ws_size,
                              hipStream_t stream) {
    const float* x   = (const float*)d_in[0];
    const int*   ei  = (const int*)d_in[1];
    const float* W1  = (const float*)d_in[2];
    const float* as1 = (const float*)d_in[3];
    const float* ad1 = (const float*)d_in[4];
    const float* b1  = (const float*)d_in[5];
    const float* W2  = (const float*)d_in[6];
    const float* as2 = (const float*)d_in[7];
    const float* ad2 = (const float*)d_in[8];
    const float* b2  = (const float*)d_in[9];
    float* out = (float*)d_out;

    const int* src = ei;             // row 0
    const int* dst = ei + E_EDGES;   // row 1

    char* ws = (char*)d_ws;
    size_t off = 0;
    auto alloc = [&](size_t bytes) -> void* {
        void* p = ws + off;
        off += (bytes + 255) & ~size_t(255);
        return p;
    };
    unsigned short* xb     = (unsigned short*)alloc((size_t)N_NODES * IN_DIM * 2);
    unsigned char*  h1f    = (unsigned char*)alloc((size_t)N_NODES * HID);
    unsigned char*  h2f    = (unsigned char*)alloc((size_t)N_NODES * OUT_DIM);
    unsigned short* w1t    = (unsigned short*)alloc((size_t)HID * IN_DIM * 2);
    unsigned short* p1t    = (unsigned short*)alloc((size_t)16 * IN_DIM * 2);
    unsigned short* w2t    = (unsigned short*)alloc((size_t)OUT_DIM * HID * 2);
    unsigned short* p2t    = (unsigned short*)alloc((size_t)16 * HID * 2);
    float* a_src1    = (float*)alloc((size_t)N_NODES * HEADS * 4);
    float* a_dst1    = (float*)alloc((size_t)N_NODES * HEADS * 4);
    float* a_src2    = (float*)alloc((size_t)N_NODES * 4);
    float* a_dst2    = (float*)alloc((size_t)N_NODES * 4);
    int*   row_start = (int*)alloc((size_t)(N_NODES + 1) * 4);
    int*   csr_src   = (int*)alloc((size_t)ET * 4);
    uint32* pairs    = (uint32*)alloc((size_t)ET * 4);
    int*   cnt       = (int*)alloc((size_t)NB * NT * 4);
    int*   bucketStart = (int*)alloc((size_t)(NB + 1) * 4);

    prep_all<<<MEGA_A, 256, 0, stream>>>(dst, cnt, x, xb, W1, as1, ad1,
                                         W2, as2, ad2, w1t, p1t, w2t, p2t);
    bucket_scatter<<<NT, 256, 0, stream>>>(src, dst, cnt, bucketStart, pairs);
    build_l1t<<<MEGA_B, 256, 0, stream>>>(pairs, bucketStart, row_start, csr_src,
                                          xb, w1t, p1t, h1f, a_src1, a_dst1);
    l1agg_l2t<<<FUSE_BLOCKS, 256, 0, stream>>>(h1f, a_src1, a_dst1, row_start, csr_src,
                                               b1, w2t, p2t, h2f, a_src2, a_dst2);
    l2_aggregate<<<N_NODES / 8, 128, 0, stream>>>(h2f, a_src2, a_dst2, row_start, csr_src, b2, out);
}